// Round 2
// baseline (6971.478 us; speedup 1.0000x reference)
//
#include <hip/hip_runtime.h>
#include <cstdint>
#include <cstddef>

#define NN 16384
#define EE 49152
#define BB 256
// D=256, G=16, 16 channels per group, HD=16

typedef _Float16 f16;
typedef _Float16 half8 __attribute__((ext_vector_type(8)));
typedef _Float16 half4v __attribute__((ext_vector_type(4)));
typedef float floatx4 __attribute__((ext_vector_type(4)));

static constexpr size_t ND = (size_t)NN * 256;

// ---------------- setup kernels ----------------

__global__ __launch_bounds__(256) void count_deg_kernel(const int* __restrict__ dst, int* __restrict__ cnt, int e) {
  int i = blockIdx.x * 256 + threadIdx.x;
  if (i < e) atomicAdd(&cnt[dst[i]], 1);
}
__global__ __launch_bounds__(256) void clip_deg_kernel(const int* __restrict__ cnt, int* __restrict__ deg, int n) {
  int i = blockIdx.x * 256 + threadIdx.x;
  if (i < n) { int v = cnt[i] - 1; deg[i] = v < 0 ? 0 : (v > 3 ? 3 : v); }
}
__global__ __launch_bounds__(256) void goff_kernel(const int* __restrict__ batch, int* __restrict__ goff, int n, int b) {
  int i = blockIdx.x * 256 + threadIdx.x;
  if (i > n) return;
  int cur = (i < n) ? batch[i] : b;
  int prev = (i == 0) ? -1 : batch[i - 1];
  for (int x = prev + 1; x <= cur; x++) goff[x] = i;
}
__global__ __launch_bounds__(256) void add3_kernel(float* __restrict__ dst,
    const float* __restrict__ a, const float* __restrict__ b, size_t n) {
  size_t i = (size_t)blockIdx.x * 256 + threadIdx.x;
  if (i < n) dst[i] = a[i] + b[i];
}
__global__ __launch_bounds__(256) void deg_scaled_add_kernel(float* __restrict__ xo,
    const float* __restrict__ xr, const float* __restrict__ sc, const int* __restrict__ deg) {
  size_t i = (size_t)blockIdx.x * 256 + threadIdx.x;
  int n = (int)(i >> 8), c = (int)(i & 255);
  xo[i] += expf(sc[deg[n] * 256 + c]) * xr[i];
}
__global__ __launch_bounds__(256) void bcast_add_kernel(float* __restrict__ ho,
    const float* __restrict__ vo, const float* __restrict__ vs, const int* __restrict__ batch) {
  size_t i = (size_t)blockIdx.x * 256 + threadIdx.x;
  int n = (int)(i >> 8), c = (int)(i & 255);
  ho[i] += expf(vs[c]) * vo[(size_t)batch[n] * 256 + c];
}

// fp32 -> fp16 convert (vectorized x4)
__global__ __launch_bounds__(256) void f2h_kernel(const float* __restrict__ in, f16* __restrict__ out, int n4) {
  int i = blockIdx.x * 256 + threadIdx.x;
  if (i >= n4) return;
  float4 v = reinterpret_cast<const float4*>(in)[i];
  half4v o;
  o.x = (f16)v.x; o.y = (f16)v.y; o.z = (f16)v.z; o.w = (f16)v.w;
  reinterpret_cast<half4v*>(out)[i] = o;
}

// ---------------- initial edge / node features ----------------

__global__ __launch_bounds__(256) void edge_feat_kernel(
    const int* __restrict__ eattr, const int* __restrict__ dst,
    const float* __restrict__ edist, const float* __restrict__ bond2d,
    const float* __restrict__ gmeans, const float* __restrict__ gstds,
    const float* __restrict__ attn_w, const float* __restrict__ attn_b,
    float* __restrict__ tmp) {
  int lane = threadIdx.x & 63;
  int e = blockIdx.x * 4 + (threadIdx.x >> 6);
  if (e >= EE) return;
  int a0 = eattr[e * 3 + 0], a1 = eattr[e * 3 + 1], a2 = eattr[e * 3 + 2];
  float dist = edist[e];
  int d = dst[e];
  const float SQ2PI = sqrtf(2.0f * 3.14159f);
  float h2[4], h3[4];
  float part = 0.f;
#pragma unroll
  for (int i = 0; i < 4; i++) {
    int c = lane + 64 * i;
    h2[i] = bond2d[a0 * 256 + c] + bond2d[2048 + a1 * 256 + c] + bond2d[4096 + a2 * 256 + c];
    float sd = fabsf(gstds[c]) + 0.01f;
    float df = (dist - gmeans[c]) / sd;
    h3[i] = expf(-0.5f * df * df) / (SQ2PI * sd);
    part += attn_w[c] * h2[i] + attn_w[256 + c] * h3[i];
  }
#pragma unroll
  for (int off = 32; off > 0; off >>= 1) part += __shfl_xor(part, off);
  float wg = 1.f / (1.f + expf(-(part + attn_b[0])));
#pragma unroll
  for (int i = 0; i < 4; i++) {
    int c = lane + 64 * i;
    atomicAdd(&tmp[(size_t)d * 256 + c], wg * h2[i] + (1.f - wg) * h3[i]);
  }
}

__global__ __launch_bounds__(256) void atom_finish_kernel(
    const int* __restrict__ xf, const float* __restrict__ emb,
    const float* __restrict__ scale_both, const int* __restrict__ deg,
    const float* __restrict__ tmp, float* __restrict__ h_in) {
  size_t i = (size_t)blockIdx.x * 256 + threadIdx.x;
  int n = (int)(i >> 8), c = (int)(i & 255);
  float acc = 0.f;
#pragma unroll
  for (int f = 0; f < 9; f++) {
    int v = xf[n * 9 + f];
    acc += emb[((size_t)(f * 128 + v)) * 256 + c];
  }
  h_in[i] = acc + expf(scale_both[deg[n] * 256 + c]) * tmp[i];
}

// ---------------- fp16 MFMA GEMM: C[M,256](f32) = A[M,K](f16) @ W[256,K](f16)^T ----------------
// MODE 0: store (+bias if non-null); MODE 2: C += expf(scale[col])*(acc+bias[col]);
// MODE 3: store acc + cnt[row]*bias[col]
// block = 256 thr (4 waves, 2x2 of 64x64), tile 128x128, BK=32, mfma 16x16x32 f16
template <int MODE>
__global__ __launch_bounds__(256) void hgemm_kernel(
    const f16* __restrict__ A, const f16* __restrict__ W,
    const float* __restrict__ bias, const float* __restrict__ scale,
    const int* __restrict__ cnt, float* __restrict__ C, int K) {
  __shared__ f16 Ah[128 * 40];  // row stride 40 halfs (80B) -> 2-way bank alias only
  __shared__ f16 Wh[128 * 40];
  const int tid = threadIdx.x;
  const int row0 = blockIdx.x * 128, col0 = blockIdx.y * 128;
  const int lane = tid & 63;
  const int wave = tid >> 6;
  const int wr = (wave >> 1) * 64, wc = (wave & 1) * 64;
  const floatx4 fz = {0.f, 0.f, 0.f, 0.f};
  floatx4 acc[4][4];
#pragma unroll
  for (int m = 0; m < 4; m++)
#pragma unroll
    for (int n = 0; n < 4; n++) acc[m][n] = fz;
  // staging assignment: 512 16B-chunks, 2 per thread (chunk q -> row q/4, part q%4)
  const int q0 = tid * 2;
  const int r0s = q0 >> 2, p0s = q0 & 3;
  const int r1s = (q0 + 1) >> 2, p1s = (q0 + 1) & 3;
  const int kb = (lane >> 4) * 8;
  const int fr = lane & 15;
  for (int k0 = 0; k0 < K; k0 += 32) {
    uint4 a0 = *reinterpret_cast<const uint4*>(&A[(size_t)(row0 + r0s) * K + k0 + p0s * 8]);
    uint4 a1 = *reinterpret_cast<const uint4*>(&A[(size_t)(row0 + r1s) * K + k0 + p1s * 8]);
    uint4 w0 = *reinterpret_cast<const uint4*>(&W[(size_t)(col0 + r0s) * K + k0 + p0s * 8]);
    uint4 w1 = *reinterpret_cast<const uint4*>(&W[(size_t)(col0 + r1s) * K + k0 + p1s * 8]);
    *reinterpret_cast<uint4*>(&Ah[r0s * 40 + p0s * 8]) = a0;
    *reinterpret_cast<uint4*>(&Ah[r1s * 40 + p1s * 8]) = a1;
    *reinterpret_cast<uint4*>(&Wh[r0s * 40 + p0s * 8]) = w0;
    *reinterpret_cast<uint4*>(&Wh[r1s * 40 + p1s * 8]) = w1;
    __syncthreads();
    half8 af[4], wf[4];
#pragma unroll
    for (int m = 0; m < 4; m++)
      af[m] = *reinterpret_cast<const half8*>(&Ah[(wr + m * 16 + fr) * 40 + kb]);
#pragma unroll
    for (int n = 0; n < 4; n++)
      wf[n] = *reinterpret_cast<const half8*>(&Wh[(wc + n * 16 + fr) * 40 + kb]);
#pragma unroll
    for (int m = 0; m < 4; m++)
#pragma unroll
      for (int n = 0; n < 4; n++)
        acc[m][n] = __builtin_amdgcn_mfma_f32_16x16x32_f16(af[m], wf[n], acc[m][n], 0, 0, 0);
    __syncthreads();
  }
  const int rl4 = (lane >> 4) * 4, cl = lane & 15;
#pragma unroll
  for (int m = 0; m < 4; m++) {
#pragma unroll
    for (int i = 0; i < 4; i++) {
      int row = row0 + wr + m * 16 + rl4 + i;
      float cb = (MODE == 3) ? (float)cnt[row] : 1.f;
#pragma unroll
      for (int n = 0; n < 4; n++) {
        int col = col0 + wc + n * 16 + cl;
        float v = acc[m][n][i];
        if (MODE == 3) v += cb * bias[col];
        else if (bias) v += bias[col];
        if (MODE == 2) C[(size_t)row * 256 + col] += expf(scale[col]) * v;
        else C[(size_t)row * 256 + col] = v;
      }
    }
  }
}

// ---------------- conv edge: gather + bond + GN + glin(gate/val) + product + scatter-sum ----------------
// thread = (edge, group); scatters its 16 output channels into agg[dst] with f32 atomics
__global__ __launch_bounds__(256) void conv_edge_kernel(
    const float* __restrict__ xp, const int* __restrict__ eattr,
    const int* __restrict__ src, const int* __restrict__ dst,
    const float* __restrict__ bond_emb, const float* __restrict__ gate_w,
    const float* __restrict__ val_w, float* __restrict__ agg) {
  __shared__ float sb[6144];  // [3][8][256]
  __shared__ float sg[4096];  // transposed [o][i][g]
  __shared__ float sv[4096];
  int tid = threadIdx.x;
  for (int i = tid; i < 6144; i += 256) sb[i] = bond_emb[i];
  for (int i = tid; i < 4096; i += 256) {
    int g = i >> 8, o = (i >> 4) & 15, ii = i & 15;
    int t = (o * 16 + ii) * 16 + g;
    sg[t] = gate_w[i];
    sv[t] = val_w[i];
  }
  __syncthreads();
  int idx = blockIdx.x * 256 + tid;
  int e = idx >> 4, g = idx & 15;
  int a0 = eattr[e * 3 + 0], a1 = eattr[e * 3 + 1], a2 = eattr[e * 3 + 2];
  int d = dst[e], s = src[e];
  const float* xd = &xp[(size_t)d * 256 + g * 16];
  const float* xs = &xp[(size_t)s * 256 + g * 16];
  float xg[16], xv[16];
  float mg = 0.f, mv = 0.f;
#pragma unroll
  for (int i = 0; i < 16; i++) {
    float bo = sb[a0 * 256 + g * 16 + i] + sb[2048 + a1 * 256 + g * 16 + i] + sb[4096 + a2 * 256 + g * 16 + i];
    xg[i] = xd[i] + bo;
    xv[i] = xs[i] + bo;
    mg += xg[i];
    mv += xv[i];
  }
  mg *= (1.f / 16.f);
  mv *= (1.f / 16.f);
  float vg = 0.f, vv = 0.f;
#pragma unroll
  for (int i = 0; i < 16; i++) {
    float dg_ = xg[i] - mg, dv_ = xv[i] - mv;
    vg += dg_ * dg_;
    vv += dv_ * dv_;
  }
  float rg = rsqrtf(vg * (1.f / 16.f) + 1e-5f);
  float rv = rsqrtf(vv * (1.f / 16.f) + 1e-5f);
#pragma unroll
  for (int i = 0; i < 16; i++) {
    xg[i] = (xg[i] - mg) * rg;
    xv[i] = (xv[i] - mv) * rv;
  }
  float* op = &agg[(size_t)d * 256 + g * 16];
#pragma unroll
  for (int o = 0; o < 16; o++) {
    float ag = 0.f, av = 0.f;
#pragma unroll
    for (int i = 0; i < 16; i++) {
      ag += xg[i] * sg[(o * 16 + i) * 16 + g];
      av += xv[i] * sv[(o * 16 + i) * 16 + g];
    }
    atomicAdd(&op[o], fmaxf(ag, 0.f) * av);
  }
}

// ---------------- glb middle: GN + glin + relu*mul, fp16 output ----------------
template <int DOUT>
__global__ __launch_bounds__(256) void glb_mid_kernel(
    const float* __restrict__ X, const float* __restrict__ gate_w,
    const float* __restrict__ val_w, f16* __restrict__ out) {
  __shared__ float sg[16 * DOUT * 16];
  __shared__ float sv[16 * DOUT * 16];
  int tid = threadIdx.x;
  for (int i = tid; i < 16 * DOUT * 16; i += 256) {
    int g = i / (DOUT * 16), rem = i % (DOUT * 16), o = rem >> 4, ii = rem & 15;
    int t = (o * 16 + ii) * 16 + g;
    sg[t] = gate_w[i];
    sv[t] = val_w[i];
  }
  __syncthreads();
  int idx = blockIdx.x * 256 + tid;
  int n = idx >> 4, g = idx & 15;
  float x[16];
  float m = 0.f;
#pragma unroll
  for (int i = 0; i < 16; i++) {
    x[i] = X[(size_t)n * 256 + g * 16 + i];
    m += x[i];
  }
  m *= (1.f / 16.f);
  float v = 0.f;
#pragma unroll
  for (int i = 0; i < 16; i++) {
    float d_ = x[i] - m;
    v += d_ * d_;
  }
  float r = rsqrtf(v * (1.f / 16.f) + 1e-5f);
#pragma unroll
  for (int i = 0; i < 16; i++) x[i] = (x[i] - m) * r;
  f16* op = &out[(size_t)n * (16 * DOUT) + g * DOUT];
  for (int o = 0; o < DOUT; o++) {
    float ag = 0.f, av = 0.f;
#pragma unroll
    for (int i = 0; i < 16; i++) {
      ag += x[i] * sg[(o * 16 + i) * 16 + g];
      av += x[i] * sv[(o * 16 + i) * 16 + g];
    }
    op[o] = (f16)(fmaxf(ag, 0.f) * av);
  }
}

// standalone GroupNorm (in place)
__global__ __launch_bounds__(256) void gn_kernel(float* __restrict__ X) {
  int idx = blockIdx.x * 256 + threadIdx.x;
  int n = idx >> 4, g = idx & 15;
  float x[16];
  float m = 0.f;
#pragma unroll
  for (int i = 0; i < 16; i++) {
    x[i] = X[(size_t)n * 256 + g * 16 + i];
    m += x[i];
  }
  m *= (1.f / 16.f);
  float v = 0.f;
#pragma unroll
  for (int i = 0; i < 16; i++) {
    float d_ = x[i] - m;
    v += d_ * d_;
  }
  float r = rsqrtf(v * (1.f / 16.f) + 1e-5f);
#pragma unroll
  for (int i = 0; i < 16; i++) X[(size_t)n * 256 + g * 16 + i] = (x[i] - m) * r;
}

// ---------------- attention ----------------
__global__ __launch_bounds__(256) void att_graph_kernel(
    const float* __restrict__ xv0, const float* __restrict__ k_w,
    const float* __restrict__ v_w, const int* __restrict__ goff,
    float* __restrict__ h_att, float* __restrict__ xk_sum) {
  __shared__ float skw[8192];
  __shared__ float svw[8192];
  __shared__ float hatt[8192];
  __shared__ float kx[512], vx[512], ks[512], row[256];
  int tid = threadIdx.x, b = blockIdx.x;
  for (int i = tid; i < 8192; i += 256) {
    int o = i >> 4, ii = i & 15;
    skw[ii * 512 + o] = k_w[i];
    svw[ii * 512 + o] = v_w[i];
    hatt[i] = h_att[(size_t)b * 8192 + i];
  }
  for (int i = tid; i < 512; i += 256) ks[i] = 0.f;
  __syncthreads();
  int n0 = goff[b], n1 = goff[b + 1];
  for (int n = n0; n < n1; n++) {
    row[tid] = xv0[(size_t)n * 256 + tid];
    __syncthreads();
#pragma unroll
    for (int half = 0; half < 2; half++) {
      int o = tid + half * 256;
      int g = o >> 5;
      float aK = 0.f, aV = 0.f;
#pragma unroll
      for (int i = 0; i < 16; i++) {
        float xr = row[g * 16 + i];
        aK += xr * skw[i * 512 + o];
        aV += xr * svw[i * 512 + o];
      }
      float ek = expf(aK * 0.25f);
      kx[o] = ek;
      vx[o] = aV;
      ks[o] += ek;
    }
    __syncthreads();
#pragma unroll
    for (int rep = 0; rep < 32; rep++) {
      int id = tid + rep * 256;
      int head = id >> 8, h = (id >> 4) & 15, vv_ = id & 15;
      hatt[id] += kx[head * 16 + h] * vx[head * 16 + vv_];
    }
    __syncthreads();
  }
  for (int i = tid; i < 8192; i += 256) h_att[(size_t)b * 8192 + i] = hatt[i];
  for (int i = tid; i < 512; i += 256) xk_sum[(size_t)b * 512 + i] = ks[i];
}

__global__ __launch_bounds__(256) void att_out_kernel(
    const float* __restrict__ xv0, const float* __restrict__ q_w,
    const float* __restrict__ xk_sum, const float* __restrict__ h_att,
    const int* __restrict__ batch, f16* __restrict__ out) {
  __shared__ float sqw[8192];
  int tid = threadIdx.x;
  for (int i = tid; i < 8192; i += 256) {
    int g = i >> 9, oo = (i >> 4) & 31, ii = i & 15;
    sqw[(oo * 16 + ii) * 16 + g] = q_w[i];
  }
  __syncthreads();
  int idx = blockIdx.x * 256 + tid;
  int n = idx >> 5, head = idx & 31;
  int b = batch[n];
  int g = head >> 1, j = head & 1;
  float x[16];
#pragma unroll
  for (int i = 0; i < 16; i++) x[i] = xv0[(size_t)n * 256 + g * 16 + i];
  float q[16];
  float denom = 0.f;
#pragma unroll
  for (int h = 0; h < 16; h++) {
    float a = 0.f;
    int oo = j * 16 + h;
#pragma unroll
    for (int i = 0; i < 16; i++) a += x[i] * sqw[(oo * 16 + i) * 16 + g];
    float e = expf(a * 0.25f);
    q[h] = e;
    denom += e * xk_sum[(size_t)b * 512 + head * 16 + h];
  }
  float inv = 1.f / denom;
  const float* ha = &h_att[((size_t)b * 32 + head) * 256];
#pragma unroll
  for (int v = 0; v < 16; v++) {
    float a = 0.f;
#pragma unroll
    for (int h = 0; h < 16; h++) a += q[h] * ha[h * 16 + v];
    out[(size_t)n * 512 + head * 16 + v] = (f16)(a * inv);
  }
}

__global__ __launch_bounds__(256) void virt_seg_kernel(const float* __restrict__ h_in,
    const int* __restrict__ goff, float* __restrict__ h_virt) {
  int b = blockIdx.x, c = threadIdx.x;
  float acc = h_virt[(size_t)b * 256 + c];
  int n0 = goff[b], n1 = goff[b + 1];
  for (int n = n0; n < n1; n++) acc += h_in[(size_t)n * 256 + c];
  h_virt[(size_t)b * 256 + c] = acc;
}

// ---------------- host driver ----------------

extern "C" void kernel_launch(void* const* d_in, const int* in_sizes, int n_in,
                              void* d_out, int out_size, void* d_ws, size_t ws_size,
                              hipStream_t stream) {
  const int* x_feat = (const int*)d_in[0];
  const int* eidx = (const int*)d_in[1];
  const int* eattr = (const int*)d_in[2];
  const int* batch = (const int*)d_in[3];
  const float* edist = (const float*)d_in[5];
  const float* atom_emb = (const float*)d_in[6];
  const float* bond2d = (const float*)d_in[7];
  const float* gmeans = (const float*)d_in[8];
  const float* gstds = (const float*)d_in[9];
  const float* attn_w = (const float*)d_in[10];
  const float* attn_b = (const float*)d_in[11];
  const float* scale_both = (const float*)d_in[12];
  const float* conv_bond_emb = (const float*)d_in[13];
  const float* conv_pre_w = (const float*)d_in[14];
  const float* conv_gate_w = (const float*)d_in[15];
  const float* conv_val_w = (const float*)d_in[16];
  const float* conv_post_w = (const float*)d_in[17];
  const float* conv_post_b = (const float*)d_in[18];
  const float* conv_scale = (const float*)d_in[19];
  const float* virt_pre_w = (const float*)d_in[20];
  const float* virt_pre_b = (const float*)d_in[21];
  const float* virt_gate_w = (const float*)d_in[22];
  const float* virt_val_w = (const float*)d_in[23];
  const float* virt_post_w = (const float*)d_in[24];
  const float* virt_post_b = (const float*)d_in[25];
  const float* virt_scale = (const float*)d_in[26];
  const float* att_pre_w = (const float*)d_in[27];
  const float* att_pre_b = (const float*)d_in[28];
  const float* att_q_w = (const float*)d_in[29];
  const float* att_k_w = (const float*)d_in[30];
  const float* att_v_w = (const float*)d_in[31];
  const float* att_post_w = (const float*)d_in[32];
  const float* att_post_b = (const float*)d_in[33];
  const float* att_scale = (const float*)d_in[34];
  const float* main_pre_w = (const float*)d_in[35];
  const float* main_pre_b = (const float*)d_in[36];
  const float* main_gate_w = (const float*)d_in[37];
  const float* main_val_w = (const float*)d_in[38];
  const float* main_post_w = (const float*)d_in[39];
  const float* main_post_b = (const float*)d_in[40];

  const int* src = eidx;
  const int* dst = eidx + EE;

  float* ws = (float*)d_ws;
  float* h_in = ws;
  float* h_out = ws + ND;  // doubles as conv scatter accumulator (agg)
  float* x_raw = ws + 2 * ND;
  float* x_out = ws + 3 * ND;
  float* nodeA = ws + 4 * ND;
  f16* hX = (f16*)(ws + 5 * ND);                 // ND halfs
  f16* hE = (f16*)(ws + 5 * ND + ND / 2);        // N*768 halfs
  float* sm = ws + 7 * ND;
  f16* hW = (f16*)sm;                            // 2359296 halfs
  float* h_virt = sm + 1179648;                  // B*256
  float* h_att = h_virt + 65536;                 // B*32*16*16
  float* xk_sum = h_att + 2097152;               // B*512
  float* vt1 = xk_sum + 131072;                  // B*256
  f16* vmid_h = (f16*)(vt1 + 65536);             // B*512 halfs
  float* vout = vt1 + 65536 + 65536;             // B*256
  int* cnt = (int*)(vout + 65536);
  int* deg = cnt + NN;
  int* goff = deg + NN;

  f16* wCpre = hW;
  f16* wCpost = hW + 524288;
  f16* wApre = hW + 1048576;
  f16* wApost = hW + 1179648;
  f16* wMpre = hW + 1441792;
  f16* wMpost = hW + 1572864;
  f16* wVpre = hW + 1966080;
  f16* wVpost = hW + 2097152;

  float* agg = h_out;

  auto cvt = [&](const float* in, f16* out, int n) {
    f2h_kernel<<<n / 4 / 256, 256, 0, stream>>>(in, out, n / 4);
  };

  // weights -> fp16 (once per call)
  cvt(conv_pre_w, wCpre, 524288);
  cvt(conv_post_w, wCpost, 524288);
  cvt(att_pre_w, wApre, 131072);
  cvt(att_post_w, wApost, 262144);
  cvt(main_pre_w, wMpre, 131072);
  cvt(main_post_w, wMpost, 393216);
  cvt(virt_pre_w, wVpre, 131072);
  cvt(virt_post_w, wVpost, 262144);

  // degree + graph offsets
  hipMemsetAsync(cnt, 0, NN * sizeof(int), stream);
  count_deg_kernel<<<EE / 256, 256, 0, stream>>>(dst, cnt, EE);
  clip_deg_kernel<<<NN / 256, 256, 0, stream>>>(cnt, deg, NN);
  goff_kernel<<<(NN + 256) / 256, 256, 0, stream>>>(batch, goff, NN, BB);

  // initial node features
  hipMemsetAsync(x_out, 0, ND * 4, stream);
  edge_feat_kernel<<<EE / 4, 256, 0, stream>>>(eattr, dst, edist, bond2d, gmeans, gstds,
                                               attn_w, attn_b, x_out);
  atom_finish_kernel<<<(int)(ND / 256), 256, 0, stream>>>(x_feat, atom_emb, scale_both, deg,
                                                          x_out, h_in);
  hipMemsetAsync(h_virt, 0, 65536 * 4, stream);
  hipMemsetAsync(h_att, 0, 2097152 * 4, stream);

  const dim3 gN(NN / 128, 2), gB(BB / 128, 2);

  for (int l = 0; l < 2; l++) {
    // ---- ConvMessage ----
    hipMemsetAsync(x_out, 0, ND * 4, stream);
    const float* cur = h_in;
    for (int k = 0; k < 4; k++) {
      if (k == 2) {
        add3_kernel<<<(int)(ND / 256), 256, 0, stream>>>(x_raw, h_in, x_out, ND);
        hipMemsetAsync(x_out, 0, ND * 4, stream);
        cur = x_raw;
      }
      size_t lk = (size_t)(l * 4 + k);
      cvt(cur, hX, (int)ND);
      hgemm_kernel<0><<<gN, 256, 0, stream>>>(hX, wCpre + lk * 65536, nullptr, nullptr,
                                              nullptr, nodeA, 256);
      hipMemsetAsync(agg, 0, ND * 4, stream);
      conv_edge_kernel<<<EE * 16 / 256, 256, 0, stream>>>(
          nodeA, eattr, src, dst, conv_bond_emb + lk * 6144,
          conv_gate_w + lk * 4096, conv_val_w + lk * 4096, agg);
      cvt(agg, hX, (int)ND);
      hgemm_kernel<3><<<gN, 256, 0, stream>>>(hX, wCpost + lk * 65536, conv_post_b + lk * 256,
                                              nullptr, cnt, x_raw, 256);
      cur = x_raw;
      deg_scaled_add_kernel<<<(int)(ND / 256), 256, 0, stream>>>(
          x_out, x_raw, conv_scale + lk * 1024, deg);
    }
    add3_kernel<<<(int)(ND / 256), 256, 0, stream>>>(h_out, h_in, x_out, ND);

    // ---- VirtMessage ----
    virt_seg_kernel<<<BB, 256, 0, stream>>>(h_in, goff, h_virt);
    cvt(h_virt, (f16*)vmid_h, 65536);  // reuse vmid_h region briefly for h_virt fp16
    hgemm_kernel<0><<<gB, 256, 0, stream>>>((f16*)vmid_h, wVpre + (size_t)l * 65536,
                                            virt_pre_b + (size_t)l * 256, nullptr, nullptr,
                                            vt1, 256);
    glb_mid_kernel<32><<<BB * 16 / 256, 256, 0, stream>>>(
        vt1, virt_gate_w + (size_t)l * 8192, virt_val_w + (size_t)l * 8192, vmid_h);
    hgemm_kernel<0><<<gB, 256, 0, stream>>>(vmid_h, wVpost + (size_t)l * 131072,
                                            virt_post_b + (size_t)l * 256, nullptr, nullptr,
                                            vout, 512);
    bcast_add_kernel<<<(int)(ND / 256), 256, 0, stream>>>(
        h_out, vout, virt_scale + (size_t)l * 256, batch);

    // ---- AttMessage ----
    cvt(h_in, hX, (int)ND);
    hgemm_kernel<0><<<gN, 256, 0, stream>>>(hX, wApre + (size_t)l * 65536,
                                            att_pre_b + (size_t)l * 256, nullptr, nullptr,
                                            nodeA, 256);
    gn_kernel<<<NN * 16 / 256, 256, 0, stream>>>(nodeA);
    att_graph_kernel<<<BB, 256, 0, stream>>>(
        nodeA, att_k_w + (size_t)l * 8192, att_v_w + (size_t)l * 8192, goff, h_att, xk_sum);
    att_out_kernel<<<NN * 32 / 256, 256, 0, stream>>>(
        nodeA, att_q_w + (size_t)l * 8192, xk_sum, h_att, batch, hE);
    hgemm_kernel<2><<<gN, 256, 0, stream>>>(hE, wApost + (size_t)l * 131072,
                                            att_post_b + (size_t)l * 256,
                                            att_scale + (size_t)l * 256, nullptr, h_out, 512);

    // ---- main gated block ----
    cvt(h_out, hX, (int)ND);
    hgemm_kernel<0><<<gN, 256, 0, stream>>>(hX, wMpre + (size_t)l * 65536,
                                            main_pre_b + (size_t)l * 256, nullptr, nullptr,
                                            nodeA, 256);
    glb_mid_kernel<48><<<NN * 16 / 256, 256, 0, stream>>>(
        nodeA, main_gate_w + (size_t)l * 12288, main_val_w + (size_t)l * 12288, hE);
    float* hdst = (l == 1) ? (float*)d_out : h_in;
    hgemm_kernel<0><<<gN, 256, 0, stream>>>(hE, wMpost + (size_t)l * 196608,
                                            main_post_b + (size_t)l * 256, nullptr, nullptr,
                                            hdst, 768);
  }
}

// Round 4
// 2426.932 us; speedup vs baseline: 2.8725x; 2.8725x over previous
//
#include <hip/hip_runtime.h>
#include <cstdint>
#include <cstddef>

#define NN 16384
#define EE 49152
#define BB 256
// D=256, G=16, 16 channels per group, HD=16

typedef _Float16 f16;
typedef _Float16 half8 __attribute__((ext_vector_type(8)));
typedef _Float16 half4v __attribute__((ext_vector_type(4)));
typedef float floatx4 __attribute__((ext_vector_type(4)));

static constexpr size_t ND = (size_t)NN * 256;

// ---------------- setup kernels ----------------

__global__ __launch_bounds__(256) void count_deg_kernel(const int* __restrict__ dst, int* __restrict__ cnt, int e) {
  int i = blockIdx.x * 256 + threadIdx.x;
  if (i < e) atomicAdd(&cnt[dst[i]], 1);
}
__global__ __launch_bounds__(256) void clip_deg_kernel(const int* __restrict__ cnt, int* __restrict__ deg, int n) {
  int i = blockIdx.x * 256 + threadIdx.x;
  if (i < n) { int v = cnt[i] - 1; deg[i] = v < 0 ? 0 : (v > 3 ? 3 : v); }
}
__global__ __launch_bounds__(256) void goff_kernel(const int* __restrict__ batch, int* __restrict__ goff, int n, int b) {
  int i = blockIdx.x * 256 + threadIdx.x;
  if (i > n) return;
  int cur = (i < n) ? batch[i] : b;
  int prev = (i == 0) ? -1 : batch[i - 1];
  for (int x = prev + 1; x <= cur; x++) goff[x] = i;
}
// exclusive scan of cnt[16384] -> off[16385], single block of 256, 64 elems/thread
__global__ __launch_bounds__(256) void scan_off_kernel(const int* __restrict__ cnt, int* __restrict__ off) {
  __shared__ int part[256];
  int tid = threadIdx.x;
  int base = tid * 64;
  int s = 0;
  for (int i = 0; i < 64; i++) s += cnt[base + i];
  part[tid] = s;
  __syncthreads();
  for (int o = 1; o < 256; o <<= 1) {
    int t = (tid >= o) ? part[tid - o] : 0;
    __syncthreads();
    part[tid] += t;
    __syncthreads();
  }
  int run = (tid == 0) ? 0 : part[tid - 1];
  for (int i = 0; i < 64; i++) {
    off[base + i] = run;
    run += cnt[base + i];
  }
  if (tid == 255) off[NN] = run;
}
__global__ __launch_bounds__(256) void copy_i_kernel(const int* __restrict__ a, int* __restrict__ b, int n) {
  int i = blockIdx.x * 256 + threadIdx.x;
  if (i < n) b[i] = a[i];
}
__global__ __launch_bounds__(256) void fill_elist_kernel(const int* __restrict__ dst,
    int* __restrict__ cursor, int* __restrict__ elist, int e) {
  int i = blockIdx.x * 256 + threadIdx.x;
  if (i < e) {
    int p = atomicAdd(&cursor[dst[i]], 1);
    elist[p] = i;
  }
}
__global__ __launch_bounds__(256) void add3_kernel(float* __restrict__ dst,
    const float* __restrict__ a, const float* __restrict__ b, size_t n) {
  size_t i = (size_t)blockIdx.x * 256 + threadIdx.x;
  if (i < n) dst[i] = a[i] + b[i];
}
__global__ __launch_bounds__(256) void add3_both_kernel(float* __restrict__ dst, f16* __restrict__ dstH,
    const float* __restrict__ a, const float* __restrict__ b, size_t n) {
  size_t i = (size_t)blockIdx.x * 256 + threadIdx.x;
  if (i < n) { float v = a[i] + b[i]; dst[i] = v; dstH[i] = (f16)v; }
}
__global__ __launch_bounds__(256) void bcast_add_kernel(float* __restrict__ ho,
    const float* __restrict__ vo, const float* __restrict__ vs, const int* __restrict__ batch) {
  size_t i = (size_t)blockIdx.x * 256 + threadIdx.x;
  int n = (int)(i >> 8), c = (int)(i & 255);
  ho[i] += expf(vs[c]) * vo[(size_t)batch[n] * 256 + c];
}
__global__ __launch_bounds__(256) void f2h_kernel(const float* __restrict__ in, f16* __restrict__ out, int n4) {
  int i = blockIdx.x * 256 + threadIdx.x;
  if (i >= n4) return;
  float4 v = reinterpret_cast<const float4*>(in)[i];
  half4v o;
  o.x = (f16)v.x; o.y = (f16)v.y; o.z = (f16)v.z; o.w = (f16)v.w;
  reinterpret_cast<half4v*>(out)[i] = o;
}

// ---------------- segment reduce: out[n] = sum over CSR edge list of msg[e] ----------------
template <typename OUT>
__global__ __launch_bounds__(256) void seg_reduce_kernel(const f16* __restrict__ msg,
    const int* __restrict__ off, const int* __restrict__ elist, OUT* __restrict__ out) {
  int n = blockIdx.x, c = threadIdx.x;
  int j0 = off[n], j1 = off[n + 1];
  float acc = 0.f;
  for (int j = j0; j < j1; j++) {
    int e = elist[j];
    acc += (float)msg[(size_t)e * 256 + c];
  }
  out[(size_t)n * 256 + c] = (OUT)acc;
}

// ---------------- initial edge / node features ----------------

// wave per edge; lane handles channels [lane*4, lane*4+4); dense fp16 message out
__global__ __launch_bounds__(256) void edge_feat_kernel(
    const int* __restrict__ eattr, const float* __restrict__ edist,
    const float* __restrict__ bond2d, const float* __restrict__ gmeans,
    const float* __restrict__ gstds, const float* __restrict__ attn_w,
    const float* __restrict__ attn_b, f16* __restrict__ msg) {
  int lane = threadIdx.x & 63;
  int e = blockIdx.x * 4 + (threadIdx.x >> 6);
  if (e >= EE) return;
  int a0 = eattr[e * 3 + 0], a1 = eattr[e * 3 + 1], a2 = eattr[e * 3 + 2];
  float dist = edist[e];
  const float SQ2PI = sqrtf(2.0f * 3.14159f);
  int c0 = lane * 4;
  float4 b0 = *reinterpret_cast<const float4*>(&bond2d[a0 * 256 + c0]);
  float4 b1 = *reinterpret_cast<const float4*>(&bond2d[2048 + a1 * 256 + c0]);
  float4 b2 = *reinterpret_cast<const float4*>(&bond2d[4096 + a2 * 256 + c0]);
  float4 gm = *reinterpret_cast<const float4*>(&gmeans[c0]);
  float4 gs = *reinterpret_cast<const float4*>(&gstds[c0]);
  float4 w2 = *reinterpret_cast<const float4*>(&attn_w[c0]);
  float4 w3 = *reinterpret_cast<const float4*>(&attn_w[256 + c0]);
  float h2[4], h3[4];
  float part = 0.f;
#pragma unroll
  for (int i = 0; i < 4; i++) {
    h2[i] = (&b0.x)[i] + (&b1.x)[i] + (&b2.x)[i];
    float sd = fabsf((&gs.x)[i]) + 0.01f;
    float df = (dist - (&gm.x)[i]) / sd;
    h3[i] = expf(-0.5f * df * df) / (SQ2PI * sd);
    part += (&w2.x)[i] * h2[i] + (&w3.x)[i] * h3[i];
  }
#pragma unroll
  for (int off = 32; off > 0; off >>= 1) part += __shfl_xor(part, off);
  float wg = 1.f / (1.f + expf(-(part + attn_b[0])));
  half4v o;
#pragma unroll
  for (int i = 0; i < 4; i++) o[i] = (f16)(wg * h2[i] + (1.f - wg) * h3[i]);
  *reinterpret_cast<half4v*>(&msg[(size_t)e * 256 + c0]) = o;
}

__global__ __launch_bounds__(256) void atom_finish_kernel(
    const int* __restrict__ xf, const float* __restrict__ emb,
    const float* __restrict__ scale_both, const int* __restrict__ deg,
    const float* __restrict__ tmp, float* __restrict__ h_in, f16* __restrict__ h_inH) {
  size_t i = (size_t)blockIdx.x * 256 + threadIdx.x;
  int n = (int)(i >> 8), c = (int)(i & 255);
  float acc = 0.f;
#pragma unroll
  for (int f = 0; f < 9; f++) {
    int v = xf[n * 9 + f];
    acc += emb[((size_t)(f * 128 + v)) * 256 + c];
  }
  float r = acc + expf(scale_both[deg[n] * 256 + c]) * tmp[i];
  h_in[i] = r;
  h_inH[i] = (f16)r;
}

// ---------------- fp16 MFMA GEMM: C[M,256](f32) = A[M,K](f16) @ W[256,K](f16)^T ----------------
// MODE 0: C = acc (+bias);   MODE 2: C += expf(scale[col]) * (acc + bias[col]);
// MODE 4: v = acc + cnt[row]*bias[col]; C = v; C2 += expf(scale[deg[row]*256+col]) * v
// All modes: if Cf non-null, Cf = (f16) of final C value.
template <int MODE>
__global__ __launch_bounds__(256) void hgemm_kernel(
    const f16* __restrict__ A, const f16* __restrict__ W,
    const float* __restrict__ bias, const float* __restrict__ scale,
    const int* __restrict__ cnt, const int* __restrict__ deg,
    float* __restrict__ C, float* __restrict__ C2, f16* __restrict__ Cf, int K) {
  __shared__ f16 Ah[128 * 40];
  __shared__ f16 Wh[128 * 40];
  const int tid = threadIdx.x;
  const int row0 = blockIdx.x * 128, col0 = blockIdx.y * 128;
  const int lane = tid & 63;
  const int wave = tid >> 6;
  const int wr = (wave >> 1) * 64, wc = (wave & 1) * 64;
  const floatx4 fz = {0.f, 0.f, 0.f, 0.f};
  floatx4 acc[4][4];
#pragma unroll
  for (int m = 0; m < 4; m++)
#pragma unroll
    for (int n = 0; n < 4; n++) acc[m][n] = fz;
  const int q0 = tid * 2;
  const int r0s = q0 >> 2, p0s = q0 & 3;
  const int r1s = (q0 + 1) >> 2, p1s = (q0 + 1) & 3;
  const int kb = (lane >> 4) * 8;
  const int fr = lane & 15;
  for (int k0 = 0; k0 < K; k0 += 32) {
    uint4 a0 = *reinterpret_cast<const uint4*>(&A[(size_t)(row0 + r0s) * K + k0 + p0s * 8]);
    uint4 a1 = *reinterpret_cast<const uint4*>(&A[(size_t)(row0 + r1s) * K + k0 + p1s * 8]);
    uint4 w0 = *reinterpret_cast<const uint4*>(&W[(size_t)(col0 + r0s) * K + k0 + p0s * 8]);
    uint4 w1 = *reinterpret_cast<const uint4*>(&W[(size_t)(col0 + r1s) * K + k0 + p1s * 8]);
    *reinterpret_cast<uint4*>(&Ah[r0s * 40 + p0s * 8]) = a0;
    *reinterpret_cast<uint4*>(&Ah[r1s * 40 + p1s * 8]) = a1;
    *reinterpret_cast<uint4*>(&Wh[r0s * 40 + p0s * 8]) = w0;
    *reinterpret_cast<uint4*>(&Wh[r1s * 40 + p1s * 8]) = w1;
    __syncthreads();
    half8 af[4], wf[4];
#pragma unroll
    for (int m = 0; m < 4; m++)
      af[m] = *reinterpret_cast<const half8*>(&Ah[(wr + m * 16 + fr) * 40 + kb]);
#pragma unroll
    for (int n = 0; n < 4; n++)
      wf[n] = *reinterpret_cast<const half8*>(&Wh[(wc + n * 16 + fr) * 40 + kb]);
#pragma unroll
    for (int m = 0; m < 4; m++)
#pragma unroll
      for (int n = 0; n < 4; n++)
        acc[m][n] = __builtin_amdgcn_mfma_f32_16x16x32_f16(af[m], wf[n], acc[m][n], 0, 0, 0);
    __syncthreads();
  }
  const int rl4 = (lane >> 4) * 4, cl = lane & 15;
#pragma unroll
  for (int m = 0; m < 4; m++) {
#pragma unroll
    for (int i = 0; i < 4; i++) {
      int row = row0 + wr + m * 16 + rl4 + i;
      float cb = (MODE == 4) ? (float)cnt[row] : 1.f;
      int dg = (MODE == 4) ? deg[row] : 0;
#pragma unroll
      for (int n = 0; n < 4; n++) {
        int col = col0 + wc + n * 16 + cl;
        float v = acc[m][n][i];
        size_t oi = (size_t)row * 256 + col;
        if (MODE == 4) {
          v += cb * bias[col];
          C[oi] = v;
          C2[oi] += expf(scale[dg * 256 + col]) * v;
          if (Cf) Cf[oi] = (f16)v;
        } else if (MODE == 2) {
          v += bias[col];
          float nv = C[oi] + expf(scale[col]) * v;
          C[oi] = nv;
          if (Cf) Cf[oi] = (f16)nv;
        } else {
          if (bias) v += bias[col];
          C[oi] = v;
          if (Cf) Cf[oi] = (f16)v;
        }
      }
    }
  }
}

// ---------------- conv edge: gather + bond + GN + glin(gate/val) + product, dense fp16 out ----------------
__global__ __launch_bounds__(256) void conv_edge_kernel(
    const float* __restrict__ xp, const int* __restrict__ eattr,
    const int* __restrict__ src, const int* __restrict__ dst,
    const float* __restrict__ bond_emb, const float* __restrict__ gate_w,
    const float* __restrict__ val_w, f16* __restrict__ msg) {
  __shared__ float sb[6144];  // [3][8][256]
  __shared__ float sg[4096];  // transposed [o][i][g]
  __shared__ float sv[4096];
  int tid = threadIdx.x;
  for (int i = tid; i < 6144; i += 256) sb[i] = bond_emb[i];
  for (int i = tid; i < 4096; i += 256) {
    int g = i >> 8, o = (i >> 4) & 15, ii = i & 15;
    int t = (o * 16 + ii) * 16 + g;
    sg[t] = gate_w[i];
    sv[t] = val_w[i];
  }
  __syncthreads();
  int idx = blockIdx.x * 256 + tid;
  int e = idx >> 4, g = idx & 15;
  int a0 = eattr[e * 3 + 0], a1 = eattr[e * 3 + 1], a2 = eattr[e * 3 + 2];
  int d = dst[e], s = src[e];
  const float* xd = &xp[(size_t)d * 256 + g * 16];
  const float* xs = &xp[(size_t)s * 256 + g * 16];
  float xg[16], xv[16];
  float mg = 0.f, mv = 0.f;
#pragma unroll
  for (int i = 0; i < 16; i++) {
    float bo = sb[a0 * 256 + g * 16 + i] + sb[2048 + a1 * 256 + g * 16 + i] + sb[4096 + a2 * 256 + g * 16 + i];
    xg[i] = xd[i] + bo;
    xv[i] = xs[i] + bo;
    mg += xg[i];
    mv += xv[i];
  }
  mg *= (1.f / 16.f);
  mv *= (1.f / 16.f);
  float vg = 0.f, vv = 0.f;
#pragma unroll
  for (int i = 0; i < 16; i++) {
    float dg_ = xg[i] - mg, dv_ = xv[i] - mv;
    vg += dg_ * dg_;
    vv += dv_ * dv_;
  }
  float rg = rsqrtf(vg * (1.f / 16.f) + 1e-5f);
  float rv = rsqrtf(vv * (1.f / 16.f) + 1e-5f);
#pragma unroll
  for (int i = 0; i < 16; i++) {
    xg[i] = (xg[i] - mg) * rg;
    xv[i] = (xv[i] - mv) * rv;
  }
  f16 res[16];
#pragma unroll
  for (int o = 0; o < 16; o++) {
    float ag = 0.f, av = 0.f;
#pragma unroll
    for (int i = 0; i < 16; i++) {
      ag += xg[i] * sg[(o * 16 + i) * 16 + g];
      av += xv[i] * sv[(o * 16 + i) * 16 + g];
    }
    res[o] = (f16)(fmaxf(ag, 0.f) * av);
  }
  uint4* op = reinterpret_cast<uint4*>(&msg[(size_t)e * 256 + g * 16]);
  op[0] = reinterpret_cast<const uint4*>(res)[0];
  op[1] = reinterpret_cast<const uint4*>(res)[1];
}

// ---------------- glb middle: GN + glin + relu*mul, fp16 output ----------------
template <int DOUT>
__global__ __launch_bounds__(256) void glb_mid_kernel(
    const float* __restrict__ X, const float* __restrict__ gate_w,
    const float* __restrict__ val_w, f16* __restrict__ out) {
  __shared__ float sg[16 * DOUT * 16];
  __shared__ float sv[16 * DOUT * 16];
  int tid = threadIdx.x;
  for (int i = tid; i < 16 * DOUT * 16; i += 256) {
    int g = i / (DOUT * 16), rem = i % (DOUT * 16), o = rem >> 4, ii = rem & 15;
    int t = (o * 16 + ii) * 16 + g;
    sg[t] = gate_w[i];
    sv[t] = val_w[i];
  }
  __syncthreads();
  int idx = blockIdx.x * 256 + tid;
  int n = idx >> 4, g = idx & 15;
  float x[16];
  float m = 0.f;
#pragma unroll
  for (int i = 0; i < 16; i++) {
    x[i] = X[(size_t)n * 256 + g * 16 + i];
    m += x[i];
  }
  m *= (1.f / 16.f);
  float v = 0.f;
#pragma unroll
  for (int i = 0; i < 16; i++) {
    float d_ = x[i] - m;
    v += d_ * d_;
  }
  float r = rsqrtf(v * (1.f / 16.f) + 1e-5f);
#pragma unroll
  for (int i = 0; i < 16; i++) x[i] = (x[i] - m) * r;
  f16* op = &out[(size_t)n * (16 * DOUT) + g * DOUT];
  for (int o = 0; o < DOUT; o++) {
    float ag = 0.f, av = 0.f;
#pragma unroll
    for (int i = 0; i < 16; i++) {
      ag += x[i] * sg[(o * 16 + i) * 16 + g];
      av += x[i] * sv[(o * 16 + i) * 16 + g];
    }
    op[o] = (f16)(fmaxf(ag, 0.f) * av);
  }
}

// standalone GroupNorm (in place)
__global__ __launch_bounds__(256) void gn_kernel(float* __restrict__ X) {
  int idx = blockIdx.x * 256 + threadIdx.x;
  int n = idx >> 4, g = idx & 15;
  float x[16];
  float m = 0.f;
#pragma unroll
  for (int i = 0; i < 16; i++) {
    x[i] = X[(size_t)n * 256 + g * 16 + i];
    m += x[i];
  }
  m *= (1.f / 16.f);
  float v = 0.f;
#pragma unroll
  for (int i = 0; i < 16; i++) {
    float d_ = x[i] - m;
    v += d_ * d_;
  }
  float r = rsqrtf(v * (1.f / 16.f) + 1e-5f);
#pragma unroll
  for (int i = 0; i < 16; i++) X[(size_t)n * 256 + g * 16 + i] = (x[i] - m) * r;
}

// ---------------- attention ----------------
__global__ __launch_bounds__(256) void att_graph_kernel(
    const float* __restrict__ xv0, const float* __restrict__ k_w,
    const float* __restrict__ v_w, const int* __restrict__ goff,
    float* __restrict__ h_att, float* __restrict__ xk_sum) {
  __shared__ float skw[8192];
  __shared__ float svw[8192];
  __shared__ float hatt[8192];
  __shared__ float kx[512], vx[512], ks[512], row[256];
  int tid = threadIdx.x, b = blockIdx.x;
  for (int i = tid; i < 8192; i += 256) {
    int o = i >> 4, ii = i & 15;
    skw[ii * 512 + o] = k_w[i];
    svw[ii * 512 + o] = v_w[i];
    hatt[i] = h_att[(size_t)b * 8192 + i];
  }
  for (int i = tid; i < 512; i += 256) ks[i] = 0.f;
  __syncthreads();
  int n0 = goff[b], n1 = goff[b + 1];
  for (int n = n0; n < n1; n++) {
    row[tid] = xv0[(size_t)n * 256 + tid];
    __syncthreads();
#pragma unroll
    for (int half = 0; half < 2; half++) {
      int o = tid + half * 256;
      int g = o >> 5;
      float aK = 0.f, aV = 0.f;
#pragma unroll
      for (int i = 0; i < 16; i++) {
        float xr = row[g * 16 + i];
        aK += xr * skw[i * 512 + o];
        aV += xr * svw[i * 512 + o];
      }
      float ek = expf(aK * 0.25f);
      kx[o] = ek;
      vx[o] = aV;
      ks[o] += ek;
    }
    __syncthreads();
#pragma unroll
    for (int rep = 0; rep < 32; rep++) {
      int id = tid + rep * 256;
      int head = id >> 8, h = (id >> 4) & 15, vv_ = id & 15;
      hatt[id] += kx[head * 16 + h] * vx[head * 16 + vv_];
    }
    __syncthreads();
  }
  for (int i = tid; i < 8192; i += 256) h_att[(size_t)b * 8192 + i] = hatt[i];
  for (int i = tid; i < 512; i += 256) xk_sum[(size_t)b * 512 + i] = ks[i];
}

__global__ __launch_bounds__(256) void att_out_kernel(
    const float* __restrict__ xv0, const float* __restrict__ q_w,
    const float* __restrict__ xk_sum, const float* __restrict__ h_att,
    const int* __restrict__ batch, f16* __restrict__ out) {
  __shared__ float sqw[8192];
  int tid = threadIdx.x;
  for (int i = tid; i < 8192; i += 256) {
    int g = i >> 9, oo = (i >> 4) & 31, ii = i & 15;
    sqw[(oo * 16 + ii) * 16 + g] = q_w[i];
  }
  __syncthreads();
  int idx = blockIdx.x * 256 + tid;
  int n = idx >> 5, head = idx & 31;
  int b = batch[n];
  int g = head >> 1, j = head & 1;
  float x[16];
#pragma unroll
  for (int i = 0; i < 16; i++) x[i] = xv0[(size_t)n * 256 + g * 16 + i];
  float q[16];
  float denom = 0.f;
#pragma unroll
  for (int h = 0; h < 16; h++) {
    float a = 0.f;
    int oo = j * 16 + h;
#pragma unroll
    for (int i = 0; i < 16; i++) a += x[i] * sqw[(oo * 16 + i) * 16 + g];
    float e = expf(a * 0.25f);
    q[h] = e;
    denom += e * xk_sum[(size_t)b * 512 + head * 16 + h];
  }
  float inv = 1.f / denom;
  const float* ha = &h_att[((size_t)b * 32 + head) * 256];
#pragma unroll
  for (int v = 0; v < 16; v++) {
    float a = 0.f;
#pragma unroll
    for (int h = 0; h < 16; h++) a += q[h] * ha[h * 16 + v];
    out[(size_t)n * 512 + head * 16 + v] = (f16)(a * inv);
  }
}

__global__ __launch_bounds__(256) void virt_seg_kernel(const float* __restrict__ h_in,
    const int* __restrict__ goff, float* __restrict__ h_virt) {
  int b = blockIdx.x, c = threadIdx.x;
  float acc = h_virt[(size_t)b * 256 + c];
  int n0 = goff[b], n1 = goff[b + 1];
  for (int n = n0; n < n1; n++) acc += h_in[(size_t)n * 256 + c];
  h_virt[(size_t)b * 256 + c] = acc;
}

// ---------------- host driver ----------------

extern "C" void kernel_launch(void* const* d_in, const int* in_sizes, int n_in,
                              void* d_out, int out_size, void* d_ws, size_t ws_size,
                              hipStream_t stream) {
  const int* x_feat = (const int*)d_in[0];
  const int* eidx = (const int*)d_in[1];
  const int* eattr = (const int*)d_in[2];
  const int* batch = (const int*)d_in[3];
  const float* edist = (const float*)d_in[5];
  const float* atom_emb = (const float*)d_in[6];
  const float* bond2d = (const float*)d_in[7];
  const float* gmeans = (const float*)d_in[8];
  const float* gstds = (const float*)d_in[9];
  const float* attn_w = (const float*)d_in[10];
  const float* attn_b = (const float*)d_in[11];
  const float* scale_both = (const float*)d_in[12];
  const float* conv_bond_emb = (const float*)d_in[13];
  const float* conv_pre_w = (const float*)d_in[14];
  const float* conv_gate_w = (const float*)d_in[15];
  const float* conv_val_w = (const float*)d_in[16];
  const float* conv_post_w = (const float*)d_in[17];
  const float* conv_post_b = (const float*)d_in[18];
  const float* conv_scale = (const float*)d_in[19];
  const float* virt_pre_w = (const float*)d_in[20];
  const float* virt_pre_b = (const float*)d_in[21];
  const float* virt_gate_w = (const float*)d_in[22];
  const float* virt_val_w = (const float*)d_in[23];
  const float* virt_post_w = (const float*)d_in[24];
  const float* virt_post_b = (const float*)d_in[25];
  const float* virt_scale = (const float*)d_in[26];
  const float* att_pre_w = (const float*)d_in[27];
  const float* att_pre_b = (const float*)d_in[28];
  const float* att_q_w = (const float*)d_in[29];
  const float* att_k_w = (const float*)d_in[30];
  const float* att_v_w = (const float*)d_in[31];
  const float* att_post_w = (const float*)d_in[32];
  const float* att_post_b = (const float*)d_in[33];
  const float* att_scale = (const float*)d_in[34];
  const float* main_pre_w = (const float*)d_in[35];
  const float* main_pre_b = (const float*)d_in[36];
  const float* main_gate_w = (const float*)d_in[37];
  const float* main_val_w = (const float*)d_in[38];
  const float* main_post_w = (const float*)d_in[39];
  const float* main_post_b = (const float*)d_in[40];

  const int* src = eidx;
  const int* dst = eidx + EE;

  float* ws = (float*)d_ws;
  float* h_in = ws;
  float* h_out = ws + ND;
  float* x_raw = ws + 2 * ND;
  float* x_out = ws + 3 * ND;
  float* nodeA = ws + 4 * ND;
  f16* h_inH = (f16*)(ws + 5 * ND);          // ND halfs
  f16* xrawH = (f16*)(ws + 5 * ND + ND / 2); // ND halfs
  f16* hTmp = (f16*)(ws + 6 * ND);           // ND halfs (aggH / houtH, time-shared)
  f16* msgH = (f16*)(ws + 6 * ND + ND / 2);  // 3*ND halfs (edge msgs / att_out / main mid)
  float* sm = ws + 8 * ND;
  f16* hW = (f16*)sm;                        // 2359296 halfs = 1179648 floats
  float* h_virt = sm + 1179648;              // B*256
  float* h_att = h_virt + 65536;             // B*32*16*16
  float* xk_sum = h_att + 2097152;           // B*512
  float* vt1 = xk_sum + 131072;              // B*256
  float* vout = vt1 + 65536;                 // B*256
  f16* vmidH = (f16*)(vout + 65536);         // B*512 halfs
  f16* virtH = vmidH + 131072;               // B*256 halfs
  int* cnt = (int*)(virtH + 65536);          // N
  int* deg = cnt + NN;                       // N
  int* goff = deg + NN;                      // B+1
  int* off = goff + BB + 1;                  // N+1
  int* cursor = off + NN + 1;                // N
  int* elist = cursor + NN;                  // E

  f16* wCpre = hW;
  f16* wCpost = hW + 524288;
  f16* wApre = hW + 1048576;
  f16* wApost = hW + 1179648;
  f16* wMpre = hW + 1441792;
  f16* wMpost = hW + 1572864;
  f16* wVpre = hW + 1966080;
  f16* wVpost = hW + 2097152;

  auto cvt = [&](const float* in, f16* out, int n) {
    f2h_kernel<<<n / 4 / 256, 256, 0, stream>>>(in, out, n / 4);
  };

  // weights -> fp16
  cvt(conv_pre_w, wCpre, 524288);
  cvt(conv_post_w, wCpost, 524288);
  cvt(att_pre_w, wApre, 131072);
  cvt(att_post_w, wApost, 262144);
  cvt(main_pre_w, wMpre, 131072);
  cvt(main_post_w, wMpost, 393216);
  cvt(virt_pre_w, wVpre, 131072);
  cvt(virt_post_w, wVpost, 262144);

  // degree + graph offsets + CSR (edges grouped by dst)
  (void)hipMemsetAsync(cnt, 0, NN * sizeof(int), stream);
  count_deg_kernel<<<EE / 256, 256, 0, stream>>>(dst, cnt, EE);
  clip_deg_kernel<<<NN / 256, 256, 0, stream>>>(cnt, deg, NN);
  goff_kernel<<<(NN + 256) / 256, 256, 0, stream>>>(batch, goff, NN, BB);
  scan_off_kernel<<<1, 256, 0, stream>>>(cnt, off);
  copy_i_kernel<<<NN / 256, 256, 0, stream>>>(off, cursor, NN);
  fill_elist_kernel<<<EE / 256, 256, 0, stream>>>(dst, cursor, elist, EE);

  // initial node features (dense edge msgs -> CSR reduce -> finish)
  edge_feat_kernel<<<EE / 4, 256, 0, stream>>>(eattr, edist, bond2d, gmeans, gstds,
                                               attn_w, attn_b, msgH);
  seg_reduce_kernel<float><<<NN, 256, 0, stream>>>(msgH, off, elist, x_out);
  atom_finish_kernel<<<(int)(ND / 256), 256, 0, stream>>>(x_feat, atom_emb, scale_both, deg,
                                                          x_out, h_in, h_inH);
  (void)hipMemsetAsync(h_virt, 0, 65536 * 4, stream);
  (void)hipMemsetAsync(h_att, 0, 2097152 * 4, stream);

  const dim3 gN(NN / 128, 2), gB(BB / 128, 2);

  for (int l = 0; l < 2; l++) {
    // ---- ConvMessage ----
    (void)hipMemsetAsync(x_out, 0, ND * 4, stream);
    const f16* curH = h_inH;
    for (int k = 0; k < 4; k++) {
      if (k == 2) {
        add3_both_kernel<<<(int)(ND / 256), 256, 0, stream>>>(x_raw, xrawH, h_in, x_out, ND);
        (void)hipMemsetAsync(x_out, 0, ND * 4, stream);
        curH = xrawH;
      }
      size_t lk = (size_t)(l * 4 + k);
      hgemm_kernel<0><<<gN, 256, 0, stream>>>(curH, wCpre + lk * 65536, nullptr, nullptr,
                                              nullptr, nullptr, nodeA, nullptr, nullptr, 256);
      conv_edge_kernel<<<EE * 16 / 256, 256, 0, stream>>>(
          nodeA, eattr, src, dst, conv_bond_emb + lk * 6144,
          conv_gate_w + lk * 4096, conv_val_w + lk * 4096, msgH);
      seg_reduce_kernel<f16><<<NN, 256, 0, stream>>>(msgH, off, elist, hTmp);
      hgemm_kernel<4><<<gN, 256, 0, stream>>>(hTmp, wCpost + lk * 65536,
                                              conv_post_b + lk * 256, conv_scale + lk * 1024,
                                              cnt, deg, x_raw, x_out, xrawH, 256);
      curH = xrawH;
    }
    add3_kernel<<<(int)(ND / 256), 256, 0, stream>>>(h_out, h_in, x_out, ND);

    // ---- VirtMessage ----
    virt_seg_kernel<<<BB, 256, 0, stream>>>(h_in, goff, h_virt);
    cvt(h_virt, virtH, 65536);
    hgemm_kernel<0><<<gB, 256, 0, stream>>>(virtH, wVpre + (size_t)l * 65536,
                                            virt_pre_b + (size_t)l * 256, nullptr, nullptr,
                                            nullptr, vt1, nullptr, nullptr, 256);
    glb_mid_kernel<32><<<BB * 16 / 256, 256, 0, stream>>>(
        vt1, virt_gate_w + (size_t)l * 8192, virt_val_w + (size_t)l * 8192, vmidH);
    hgemm_kernel<0><<<gB, 256, 0, stream>>>(vmidH, wVpost + (size_t)l * 131072,
                                            virt_post_b + (size_t)l * 256, nullptr, nullptr,
                                            nullptr, vout, nullptr, nullptr, 512);
    bcast_add_kernel<<<(int)(ND / 256), 256, 0, stream>>>(
        h_out, vout, virt_scale + (size_t)l * 256, batch);

    // ---- AttMessage ----
    hgemm_kernel<0><<<gN, 256, 0, stream>>>(h_inH, wApre + (size_t)l * 65536,
                                            att_pre_b + (size_t)l * 256, nullptr, nullptr,
                                            nullptr, nodeA, nullptr, nullptr, 256);
    gn_kernel<<<NN * 16 / 256, 256, 0, stream>>>(nodeA);
    att_graph_kernel<<<BB, 256, 0, stream>>>(
        nodeA, att_k_w + (size_t)l * 8192, att_v_w + (size_t)l * 8192, goff, h_att, xk_sum);
    att_out_kernel<<<NN * 32 / 256, 256, 0, stream>>>(
        nodeA, att_q_w + (size_t)l * 8192, xk_sum, h_att, batch, msgH);
    hgemm_kernel<2><<<gN, 256, 0, stream>>>(msgH, wApost + (size_t)l * 131072,
                                            att_post_b + (size_t)l * 256,
                                            att_scale + (size_t)l * 256, nullptr, nullptr,
                                            h_out, nullptr, hTmp, 512);

    // ---- main gated block ----
    hgemm_kernel<0><<<gN, 256, 0, stream>>>(hTmp, wMpre + (size_t)l * 65536,
                                            main_pre_b + (size_t)l * 256, nullptr, nullptr,
                                            nullptr, nodeA, nullptr, nullptr, 256);
    glb_mid_kernel<48><<<NN * 16 / 256, 256, 0, stream>>>(
        nodeA, main_gate_w + (size_t)l * 12288, main_val_w + (size_t)l * 12288, msgH);
    float* hdst = (l == 1) ? (float*)d_out : h_in;
    f16* hdstH = (l == 1) ? nullptr : h_inH;
    hgemm_kernel<0><<<gN, 256, 0, stream>>>(msgH, wMpost + (size_t)l * 196608,
                                            main_post_b + (size_t)l * 256, nullptr, nullptr,
                                            nullptr, hdst, nullptr, hdstH, 768);
  }
}

// Round 5
// 2099.602 us; speedup vs baseline: 3.3204x; 1.1559x over previous
//
#include <hip/hip_runtime.h>
#include <cstdint>
#include <cstddef>

#define NN 16384
#define EE 49152
#define BB 256
// D=256, G=16, 16 channels per group, HD=16

typedef _Float16 f16;
typedef _Float16 half8 __attribute__((ext_vector_type(8)));
typedef _Float16 half4v __attribute__((ext_vector_type(4)));
typedef float floatx4 __attribute__((ext_vector_type(4)));

static constexpr size_t ND = (size_t)NN * 256;

// ---------------- setup kernels ----------------

__global__ __launch_bounds__(256) void count_deg_kernel(const int* __restrict__ dst, int* __restrict__ cnt, int e) {
  int i = blockIdx.x * 256 + threadIdx.x;
  if (i < e) atomicAdd(&cnt[dst[i]], 1);
}
__global__ __launch_bounds__(256) void clip_deg_kernel(const int* __restrict__ cnt, int* __restrict__ deg, int n) {
  int i = blockIdx.x * 256 + threadIdx.x;
  if (i < n) { int v = cnt[i] - 1; deg[i] = v < 0 ? 0 : (v > 3 ? 3 : v); }
}
__global__ __launch_bounds__(256) void goff_kernel(const int* __restrict__ batch, int* __restrict__ goff, int n, int b) {
  int i = blockIdx.x * 256 + threadIdx.x;
  if (i > n) return;
  int cur = (i < n) ? batch[i] : b;
  int prev = (i == 0) ? -1 : batch[i - 1];
  for (int x = prev + 1; x <= cur; x++) goff[x] = i;
}
// exclusive scan of cnt[16384] -> off[16385], single block of 256, 64 elems/thread
__global__ __launch_bounds__(256) void scan_off_kernel(const int* __restrict__ cnt, int* __restrict__ off) {
  __shared__ int part[256];
  int tid = threadIdx.x;
  int base = tid * 64;
  int s = 0;
  for (int i = 0; i < 64; i++) s += cnt[base + i];
  part[tid] = s;
  __syncthreads();
  for (int o = 1; o < 256; o <<= 1) {
    int t = (tid >= o) ? part[tid - o] : 0;
    __syncthreads();
    part[tid] += t;
    __syncthreads();
  }
  int run = (tid == 0) ? 0 : part[tid - 1];
  for (int i = 0; i < 64; i++) {
    off[base + i] = run;
    run += cnt[base + i];
  }
  if (tid == 255) off[NN] = run;
}
__global__ __launch_bounds__(256) void copy_i_kernel(const int* __restrict__ a, int* __restrict__ b, int n) {
  int i = blockIdx.x * 256 + threadIdx.x;
  if (i < n) b[i] = a[i];
}
__global__ __launch_bounds__(256) void fill_elist_kernel(const int* __restrict__ dst,
    int* __restrict__ cursor, int* __restrict__ elist, int e) {
  int i = blockIdx.x * 256 + threadIdx.x;
  if (i < e) {
    int p = atomicAdd(&cursor[dst[i]], 1);
    elist[p] = i;
  }
}
__global__ __launch_bounds__(256) void add3_kernel(float* __restrict__ dst,
    const float* __restrict__ a, const float* __restrict__ b, size_t n) {
  size_t i = (size_t)blockIdx.x * 256 + threadIdx.x;
  if (i < n) dst[i] = a[i] + b[i];
}
__global__ __launch_bounds__(256) void add3_both_kernel(float* __restrict__ dst, f16* __restrict__ dstH,
    const float* __restrict__ a, const float* __restrict__ b, size_t n) {
  size_t i = (size_t)blockIdx.x * 256 + threadIdx.x;
  if (i < n) { float v = a[i] + b[i]; dst[i] = v; dstH[i] = (f16)v; }
}
__global__ __launch_bounds__(256) void bcast_add_kernel(float* __restrict__ ho,
    const float* __restrict__ vo, const float* __restrict__ vs, const int* __restrict__ batch) {
  size_t i = (size_t)blockIdx.x * 256 + threadIdx.x;
  int n = (int)(i >> 8), c = (int)(i & 255);
  ho[i] += expf(vs[c]) * vo[(size_t)batch[n] * 256 + c];
}
__global__ __launch_bounds__(256) void f2h_kernel(const float* __restrict__ in, f16* __restrict__ out, int n4) {
  int i = blockIdx.x * 256 + threadIdx.x;
  if (i >= n4) return;
  float4 v = reinterpret_cast<const float4*>(in)[i];
  half4v o;
  o.x = (f16)v.x; o.y = (f16)v.y; o.z = (f16)v.z; o.w = (f16)v.w;
  reinterpret_cast<half4v*>(out)[i] = o;
}

// ---------------- segment reduce: out[n] = sum over CSR edge list of msg[e] ----------------
template <typename OUT>
__global__ __launch_bounds__(256) void seg_reduce_kernel(const f16* __restrict__ msg,
    const int* __restrict__ off, const int* __restrict__ elist, OUT* __restrict__ out) {
  int n = blockIdx.x, c = threadIdx.x;
  int j0 = off[n], j1 = off[n + 1];
  float acc = 0.f;
  for (int j = j0; j < j1; j++) {
    int e = elist[j];
    acc += (float)msg[(size_t)e * 256 + c];
  }
  out[(size_t)n * 256 + c] = (OUT)acc;
}

// ---------------- initial edge / node features ----------------

__global__ __launch_bounds__(256) void edge_feat_kernel(
    const int* __restrict__ eattr, const float* __restrict__ edist,
    const float* __restrict__ bond2d, const float* __restrict__ gmeans,
    const float* __restrict__ gstds, const float* __restrict__ attn_w,
    const float* __restrict__ attn_b, f16* __restrict__ msg) {
  int lane = threadIdx.x & 63;
  int e = blockIdx.x * 4 + (threadIdx.x >> 6);
  if (e >= EE) return;
  int a0 = eattr[e * 3 + 0], a1 = eattr[e * 3 + 1], a2 = eattr[e * 3 + 2];
  float dist = edist[e];
  const float SQ2PI = sqrtf(2.0f * 3.14159f);
  int c0 = lane * 4;
  float4 b0 = *reinterpret_cast<const float4*>(&bond2d[a0 * 256 + c0]);
  float4 b1 = *reinterpret_cast<const float4*>(&bond2d[2048 + a1 * 256 + c0]);
  float4 b2 = *reinterpret_cast<const float4*>(&bond2d[4096 + a2 * 256 + c0]);
  float4 gm = *reinterpret_cast<const float4*>(&gmeans[c0]);
  float4 gs = *reinterpret_cast<const float4*>(&gstds[c0]);
  float4 w2 = *reinterpret_cast<const float4*>(&attn_w[c0]);
  float4 w3 = *reinterpret_cast<const float4*>(&attn_w[256 + c0]);
  float h2[4], h3[4];
  float part = 0.f;
#pragma unroll
  for (int i = 0; i < 4; i++) {
    h2[i] = (&b0.x)[i] + (&b1.x)[i] + (&b2.x)[i];
    float sd = fabsf((&gs.x)[i]) + 0.01f;
    float df = (dist - (&gm.x)[i]) / sd;
    h3[i] = expf(-0.5f * df * df) / (SQ2PI * sd);
    part += (&w2.x)[i] * h2[i] + (&w3.x)[i] * h3[i];
  }
#pragma unroll
  for (int off = 32; off > 0; off >>= 1) part += __shfl_xor(part, off);
  float wg = 1.f / (1.f + expf(-(part + attn_b[0])));
  half4v o;
#pragma unroll
  for (int i = 0; i < 4; i++) o[i] = (f16)(wg * h2[i] + (1.f - wg) * h3[i]);
  *reinterpret_cast<half4v*>(&msg[(size_t)e * 256 + c0]) = o;
}

__global__ __launch_bounds__(256) void atom_finish_kernel(
    const int* __restrict__ xf, const float* __restrict__ emb,
    const float* __restrict__ scale_both, const int* __restrict__ deg,
    const float* __restrict__ tmp, float* __restrict__ h_in, f16* __restrict__ h_inH) {
  size_t i = (size_t)blockIdx.x * 256 + threadIdx.x;
  int n = (int)(i >> 8), c = (int)(i & 255);
  float acc = 0.f;
#pragma unroll
  for (int f = 0; f < 9; f++) {
    int v = xf[n * 9 + f];
    acc += emb[((size_t)(f * 128 + v)) * 256 + c];
  }
  float r = acc + expf(scale_both[deg[n] * 256 + c]) * tmp[i];
  h_in[i] = r;
  h_inH[i] = (f16)r;
}

// ---------------- fp16 MFMA GEMM with K-chunk prefetch ----------------
// MODE 0: C = acc (+bias) [C may be null]; MODE 2: C += expf(scale[col])*(acc+bias[col]);
// MODE 4: v = acc + cnt[row]*bias[col]; C = v; C2 += expf(scale[deg[row]*256+col]) * v
// All modes: if Cf non-null, Cf = (f16) of final value.
template <int MODE>
__global__ __launch_bounds__(256) void hgemm_kernel(
    const f16* __restrict__ A, const f16* __restrict__ W,
    const float* __restrict__ bias, const float* __restrict__ scale,
    const int* __restrict__ cnt, const int* __restrict__ deg,
    float* __restrict__ C, float* __restrict__ C2, f16* __restrict__ Cf, int K) {
  __shared__ f16 Ah[128 * 40];
  __shared__ f16 Wh[128 * 40];
  const int tid = threadIdx.x;
  const int row0 = blockIdx.x * 128, col0 = blockIdx.y * 128;
  const int lane = tid & 63;
  const int wave = tid >> 6;
  const int wr = (wave >> 1) * 64, wc = (wave & 1) * 64;
  const floatx4 fz = {0.f, 0.f, 0.f, 0.f};
  floatx4 acc[4][4];
#pragma unroll
  for (int m = 0; m < 4; m++)
#pragma unroll
    for (int n = 0; n < 4; n++) acc[m][n] = fz;
  const int q0 = tid * 2;
  const int r0s = q0 >> 2, p0s = q0 & 3;
  const int r1s = (q0 + 1) >> 2, p1s = (q0 + 1) & 3;
  const int kb = (lane >> 4) * 8;
  const int fr = lane & 15;
  uint4 a0 = *reinterpret_cast<const uint4*>(&A[(size_t)(row0 + r0s) * K + p0s * 8]);
  uint4 a1 = *reinterpret_cast<const uint4*>(&A[(size_t)(row0 + r1s) * K + p1s * 8]);
  uint4 w0 = *reinterpret_cast<const uint4*>(&W[(size_t)(col0 + r0s) * K + p0s * 8]);
  uint4 w1 = *reinterpret_cast<const uint4*>(&W[(size_t)(col0 + r1s) * K + p1s * 8]);
  for (int k0 = 0;;) {
    *reinterpret_cast<uint4*>(&Ah[r0s * 40 + p0s * 8]) = a0;
    *reinterpret_cast<uint4*>(&Ah[r1s * 40 + p1s * 8]) = a1;
    *reinterpret_cast<uint4*>(&Wh[r0s * 40 + p0s * 8]) = w0;
    *reinterpret_cast<uint4*>(&Wh[r1s * 40 + p1s * 8]) = w1;
    __syncthreads();
    int kn = k0 + 32;
    if (kn < K) {
      a0 = *reinterpret_cast<const uint4*>(&A[(size_t)(row0 + r0s) * K + kn + p0s * 8]);
      a1 = *reinterpret_cast<const uint4*>(&A[(size_t)(row0 + r1s) * K + kn + p1s * 8]);
      w0 = *reinterpret_cast<const uint4*>(&W[(size_t)(col0 + r0s) * K + kn + p0s * 8]);
      w1 = *reinterpret_cast<const uint4*>(&W[(size_t)(col0 + r1s) * K + kn + p1s * 8]);
    }
    half8 af[4], wf[4];
#pragma unroll
    for (int m = 0; m < 4; m++)
      af[m] = *reinterpret_cast<const half8*>(&Ah[(wr + m * 16 + fr) * 40 + kb]);
#pragma unroll
    for (int n = 0; n < 4; n++)
      wf[n] = *reinterpret_cast<const half8*>(&Wh[(wc + n * 16 + fr) * 40 + kb]);
#pragma unroll
    for (int m = 0; m < 4; m++)
#pragma unroll
      for (int n = 0; n < 4; n++)
        acc[m][n] = __builtin_amdgcn_mfma_f32_16x16x32_f16(af[m], wf[n], acc[m][n], 0, 0, 0);
    if (kn >= K) break;
    __syncthreads();
    k0 = kn;
  }
  const int rl4 = (lane >> 4) * 4, cl = lane & 15;
#pragma unroll
  for (int m = 0; m < 4; m++) {
#pragma unroll
    for (int i = 0; i < 4; i++) {
      int row = row0 + wr + m * 16 + rl4 + i;
      float cb = (MODE == 4) ? (float)cnt[row] : 1.f;
      int dg = (MODE == 4) ? deg[row] : 0;
#pragma unroll
      for (int n = 0; n < 4; n++) {
        int col = col0 + wc + n * 16 + cl;
        float v = acc[m][n][i];
        size_t oi = (size_t)row * 256 + col;
        if (MODE == 4) {
          v += cb * bias[col];
          C[oi] = v;
          C2[oi] += expf(scale[dg * 256 + col]) * v;
          if (Cf) Cf[oi] = (f16)v;
        } else if (MODE == 2) {
          v += bias[col];
          float nv = C[oi] + expf(scale[col]) * v;
          C[oi] = nv;
          if (Cf) Cf[oi] = (f16)nv;
        } else {
          if (bias) v += bias[col];
          if (C) C[oi] = v;
          if (Cf) Cf[oi] = (f16)v;
        }
      }
    }
  }
}

// ---------------- conv edge: gather(fp16) + bond + GN + glin + product, dense fp16 out ----------------
__global__ __launch_bounds__(256) void conv_edge_kernel(
    const f16* __restrict__ xp, const int* __restrict__ eattr,
    const int* __restrict__ src, const int* __restrict__ dst,
    const float* __restrict__ bond_emb, const float* __restrict__ gate_w,
    const float* __restrict__ val_w, f16* __restrict__ msg) {
  __shared__ float sb[6144];  // [3][8][256]
  __shared__ float sg[4096];  // transposed [o][i][g]
  __shared__ float sv[4096];
  int tid = threadIdx.x;
  for (int i = tid; i < 6144; i += 256) sb[i] = bond_emb[i];
  for (int i = tid; i < 4096; i += 256) {
    int g = i >> 8, o = (i >> 4) & 15, ii = i & 15;
    int t = (o * 16 + ii) * 16 + g;
    sg[t] = gate_w[i];
    sv[t] = val_w[i];
  }
  __syncthreads();
  int idx = blockIdx.x * 256 + tid;
  int e = idx >> 4, g = idx & 15;
  int a0 = eattr[e * 3 + 0], a1 = eattr[e * 3 + 1], a2 = eattr[e * 3 + 2];
  int d = dst[e], s = src[e];
  half8 d0 = *reinterpret_cast<const half8*>(&xp[(size_t)d * 256 + g * 16]);
  half8 d1 = *reinterpret_cast<const half8*>(&xp[(size_t)d * 256 + g * 16 + 8]);
  half8 s0 = *reinterpret_cast<const half8*>(&xp[(size_t)s * 256 + g * 16]);
  half8 s1 = *reinterpret_cast<const half8*>(&xp[(size_t)s * 256 + g * 16 + 8]);
  float xg[16], xv[16];
  float mg = 0.f, mv = 0.f;
#pragma unroll
  for (int i = 0; i < 16; i++) {
    float bo = sb[a0 * 256 + g * 16 + i] + sb[2048 + a1 * 256 + g * 16 + i] + sb[4096 + a2 * 256 + g * 16 + i];
    float xd = (i < 8) ? (float)d0[i & 7] : (float)d1[i & 7];
    float xs = (i < 8) ? (float)s0[i & 7] : (float)s1[i & 7];
    xg[i] = xd + bo;
    xv[i] = xs + bo;
    mg += xg[i];
    mv += xv[i];
  }
  mg *= (1.f / 16.f);
  mv *= (1.f / 16.f);
  float vg = 0.f, vv = 0.f;
#pragma unroll
  for (int i = 0; i < 16; i++) {
    float dg_ = xg[i] - mg, dv_ = xv[i] - mv;
    vg += dg_ * dg_;
    vv += dv_ * dv_;
  }
  float rg = rsqrtf(vg * (1.f / 16.f) + 1e-5f);
  float rv = rsqrtf(vv * (1.f / 16.f) + 1e-5f);
#pragma unroll
  for (int i = 0; i < 16; i++) {
    xg[i] = (xg[i] - mg) * rg;
    xv[i] = (xv[i] - mv) * rv;
  }
  f16 res[16];
#pragma unroll
  for (int o = 0; o < 16; o++) {
    float ag = 0.f, av = 0.f;
#pragma unroll
    for (int i = 0; i < 16; i++) {
      ag += xg[i] * sg[(o * 16 + i) * 16 + g];
      av += xv[i] * sv[(o * 16 + i) * 16 + g];
    }
    res[o] = (f16)(fmaxf(ag, 0.f) * av);
  }
  uint4* op = reinterpret_cast<uint4*>(&msg[(size_t)e * 256 + g * 16]);
  op[0] = reinterpret_cast<const uint4*>(res)[0];
  op[1] = reinterpret_cast<const uint4*>(res)[1];
}

// ---------------- glb middle: GN + glin + relu*mul, fp16 output ----------------
template <int DOUT>
__global__ __launch_bounds__(256) void glb_mid_kernel(
    const float* __restrict__ X, const float* __restrict__ gate_w,
    const float* __restrict__ val_w, f16* __restrict__ out) {
  __shared__ float sg[16 * DOUT * 16];
  __shared__ float sv[16 * DOUT * 16];
  int tid = threadIdx.x;
  for (int i = tid; i < 16 * DOUT * 16; i += 256) {
    int g = i / (DOUT * 16), rem = i % (DOUT * 16), o = rem >> 4, ii = rem & 15;
    int t = (o * 16 + ii) * 16 + g;
    sg[t] = gate_w[i];
    sv[t] = val_w[i];
  }
  __syncthreads();
  int idx = blockIdx.x * 256 + tid;
  int n = idx >> 4, g = idx & 15;
  float x[16];
  float m = 0.f;
#pragma unroll
  for (int i = 0; i < 16; i++) {
    x[i] = X[(size_t)n * 256 + g * 16 + i];
    m += x[i];
  }
  m *= (1.f / 16.f);
  float v = 0.f;
#pragma unroll
  for (int i = 0; i < 16; i++) {
    float d_ = x[i] - m;
    v += d_ * d_;
  }
  float r = rsqrtf(v * (1.f / 16.f) + 1e-5f);
#pragma unroll
  for (int i = 0; i < 16; i++) x[i] = (x[i] - m) * r;
  f16* op = &out[(size_t)n * (16 * DOUT) + g * DOUT];
  for (int o = 0; o < DOUT; o++) {
    float ag = 0.f, av = 0.f;
#pragma unroll
    for (int i = 0; i < 16; i++) {
      ag += x[i] * sg[(o * 16 + i) * 16 + g];
      av += x[i] * sv[(o * 16 + i) * 16 + g];
    }
    op[o] = (f16)(fmaxf(ag, 0.f) * av);
  }
}

// standalone GroupNorm (in place)
__global__ __launch_bounds__(256) void gn_kernel(float* __restrict__ X) {
  int idx = blockIdx.x * 256 + threadIdx.x;
  int n = idx >> 4, g = idx & 15;
  float x[16];
  float m = 0.f;
#pragma unroll
  for (int i = 0; i < 16; i++) {
    x[i] = X[(size_t)n * 256 + g * 16 + i];
    m += x[i];
  }
  m *= (1.f / 16.f);
  float v = 0.f;
#pragma unroll
  for (int i = 0; i < 16; i++) {
    float d_ = x[i] - m;
    v += d_ * d_;
  }
  float r = rsqrtf(v * (1.f / 16.f) + 1e-5f);
#pragma unroll
  for (int i = 0; i < 16; i++) X[(size_t)n * 256 + g * 16 + i] = (x[i] - m) * r;
}

// ---------------- attention: batched per-graph K/V + h_att + xk_sum ----------------
// Block per graph. Weights held in registers (per-thread 2 output cols), h_att in
// registers (32 elems/thread), rows double-pumped 8 nodes per iteration.
__global__ __launch_bounds__(256) void att_graph_kernel(
    const float* __restrict__ xv0, const float* __restrict__ k_w,
    const float* __restrict__ v_w, const int* __restrict__ goff,
    float* __restrict__ h_att, float* __restrict__ xk_sum) {
  __shared__ float kx[8][512];
  __shared__ float vx[8][512];
  __shared__ float rows[8][256];
  const int tid = threadIdx.x, b = blockIdx.x;
  // per-thread weight slices: cols o0=tid, o1=tid+256; w[o*16+i]
  float wk0[16], wv0[16], wk1[16], wv1[16];
#pragma unroll
  for (int i = 0; i < 4; i++) {
    float4 k0 = *reinterpret_cast<const float4*>(&k_w[tid * 16 + i * 4]);
    float4 v0 = *reinterpret_cast<const float4*>(&v_w[tid * 16 + i * 4]);
    float4 k1 = *reinterpret_cast<const float4*>(&k_w[(tid + 256) * 16 + i * 4]);
    float4 v1 = *reinterpret_cast<const float4*>(&v_w[(tid + 256) * 16 + i * 4]);
    wk0[i * 4 + 0] = k0.x; wk0[i * 4 + 1] = k0.y; wk0[i * 4 + 2] = k0.z; wk0[i * 4 + 3] = k0.w;
    wv0[i * 4 + 0] = v0.x; wv0[i * 4 + 1] = v0.y; wv0[i * 4 + 2] = v0.z; wv0[i * 4 + 3] = v0.w;
    wk1[i * 4 + 0] = k1.x; wk1[i * 4 + 1] = k1.y; wk1[i * 4 + 2] = k1.z; wk1[i * 4 + 3] = k1.w;
    wv1[i * 4 + 0] = v1.x; wv1[i * 4 + 1] = v1.y; wv1[i * 4 + 2] = v1.z; wv1[i * 4 + 3] = v1.w;
  }
  // h_att accumulator in registers: elems p*16+j for p in {tid, tid+256}
  float hacc[2][16];
  const float* hg = &h_att[(size_t)b * 8192];
#pragma unroll
  for (int c = 0; c < 2; c++) {
    int p = tid + c * 256;
#pragma unroll
    for (int j = 0; j < 16; j++) hacc[c][j] = hg[p * 16 + j];
  }
  float ks0 = 0.f, ks1 = 0.f;
  const int n0 = goff[b], n1 = goff[b + 1];
  const int g0 = tid >> 5, g1 = (tid + 256) >> 5;
  // prefetch chunk 0
  float r[8];
#pragma unroll
  for (int nn = 0; nn < 8; nn++) {
    int n = n0 + nn;
    r[nn] = (n < n1) ? xv0[(size_t)n * 256 + tid] : 0.f;
  }
  for (int nbase = n0; nbase < n1; nbase += 8) {
#pragma unroll
    for (int nn = 0; nn < 8; nn++) rows[nn][tid] = r[nn];
    __syncthreads();
#pragma unroll
    for (int nn = 0; nn < 8; nn++) {
      int n = nbase + 8 + nn;
      r[nn] = (n < n1) ? xv0[(size_t)n * 256 + tid] : 0.f;
    }
    // compute kx/vx for this chunk
#pragma unroll
    for (int nn = 0; nn < 8; nn++) {
      const float4* rp0 = reinterpret_cast<const float4*>(&rows[nn][g0 * 16]);
      const float4* rp1 = reinterpret_cast<const float4*>(&rows[nn][g1 * 16]);
      float aK0 = 0.f, aV0 = 0.f, aK1 = 0.f, aV1 = 0.f;
#pragma unroll
      for (int q = 0; q < 4; q++) {
        float4 x0 = rp0[q], x1 = rp1[q];
#pragma unroll
        for (int t = 0; t < 4; t++) {
          float e0 = (&x0.x)[t], e1 = (&x1.x)[t];
          aK0 += e0 * wk0[q * 4 + t];
          aV0 += e0 * wv0[q * 4 + t];
          aK1 += e1 * wk1[q * 4 + t];
          aV1 += e1 * wv1[q * 4 + t];
        }
      }
      bool valid = (nbase + nn) < n1;
      float ek0 = valid ? expf(aK0 * 0.25f) : 0.f;
      float ek1 = valid ? expf(aK1 * 0.25f) : 0.f;
      kx[nn][tid] = ek0;
      kx[nn][tid + 256] = ek1;
      vx[nn][tid] = aV0;
      vx[nn][tid + 256] = aV1;
      ks0 += ek0;
      ks1 += ek1;
    }
    __syncthreads();
    // accumulate h_att
#pragma unroll
    for (int c = 0; c < 2; c++) {
      int p = tid + c * 256;
      int head = p >> 4, h = p & 15;
#pragma unroll
      for (int nn = 0; nn < 8; nn++) {
        float kk = kx[nn][head * 16 + h];
        const float4* vp = reinterpret_cast<const float4*>(&vx[nn][head * 16]);
#pragma unroll
        for (int q = 0; q < 4; q++) {
          float4 vq = vp[q];
          hacc[c][q * 4 + 0] += kk * vq.x;
          hacc[c][q * 4 + 1] += kk * vq.y;
          hacc[c][q * 4 + 2] += kk * vq.z;
          hacc[c][q * 4 + 3] += kk * vq.w;
        }
      }
    }
    __syncthreads();
  }
  float* hgo = &h_att[(size_t)b * 8192];
#pragma unroll
  for (int c = 0; c < 2; c++) {
    int p = tid + c * 256;
#pragma unroll
    for (int j = 0; j < 16; j++) hgo[p * 16 + j] = hacc[c][j];
  }
  xk_sum[(size_t)b * 512 + tid] = ks0;
  xk_sum[(size_t)b * 512 + tid + 256] = ks1;
}

__global__ __launch_bounds__(256) void att_out_kernel(
    const float* __restrict__ xv0, const float* __restrict__ q_w,
    const float* __restrict__ xk_sum, const float* __restrict__ h_att,
    const int* __restrict__ batch, f16* __restrict__ out) {
  __shared__ float sqw[8192];
  int tid = threadIdx.x;
  for (int i = tid; i < 8192; i += 256) {
    int g = i >> 9, oo = (i >> 4) & 31, ii = i & 15;
    sqw[(oo * 16 + ii) * 16 + g] = q_w[i];
  }
  __syncthreads();
  int idx = blockIdx.x * 256 + tid;
  int n = idx >> 5, head = idx & 31;
  int b = batch[n];
  int g = head >> 1, j = head & 1;
  float x[16];
#pragma unroll
  for (int i = 0; i < 16; i++) x[i] = xv0[(size_t)n * 256 + g * 16 + i];
  float q[16];
  float denom = 0.f;
#pragma unroll
  for (int h = 0; h < 16; h++) {
    float a = 0.f;
    int oo = j * 16 + h;
#pragma unroll
    for (int i = 0; i < 16; i++) a += x[i] * sqw[(oo * 16 + i) * 16 + g];
    float e = expf(a * 0.25f);
    q[h] = e;
    denom += e * xk_sum[(size_t)b * 512 + head * 16 + h];
  }
  float inv = 1.f / denom;
  const float* ha = &h_att[((size_t)b * 32 + head) * 256];
#pragma unroll
  for (int v = 0; v < 16; v++) {
    float a = 0.f;
#pragma unroll
    for (int h = 0; h < 16; h++) a += q[h] * ha[h * 16 + v];
    out[(size_t)n * 512 + head * 16 + v] = (f16)(a * inv);
  }
}

__global__ __launch_bounds__(256) void virt_seg_kernel(const float* __restrict__ h_in,
    const int* __restrict__ goff, float* __restrict__ h_virt) {
  int b = blockIdx.x, c = threadIdx.x;
  float acc = h_virt[(size_t)b * 256 + c];
  int n0 = goff[b], n1 = goff[b + 1];
  for (int n = n0; n < n1; n++) acc += h_in[(size_t)n * 256 + c];
  h_virt[(size_t)b * 256 + c] = acc;
}

// ---------------- host driver ----------------

extern "C" void kernel_launch(void* const* d_in, const int* in_sizes, int n_in,
                              void* d_out, int out_size, void* d_ws, size_t ws_size,
                              hipStream_t stream) {
  const int* x_feat = (const int*)d_in[0];
  const int* eidx = (const int*)d_in[1];
  const int* eattr = (const int*)d_in[2];
  const int* batch = (const int*)d_in[3];
  const float* edist = (const float*)d_in[5];
  const float* atom_emb = (const float*)d_in[6];
  const float* bond2d = (const float*)d_in[7];
  const float* gmeans = (const float*)d_in[8];
  const float* gstds = (const float*)d_in[9];
  const float* attn_w = (const float*)d_in[10];
  const float* attn_b = (const float*)d_in[11];
  const float* scale_both = (const float*)d_in[12];
  const float* conv_bond_emb = (const float*)d_in[13];
  const float* conv_pre_w = (const float*)d_in[14];
  const float* conv_gate_w = (const float*)d_in[15];
  const float* conv_val_w = (const float*)d_in[16];
  const float* conv_post_w = (const float*)d_in[17];
  const float* conv_post_b = (const float*)d_in[18];
  const float* conv_scale = (const float*)d_in[19];
  const float* virt_pre_w = (const float*)d_in[20];
  const float* virt_pre_b = (const float*)d_in[21];
  const float* virt_gate_w = (const float*)d_in[22];
  const float* virt_val_w = (const float*)d_in[23];
  const float* virt_post_w = (const float*)d_in[24];
  const float* virt_post_b = (const float*)d_in[25];
  const float* virt_scale = (const float*)d_in[26];
  const float* att_pre_w = (const float*)d_in[27];
  const float* att_pre_b = (const float*)d_in[28];
  const float* att_q_w = (const float*)d_in[29];
  const float* att_k_w = (const float*)d_in[30];
  const float* att_v_w = (const float*)d_in[31];
  const float* att_post_w = (const float*)d_in[32];
  const float* att_post_b = (const float*)d_in[33];
  const float* att_scale = (const float*)d_in[34];
  const float* main_pre_w = (const float*)d_in[35];
  const float* main_pre_b = (const float*)d_in[36];
  const float* main_gate_w = (const float*)d_in[37];
  const float* main_val_w = (const float*)d_in[38];
  const float* main_post_w = (const float*)d_in[39];
  const float* main_post_b = (const float*)d_in[40];

  const int* src = eidx;
  const int* dst = eidx + EE;

  float* ws = (float*)d_ws;
  float* h_in = ws;
  float* h_out = ws + ND;
  float* x_raw = ws + 2 * ND;
  float* x_out = ws + 3 * ND;
  float* nodeA = ws + 4 * ND;
  f16* h_inH = (f16*)(ws + 5 * ND);          // ND halfs
  f16* xrawH = (f16*)(ws + 5 * ND + ND / 2); // ND halfs
  f16* hTmp = (f16*)(ws + 6 * ND);           // ND halfs (nodeAH / aggH / houtH, time-shared)
  f16* msgH = (f16*)(ws + 6 * ND + ND / 2);  // 3*ND halfs (edge msgs / att_out / main mid)
  float* sm = ws + 8 * ND;
  f16* hW = (f16*)sm;                        // 2359296 halfs = 1179648 floats
  float* h_virt = sm + 1179648;              // B*256
  float* h_att = h_virt + 65536;             // B*32*16*16
  float* xk_sum = h_att + 2097152;           // B*512
  float* vt1 = xk_sum + 131072;              // B*256
  float* vout = vt1 + 65536;                 // B*256
  f16* vmidH = (f16*)(vout + 65536);         // B*512 halfs
  f16* virtH = vmidH + 131072;               // B*256 halfs
  int* cnt = (int*)(virtH + 65536);          // N
  int* deg = cnt + NN;                       // N
  int* goff = deg + NN;                      // B+1
  int* off = goff + BB + 1;                  // N+1
  int* cursor = off + NN + 1;                // N
  int* elist = cursor + NN;                  // E

  f16* wCpre = hW;
  f16* wCpost = hW + 524288;
  f16* wApre = hW + 1048576;
  f16* wApost = hW + 1179648;
  f16* wMpre = hW + 1441792;
  f16* wMpost = hW + 1572864;
  f16* wVpre = hW + 1966080;
  f16* wVpost = hW + 2097152;

  auto cvt = [&](const float* in, f16* out, int n) {
    f2h_kernel<<<n / 4 / 256, 256, 0, stream>>>(in, out, n / 4);
  };

  // weights -> fp16
  cvt(conv_pre_w, wCpre, 524288);
  cvt(conv_post_w, wCpost, 524288);
  cvt(att_pre_w, wApre, 131072);
  cvt(att_post_w, wApost, 262144);
  cvt(main_pre_w, wMpre, 131072);
  cvt(main_post_w, wMpost, 393216);
  cvt(virt_pre_w, wVpre, 131072);
  cvt(virt_post_w, wVpost, 262144);

  // degree + graph offsets + CSR (edges grouped by dst)
  (void)hipMemsetAsync(cnt, 0, NN * sizeof(int), stream);
  count_deg_kernel<<<EE / 256, 256, 0, stream>>>(dst, cnt, EE);
  clip_deg_kernel<<<NN / 256, 256, 0, stream>>>(cnt, deg, NN);
  goff_kernel<<<(NN + 256) / 256, 256, 0, stream>>>(batch, goff, NN, BB);
  scan_off_kernel<<<1, 256, 0, stream>>>(cnt, off);
  copy_i_kernel<<<NN / 256, 256, 0, stream>>>(off, cursor, NN);
  fill_elist_kernel<<<EE / 256, 256, 0, stream>>>(dst, cursor, elist, EE);

  // initial node features (dense edge msgs -> CSR reduce -> finish)
  edge_feat_kernel<<<EE / 4, 256, 0, stream>>>(eattr, edist, bond2d, gmeans, gstds,
                                               attn_w, attn_b, msgH);
  seg_reduce_kernel<float><<<NN, 256, 0, stream>>>(msgH, off, elist, x_out);
  atom_finish_kernel<<<(int)(ND / 256), 256, 0, stream>>>(x_feat, atom_emb, scale_both, deg,
                                                          x_out, h_in, h_inH);
  (void)hipMemsetAsync(h_virt, 0, 65536 * 4, stream);
  (void)hipMemsetAsync(h_att, 0, 2097152 * 4, stream);

  const dim3 gN(NN / 128, 2), gB(BB / 128, 2);

  for (int l = 0; l < 2; l++) {
    // ---- ConvMessage ----
    (void)hipMemsetAsync(x_out, 0, ND * 4, stream);
    const f16* curH = h_inH;
    for (int k = 0; k < 4; k++) {
      if (k == 2) {
        add3_both_kernel<<<(int)(ND / 256), 256, 0, stream>>>(x_raw, xrawH, h_in, x_out, ND);
        (void)hipMemsetAsync(x_out, 0, ND * 4, stream);
        curH = xrawH;
      }
      size_t lk = (size_t)(l * 4 + k);
      hgemm_kernel<0><<<gN, 256, 0, stream>>>(curH, wCpre + lk * 65536, nullptr, nullptr,
                                              nullptr, nullptr, nullptr, nullptr, hTmp, 256);
      conv_edge_kernel<<<EE * 16 / 256, 256, 0, stream>>>(
          hTmp, eattr, src, dst, conv_bond_emb + lk * 6144,
          conv_gate_w + lk * 4096, conv_val_w + lk * 4096, msgH);
      seg_reduce_kernel<f16><<<NN, 256, 0, stream>>>(msgH, off, elist, hTmp);
      hgemm_kernel<4><<<gN, 256, 0, stream>>>(hTmp, wCpost + lk * 65536,
                                              conv_post_b + lk * 256, conv_scale + lk * 1024,
                                              cnt, deg, x_raw, x_out, xrawH, 256);
      curH = xrawH;
    }
    add3_kernel<<<(int)(ND / 256), 256, 0, stream>>>(h_out, h_in, x_out, ND);

    // ---- VirtMessage ----
    virt_seg_kernel<<<BB, 256, 0, stream>>>(h_in, goff, h_virt);
    cvt(h_virt, virtH, 65536);
    hgemm_kernel<0><<<gB, 256, 0, stream>>>(virtH, wVpre + (size_t)l * 65536,
                                            virt_pre_b + (size_t)l * 256, nullptr, nullptr,
                                            nullptr, vt1, nullptr, nullptr, 256);
    glb_mid_kernel<32><<<BB * 16 / 256, 256, 0, stream>>>(
        vt1, virt_gate_w + (size_t)l * 8192, virt_val_w + (size_t)l * 8192, vmidH);
    hgemm_kernel<0><<<gB, 256, 0, stream>>>(vmidH, wVpost + (size_t)l * 131072,
                                            virt_post_b + (size_t)l * 256, nullptr, nullptr,
                                            nullptr, vout, nullptr, nullptr, 512);
    bcast_add_kernel<<<(int)(ND / 256), 256, 0, stream>>>(
        h_out, vout, virt_scale + (size_t)l * 256, batch);

    // ---- AttMessage ----
    hgemm_kernel<0><<<gN, 256, 0, stream>>>(h_inH, wApre + (size_t)l * 65536,
                                            att_pre_b + (size_t)l * 256, nullptr, nullptr,
                                            nullptr, nodeA, nullptr, nullptr, 256);
    gn_kernel<<<NN * 16 / 256, 256, 0, stream>>>(nodeA);
    att_graph_kernel<<<BB, 256, 0, stream>>>(
        nodeA, att_k_w + (size_t)l * 8192, att_v_w + (size_t)l * 8192, goff, h_att, xk_sum);
    att_out_kernel<<<NN * 32 / 256, 256, 0, stream>>>(
        nodeA, att_q_w + (size_t)l * 8192, xk_sum, h_att, batch, msgH);
    hgemm_kernel<2><<<gN, 256, 0, stream>>>(msgH, wApost + (size_t)l * 131072,
                                            att_post_b + (size_t)l * 256,
                                            att_scale + (size_t)l * 256, nullptr, nullptr,
                                            h_out, nullptr, hTmp, 512);

    // ---- main gated block ----
    hgemm_kernel<0><<<gN, 256, 0, stream>>>(hTmp, wMpre + (size_t)l * 65536,
                                            main_pre_b + (size_t)l * 256, nullptr, nullptr,
                                            nullptr, nodeA, nullptr, nullptr, 256);
    glb_mid_kernel<48><<<NN * 16 / 256, 256, 0, stream>>>(
        nodeA, main_gate_w + (size_t)l * 12288, main_val_w + (size_t)l * 12288, msgH);
    float* hdst = (l == 1) ? (float*)d_out : h_in;
    f16* hdstH = (l == 1) ? nullptr : h_inH;
    hgemm_kernel<0><<<gN, 256, 0, stream>>>(msgH, wMpost + (size_t)l * 196608,
                                            main_post_b + (size_t)l * 256, nullptr, nullptr,
                                            nullptr, hdst, nullptr, hdstH, 768);
  }
}

// Round 6
// 1281.581 us; speedup vs baseline: 5.4397x; 1.6383x over previous
//
#include <hip/hip_runtime.h>
#include <cstdint>
#include <cstddef>
#include <type_traits>

#define NN 16384
#define EE 49152
#define BB 256
// D=256, G=16, 16 channels per group, HD=16

typedef _Float16 f16;
typedef _Float16 half8 __attribute__((ext_vector_type(8)));
typedef _Float16 half4v __attribute__((ext_vector_type(4)));
typedef float floatx4 __attribute__((ext_vector_type(4)));

static constexpr size_t ND = (size_t)NN * 256;

// ---------------- setup kernels ----------------

__global__ __launch_bounds__(256) void count_deg_kernel(const int* __restrict__ dst, int* __restrict__ cnt, int e) {
  int i = blockIdx.x * 256 + threadIdx.x;
  if (i < e) atomicAdd(&cnt[dst[i]], 1);
}
__global__ __launch_bounds__(256) void clip_deg_kernel(const int* __restrict__ cnt, int* __restrict__ deg, int n) {
  int i = blockIdx.x * 256 + threadIdx.x;
  if (i < n) { int v = cnt[i] - 1; deg[i] = v < 0 ? 0 : (v > 3 ? 3 : v); }
}
__global__ __launch_bounds__(256) void goff_kernel(const int* __restrict__ batch, int* __restrict__ goff, int n, int b) {
  int i = blockIdx.x * 256 + threadIdx.x;
  if (i > n) return;
  int cur = (i < n) ? batch[i] : b;
  int prev = (i == 0) ? -1 : batch[i - 1];
  for (int x = prev + 1; x <= cur; x++) goff[x] = i;
}
__global__ __launch_bounds__(256) void scan_off_kernel(const int* __restrict__ cnt, int* __restrict__ off) {
  __shared__ int part[256];
  int tid = threadIdx.x;
  int base = tid * 64;
  int s = 0;
  for (int i = 0; i < 64; i++) s += cnt[base + i];
  part[tid] = s;
  __syncthreads();
  for (int o = 1; o < 256; o <<= 1) {
    int t = (tid >= o) ? part[tid - o] : 0;
    __syncthreads();
    part[tid] += t;
    __syncthreads();
  }
  int run = (tid == 0) ? 0 : part[tid - 1];
  for (int i = 0; i < 64; i++) {
    off[base + i] = run;
    run += cnt[base + i];
  }
  if (tid == 255) off[NN] = run;
}
__global__ __launch_bounds__(256) void copy_i_kernel(const int* __restrict__ a, int* __restrict__ b, int n) {
  int i = blockIdx.x * 256 + threadIdx.x;
  if (i < n) b[i] = a[i];
}
__global__ __launch_bounds__(256) void fill_elist_kernel(const int* __restrict__ dst,
    int* __restrict__ cursor, int* __restrict__ elist, int e) {
  int i = blockIdx.x * 256 + threadIdx.x;
  if (i < e) {
    int p = atomicAdd(&cursor[dst[i]], 1);
    elist[p] = i;
  }
}
// gather edge data into CSR (dst-sorted) order
__global__ __launch_bounds__(256) void gather_edges_kernel(const int* __restrict__ elist,
    const int* __restrict__ eattr, const int* __restrict__ src, const int* __restrict__ dst,
    const float* __restrict__ edist, int* __restrict__ ea_s, int* __restrict__ src_s,
    int* __restrict__ dst_s, float* __restrict__ ed_s) {
  int j = blockIdx.x * 256 + threadIdx.x;
  if (j >= EE) return;
  int e = elist[j];
  ea_s[j * 3 + 0] = eattr[e * 3 + 0];
  ea_s[j * 3 + 1] = eattr[e * 3 + 1];
  ea_s[j * 3 + 2] = eattr[e * 3 + 2];
  src_s[j] = src[e];
  dst_s[j] = dst[e];
  ed_s[j] = edist[e];
}
// float4 elementwise
__global__ __launch_bounds__(256) void add3_kernel(float* __restrict__ dst,
    const float* __restrict__ a, const float* __restrict__ b, int n4) {
  int i = blockIdx.x * 256 + threadIdx.x;
  if (i >= n4) return;
  float4 x = reinterpret_cast<const float4*>(a)[i];
  float4 y = reinterpret_cast<const float4*>(b)[i];
  x.x += y.x; x.y += y.y; x.z += y.z; x.w += y.w;
  reinterpret_cast<float4*>(dst)[i] = x;
}
__global__ __launch_bounds__(256) void add3_both_kernel(float* __restrict__ dst, f16* __restrict__ dstH,
    const float* __restrict__ a, const float* __restrict__ b, int n4) {
  int i = blockIdx.x * 256 + threadIdx.x;
  if (i >= n4) return;
  float4 x = reinterpret_cast<const float4*>(a)[i];
  float4 y = reinterpret_cast<const float4*>(b)[i];
  x.x += y.x; x.y += y.y; x.z += y.z; x.w += y.w;
  reinterpret_cast<float4*>(dst)[i] = x;
  half4v h;
  h[0] = (f16)x.x; h[1] = (f16)x.y; h[2] = (f16)x.z; h[3] = (f16)x.w;
  reinterpret_cast<half4v*>(dstH)[i] = h;
}
__global__ __launch_bounds__(256) void bcast_add_kernel(float* __restrict__ ho,
    const float* __restrict__ vo, const float* __restrict__ vs, const int* __restrict__ batch) {
  int i4 = blockIdx.x * 256 + threadIdx.x;
  int i = i4 * 4;
  int n = i >> 8, c = i & 255;
  float4 h = reinterpret_cast<const float4*>(&ho[i])[0];
  float4 v = *reinterpret_cast<const float4*>(&vo[(size_t)batch[n] * 256 + c]);
  float4 s = *reinterpret_cast<const float4*>(&vs[c]);
  h.x += expf(s.x) * v.x; h.y += expf(s.y) * v.y;
  h.z += expf(s.z) * v.z; h.w += expf(s.w) * v.w;
  *reinterpret_cast<float4*>(&ho[i]) = h;
}
__global__ __launch_bounds__(256) void f2h_kernel(const float* __restrict__ in, f16* __restrict__ out, int n4) {
  int i = blockIdx.x * 256 + threadIdx.x;
  if (i >= n4) return;
  float4 v = reinterpret_cast<const float4*>(in)[i];
  half4v o;
  o[0] = (f16)v.x; o[1] = (f16)v.y; o[2] = (f16)v.z; o[3] = (f16)v.w;
  reinterpret_cast<half4v*>(out)[i] = o;
}

// ---------------- segment reduce over CONTIGUOUS CSR rows ----------------
// block = 4 nodes x 64 threads; thread handles 4 channels
template <typename OUT>
__global__ __launch_bounds__(256) void seg_reduce_kernel(const f16* __restrict__ msg,
    const int* __restrict__ off, OUT* __restrict__ out) {
  int idx = blockIdx.x * 256 + threadIdx.x;
  int n = idx >> 6, c0 = (idx & 63) * 4;
  int j0 = off[n], j1 = off[n + 1];
  float a0 = 0.f, a1 = 0.f, a2 = 0.f, a3 = 0.f;
  int j = j0;
  for (; j + 1 < j1; j += 2) {
    half4v m0 = *reinterpret_cast<const half4v*>(&msg[(size_t)j * 256 + c0]);
    half4v m1 = *reinterpret_cast<const half4v*>(&msg[(size_t)(j + 1) * 256 + c0]);
    a0 += (float)m0[0] + (float)m1[0];
    a1 += (float)m0[1] + (float)m1[1];
    a2 += (float)m0[2] + (float)m1[2];
    a3 += (float)m0[3] + (float)m1[3];
  }
  if (j < j1) {
    half4v m0 = *reinterpret_cast<const half4v*>(&msg[(size_t)j * 256 + c0]);
    a0 += (float)m0[0]; a1 += (float)m0[1]; a2 += (float)m0[2]; a3 += (float)m0[3];
  }
  if constexpr (std::is_same<OUT, float>::value) {
    float4 o = {a0, a1, a2, a3};
    *reinterpret_cast<float4*>(&out[(size_t)n * 256 + c0]) = o;
  } else {
    half4v o;
    o[0] = (f16)a0; o[1] = (f16)a1; o[2] = (f16)a2; o[3] = (f16)a3;
    *reinterpret_cast<half4v*>(&out[(size_t)n * 256 + c0]) = o;
  }
}

// ---------------- initial edge / node features (CSR order) ----------------

__global__ __launch_bounds__(256) void edge_feat_kernel(
    const int* __restrict__ ea_s, const float* __restrict__ ed_s,
    const float* __restrict__ bond2d, const float* __restrict__ gmeans,
    const float* __restrict__ gstds, const float* __restrict__ attn_w,
    const float* __restrict__ attn_b, f16* __restrict__ msg) {
  int lane = threadIdx.x & 63;
  int j = blockIdx.x * 4 + (threadIdx.x >> 6);
  if (j >= EE) return;
  int a0 = ea_s[j * 3 + 0], a1 = ea_s[j * 3 + 1], a2 = ea_s[j * 3 + 2];
  float dist = ed_s[j];
  const float SQ2PI = sqrtf(2.0f * 3.14159f);
  int c0 = lane * 4;
  float4 b0 = *reinterpret_cast<const float4*>(&bond2d[a0 * 256 + c0]);
  float4 b1 = *reinterpret_cast<const float4*>(&bond2d[2048 + a1 * 256 + c0]);
  float4 b2 = *reinterpret_cast<const float4*>(&bond2d[4096 + a2 * 256 + c0]);
  float4 gm = *reinterpret_cast<const float4*>(&gmeans[c0]);
  float4 gs = *reinterpret_cast<const float4*>(&gstds[c0]);
  float4 w2 = *reinterpret_cast<const float4*>(&attn_w[c0]);
  float4 w3 = *reinterpret_cast<const float4*>(&attn_w[256 + c0]);
  float h2[4], h3[4];
  float part = 0.f;
#pragma unroll
  for (int i = 0; i < 4; i++) {
    h2[i] = (&b0.x)[i] + (&b1.x)[i] + (&b2.x)[i];
    float sd = fabsf((&gs.x)[i]) + 0.01f;
    float df = (dist - (&gm.x)[i]) / sd;
    h3[i] = expf(-0.5f * df * df) / (SQ2PI * sd);
    part += (&w2.x)[i] * h2[i] + (&w3.x)[i] * h3[i];
  }
#pragma unroll
  for (int off = 32; off > 0; off >>= 1) part += __shfl_xor(part, off);
  float wg = 1.f / (1.f + expf(-(part + attn_b[0])));
  half4v o;
#pragma unroll
  for (int i = 0; i < 4; i++) o[i] = (f16)(wg * h2[i] + (1.f - wg) * h3[i]);
  *reinterpret_cast<half4v*>(&msg[(size_t)j * 256 + c0]) = o;
}

// thread = (node, 4 channels); wave = one node
__global__ __launch_bounds__(256) void atom_finish_kernel(
    const int* __restrict__ xf, const float* __restrict__ emb,
    const float* __restrict__ scale_both, const int* __restrict__ deg,
    const float* __restrict__ tmp, float* __restrict__ h_in, f16* __restrict__ h_inH) {
  int idx = blockIdx.x * 256 + threadIdx.x;
  int n = idx >> 6, c = (idx & 63) * 4;
  float a0 = 0.f, a1 = 0.f, a2 = 0.f, a3 = 0.f;
#pragma unroll
  for (int f = 0; f < 9; f++) {
    int v = xf[n * 9 + f];
    float4 e = *reinterpret_cast<const float4*>(&emb[((size_t)(f * 128 + v)) * 256 + c]);
    a0 += e.x; a1 += e.y; a2 += e.z; a3 += e.w;
  }
  int dg = deg[n];
  float4 s = *reinterpret_cast<const float4*>(&scale_both[dg * 256 + c]);
  float4 t = *reinterpret_cast<const float4*>(&tmp[(size_t)n * 256 + c]);
  float4 r;
  r.x = a0 + expf(s.x) * t.x; r.y = a1 + expf(s.y) * t.y;
  r.z = a2 + expf(s.z) * t.z; r.w = a3 + expf(s.w) * t.w;
  *reinterpret_cast<float4*>(&h_in[(size_t)n * 256 + c]) = r;
  half4v h;
  h[0] = (f16)r.x; h[1] = (f16)r.y; h[2] = (f16)r.z; h[3] = (f16)r.w;
  *reinterpret_cast<half4v*>(&h_inH[(size_t)n * 256 + c]) = h;
}

// ---------------- fp16 MFMA GEMM, tile 128x64, 4 waves (2x2), BK=32, reg prefetch ----------------
// MODE 0: v=acc(+bias); C?=v; Cf?=f16(v)
// MODE 2: v=acc+bias; nv=Cadd[oi]+expf(scale[col])*v; C?=nv; Cf?=f16(nv)
// MODE 4: v=acc+cnt[row]*bias[col]; Cadd[oi]+=expf(scale[deg[row]*256+col])*v; Cf?=f16(v)
// MODE 5: like 4 but Cadd[oi]= (init store)
template <int MODE>
__global__ __launch_bounds__(256) void hgemm_kernel(
    const f16* __restrict__ A, const f16* __restrict__ W,
    const float* __restrict__ bias, const float* __restrict__ scale,
    const int* __restrict__ cnt, const int* __restrict__ deg,
    float* __restrict__ C, float* __restrict__ Cadd, f16* __restrict__ Cf, int K) {
  __shared__ f16 Ah[128 * 40];
  __shared__ f16 Wh[64 * 40];
  const int tid = threadIdx.x;
  const int row0 = blockIdx.x * 128, col0 = blockIdx.y * 64;
  const int lane = tid & 63;
  const int wave = tid >> 6;
  const int wr = (wave >> 1) * 64, wc = (wave & 1) * 32;
  const floatx4 fz = {0.f, 0.f, 0.f, 0.f};
  floatx4 acc[4][2];
#pragma unroll
  for (int m = 0; m < 4; m++)
#pragma unroll
    for (int n = 0; n < 2; n++) acc[m][n] = fz;
  const int q0 = tid * 2;
  const int rA0 = q0 >> 2, pA0 = q0 & 3;
  const int rA1 = (q0 + 1) >> 2, pA1 = (q0 + 1) & 3;
  const int rW = tid >> 2, pW = tid & 3;
  const int kb = (lane >> 4) * 8;
  const int fr = lane & 15;
  uint4 a0 = *reinterpret_cast<const uint4*>(&A[(size_t)(row0 + rA0) * K + pA0 * 8]);
  uint4 a1 = *reinterpret_cast<const uint4*>(&A[(size_t)(row0 + rA1) * K + pA1 * 8]);
  uint4 w0 = *reinterpret_cast<const uint4*>(&W[(size_t)(col0 + rW) * K + pW * 8]);
  for (int k0 = 0;;) {
    *reinterpret_cast<uint4*>(&Ah[rA0 * 40 + pA0 * 8]) = a0;
    *reinterpret_cast<uint4*>(&Ah[rA1 * 40 + pA1 * 8]) = a1;
    *reinterpret_cast<uint4*>(&Wh[rW * 40 + pW * 8]) = w0;
    __syncthreads();
    int kn = k0 + 32;
    if (kn < K) {
      a0 = *reinterpret_cast<const uint4*>(&A[(size_t)(row0 + rA0) * K + kn + pA0 * 8]);
      a1 = *reinterpret_cast<const uint4*>(&A[(size_t)(row0 + rA1) * K + kn + pA1 * 8]);
      w0 = *reinterpret_cast<const uint4*>(&W[(size_t)(col0 + rW) * K + kn + pW * 8]);
    }
    half8 af[4], wf[2];
#pragma unroll
    for (int m = 0; m < 4; m++)
      af[m] = *reinterpret_cast<const half8*>(&Ah[(wr + m * 16 + fr) * 40 + kb]);
#pragma unroll
    for (int n = 0; n < 2; n++)
      wf[n] = *reinterpret_cast<const half8*>(&Wh[(wc + n * 16 + fr) * 40 + kb]);
#pragma unroll
    for (int m = 0; m < 4; m++)
#pragma unroll
      for (int n = 0; n < 2; n++)
        acc[m][n] = __builtin_amdgcn_mfma_f32_16x16x32_f16(af[m], wf[n], acc[m][n], 0, 0, 0);
    if (kn >= K) break;
    __syncthreads();
    k0 = kn;
  }
  const int rl4 = (lane >> 4) * 4, cl = lane & 15;
#pragma unroll
  for (int m = 0; m < 4; m++) {
#pragma unroll
    for (int i = 0; i < 4; i++) {
      int row = row0 + wr + m * 16 + rl4 + i;
      float cb = (MODE >= 4) ? (float)cnt[row] : 1.f;
      int dg = (MODE >= 4) ? deg[row] : 0;
#pragma unroll
      for (int n = 0; n < 2; n++) {
        int col = col0 + wc + n * 16 + cl;
        float v = acc[m][n][i];
        size_t oi = (size_t)row * 256 + col;
        if (MODE >= 4) {
          v += cb * bias[col];
          float sc = expf(scale[dg * 256 + col]);
          if (MODE == 4) Cadd[oi] += sc * v;
          else Cadd[oi] = sc * v;
          if (Cf) Cf[oi] = (f16)v;
        } else if (MODE == 2) {
          v += bias[col];
          float nv = Cadd[oi] + expf(scale[col]) * v;
          if (C) C[oi] = nv;
          if (Cf) Cf[oi] = (f16)nv;
        } else {
          if (bias) v += bias[col];
          if (C) C[oi] = v;
          if (Cf) Cf[oi] = (f16)v;
        }
      }
    }
  }
}

// ---------------- conv edge (CSR order): gather(fp16) + bond(global) + GN + glin + product ----------------
__global__ __launch_bounds__(256) void conv_edge_kernel(
    const f16* __restrict__ xp, const int* __restrict__ ea_s,
    const int* __restrict__ src_s, const int* __restrict__ dst_s,
    const float* __restrict__ bond_emb, const float* __restrict__ gate_w,
    const float* __restrict__ val_w, f16* __restrict__ msg) {
  __shared__ float sg[16 * 260];  // [g][o*16+i], row stride 260 (bank-spread)
  __shared__ float sv[16 * 260];
  int tid = threadIdx.x;
  for (int i = tid; i < 4096; i += 256) {
    int g = i >> 8, rem = i & 255;
    sg[g * 260 + rem] = gate_w[i];
    sv[g * 260 + rem] = val_w[i];
  }
  __syncthreads();
  int idx = blockIdx.x * 256 + tid;
  int j = idx >> 4, g = idx & 15;
  int a0 = ea_s[j * 3 + 0], a1 = ea_s[j * 3 + 1], a2 = ea_s[j * 3 + 2];
  int d = dst_s[j], s = src_s[j];
  half8 xd0 = *reinterpret_cast<const half8*>(&xp[(size_t)d * 256 + g * 16]);
  half8 xd1 = *reinterpret_cast<const half8*>(&xp[(size_t)d * 256 + g * 16 + 8]);
  half8 xs0 = *reinterpret_cast<const half8*>(&xp[(size_t)s * 256 + g * 16]);
  half8 xs1 = *reinterpret_cast<const half8*>(&xp[(size_t)s * 256 + g * 16 + 8]);
  const float4* b0p = reinterpret_cast<const float4*>(&bond_emb[a0 * 256 + g * 16]);
  const float4* b1p = reinterpret_cast<const float4*>(&bond_emb[2048 + a1 * 256 + g * 16]);
  const float4* b2p = reinterpret_cast<const float4*>(&bond_emb[4096 + a2 * 256 + g * 16]);
  float xg[16], xv[16];
  float mg = 0.f, mv = 0.f;
#pragma unroll
  for (int q = 0; q < 4; q++) {
    float4 b0 = b0p[q], b1 = b1p[q], b2 = b2p[q];
#pragma unroll
    for (int t = 0; t < 4; t++) {
      int i = q * 4 + t;
      float bo = (&b0.x)[t] + (&b1.x)[t] + (&b2.x)[t];
      float xd = (i < 8) ? (float)xd0[i & 7] : (float)xd1[i & 7];
      float xs = (i < 8) ? (float)xs0[i & 7] : (float)xs1[i & 7];
      xg[i] = xd + bo;
      xv[i] = xs + bo;
      mg += xg[i];
      mv += xv[i];
    }
  }
  mg *= (1.f / 16.f);
  mv *= (1.f / 16.f);
  float vg = 0.f, vv = 0.f;
#pragma unroll
  for (int i = 0; i < 16; i++) {
    float dg_ = xg[i] - mg, dv_ = xv[i] - mv;
    vg += dg_ * dg_;
    vv += dv_ * dv_;
  }
  float rg = rsqrtf(vg * (1.f / 16.f) + 1e-5f);
  float rv = rsqrtf(vv * (1.f / 16.f) + 1e-5f);
#pragma unroll
  for (int i = 0; i < 16; i++) {
    xg[i] = (xg[i] - mg) * rg;
    xv[i] = (xv[i] - mv) * rv;
  }
  f16 res[16];
#pragma unroll
  for (int o = 0; o < 16; o++) {
    const float4* gp = reinterpret_cast<const float4*>(&sg[g * 260 + o * 16]);
    const float4* vp = reinterpret_cast<const float4*>(&sv[g * 260 + o * 16]);
    float ag = 0.f, av = 0.f;
#pragma unroll
    for (int q = 0; q < 4; q++) {
      float4 gq = gp[q], vq = vp[q];
#pragma unroll
      for (int t = 0; t < 4; t++) {
        ag += xg[q * 4 + t] * (&gq.x)[t];
        av += xv[q * 4 + t] * (&vq.x)[t];
      }
    }
    res[o] = (f16)(fmaxf(ag, 0.f) * av);
  }
  uint4* op = reinterpret_cast<uint4*>(&msg[(size_t)j * 256 + g * 16]);
  op[0] = reinterpret_cast<const uint4*>(res)[0];
  op[1] = reinterpret_cast<const uint4*>(res)[1];
}

// ---------------- glb middle: GN + glin + relu*mul (fp16 weights in LDS) ----------------
template <int DOUT>
__global__ __launch_bounds__(256) void glb_mid_kernel(
    const float* __restrict__ X, const float* __restrict__ gate_w,
    const float* __restrict__ val_w, f16* __restrict__ out) {
  __shared__ f16 sg[16 * DOUT * 16];
  __shared__ f16 sv[16 * DOUT * 16];
  int tid = threadIdx.x;
  for (int i = tid; i < 16 * DOUT * 16; i += 256) {
    int g = i / (DOUT * 16), rem = i % (DOUT * 16), o = rem >> 4, ii = rem & 15;
    int t = (o * 16 + ii) * 16 + g;
    sg[t] = (f16)gate_w[i];
    sv[t] = (f16)val_w[i];
  }
  __syncthreads();
  int idx = blockIdx.x * 256 + tid;
  int n = idx >> 4, g = idx & 15;
  float x[16];
  float m = 0.f;
  const float4* xp4 = reinterpret_cast<const float4*>(&X[(size_t)n * 256 + g * 16]);
#pragma unroll
  for (int q = 0; q < 4; q++) {
    float4 xq = xp4[q];
#pragma unroll
    for (int t = 0; t < 4; t++) {
      x[q * 4 + t] = (&xq.x)[t];
      m += (&xq.x)[t];
    }
  }
  m *= (1.f / 16.f);
  float v = 0.f;
#pragma unroll
  for (int i = 0; i < 16; i++) {
    float d_ = x[i] - m;
    v += d_ * d_;
  }
  float r = rsqrtf(v * (1.f / 16.f) + 1e-5f);
#pragma unroll
  for (int i = 0; i < 16; i++) x[i] = (x[i] - m) * r;
  f16* op = &out[(size_t)n * (16 * DOUT) + g * DOUT];
  for (int o = 0; o < DOUT; o++) {
    float ag = 0.f, av = 0.f;
#pragma unroll
    for (int i = 0; i < 16; i++) {
      ag += x[i] * (float)sg[(o * 16 + i) * 16 + g];
      av += x[i] * (float)sv[(o * 16 + i) * 16 + g];
    }
    op[o] = (f16)(fmaxf(ag, 0.f) * av);
  }
}

// vectorized GroupNorm in place: thread = (node, 4 channels), 4-lane group reduce
__global__ __launch_bounds__(256) void gn_vec_kernel(float* __restrict__ X) {
  int idx = blockIdx.x * 256 + threadIdx.x;
  int n = idx >> 6, q = idx & 63;
  float4 x = *reinterpret_cast<const float4*>(&X[(size_t)n * 256 + q * 4]);
  float s = x.x + x.y + x.z + x.w;
  float s2 = x.x * x.x + x.y * x.y + x.z * x.z + x.w * x.w;
  s += __shfl_xor(s, 1); s2 += __shfl_xor(s2, 1);
  s += __shfl_xor(s, 2); s2 += __shfl_xor(s2, 2);
  float m = s * (1.f / 16.f);
  float var = s2 * (1.f / 16.f) - m * m;
  float r = rsqrtf(var + 1e-5f);
  x.x = (x.x - m) * r; x.y = (x.y - m) * r;
  x.z = (x.z - m) * r; x.w = (x.w - m) * r;
  *reinterpret_cast<float4*>(&X[(size_t)n * 256 + q * 4]) = x;
}

// ---------------- attention ----------------
__global__ __launch_bounds__(256) void att_graph_kernel(
    const float* __restrict__ xv0, const float* __restrict__ k_w,
    const float* __restrict__ v_w, const int* __restrict__ goff,
    float* __restrict__ h_att, float* __restrict__ xk_sum) {
  __shared__ float kx[8][512];
  __shared__ float vx[8][512];
  __shared__ float rows[8][256];
  const int tid = threadIdx.x, b = blockIdx.x;
  float wk0[16], wv0[16], wk1[16], wv1[16];
#pragma unroll
  for (int i = 0; i < 4; i++) {
    float4 k0 = *reinterpret_cast<const float4*>(&k_w[tid * 16 + i * 4]);
    float4 v0 = *reinterpret_cast<const float4*>(&v_w[tid * 16 + i * 4]);
    float4 k1 = *reinterpret_cast<const float4*>(&k_w[(tid + 256) * 16 + i * 4]);
    float4 v1 = *reinterpret_cast<const float4*>(&v_w[(tid + 256) * 16 + i * 4]);
    wk0[i * 4 + 0] = k0.x; wk0[i * 4 + 1] = k0.y; wk0[i * 4 + 2] = k0.z; wk0[i * 4 + 3] = k0.w;
    wv0[i * 4 + 0] = v0.x; wv0[i * 4 + 1] = v0.y; wv0[i * 4 + 2] = v0.z; wv0[i * 4 + 3] = v0.w;
    wk1[i * 4 + 0] = k1.x; wk1[i * 4 + 1] = k1.y; wk1[i * 4 + 2] = k1.z; wk1[i * 4 + 3] = k1.w;
    wv1[i * 4 + 0] = v1.x; wv1[i * 4 + 1] = v1.y; wv1[i * 4 + 2] = v1.z; wv1[i * 4 + 3] = v1.w;
  }
  float hacc[2][16];
  const float* hg = &h_att[(size_t)b * 8192];
#pragma unroll
  for (int c = 0; c < 2; c++) {
    int p = tid + c * 256;
#pragma unroll
    for (int j = 0; j < 16; j++) hacc[c][j] = hg[p * 16 + j];
  }
  float ks0 = 0.f, ks1 = 0.f;
  const int n0 = goff[b], n1 = goff[b + 1];
  const int g0 = tid >> 5, g1 = (tid + 256) >> 5;
  float r[8];
#pragma unroll
  for (int nn = 0; nn < 8; nn++) {
    int n = n0 + nn;
    r[nn] = (n < n1) ? xv0[(size_t)n * 256 + tid] : 0.f;
  }
  for (int nbase = n0; nbase < n1; nbase += 8) {
#pragma unroll
    for (int nn = 0; nn < 8; nn++) rows[nn][tid] = r[nn];
    __syncthreads();
#pragma unroll
    for (int nn = 0; nn < 8; nn++) {
      int n = nbase + 8 + nn;
      r[nn] = (n < n1) ? xv0[(size_t)n * 256 + tid] : 0.f;
    }
#pragma unroll
    for (int nn = 0; nn < 8; nn++) {
      const float4* rp0 = reinterpret_cast<const float4*>(&rows[nn][g0 * 16]);
      const float4* rp1 = reinterpret_cast<const float4*>(&rows[nn][g1 * 16]);
      float aK0 = 0.f, aV0 = 0.f, aK1 = 0.f, aV1 = 0.f;
#pragma unroll
      for (int q = 0; q < 4; q++) {
        float4 x0 = rp0[q], x1 = rp1[q];
#pragma unroll
        for (int t = 0; t < 4; t++) {
          float e0 = (&x0.x)[t], e1 = (&x1.x)[t];
          aK0 += e0 * wk0[q * 4 + t];
          aV0 += e0 * wv0[q * 4 + t];
          aK1 += e1 * wk1[q * 4 + t];
          aV1 += e1 * wv1[q * 4 + t];
        }
      }
      bool valid = (nbase + nn) < n1;
      float ek0 = valid ? expf(aK0 * 0.25f) : 0.f;
      float ek1 = valid ? expf(aK1 * 0.25f) : 0.f;
      kx[nn][tid] = ek0;
      kx[nn][tid + 256] = ek1;
      vx[nn][tid] = aV0;
      vx[nn][tid + 256] = aV1;
      ks0 += ek0;
      ks1 += ek1;
    }
    __syncthreads();
#pragma unroll
    for (int c = 0; c < 2; c++) {
      int p = tid + c * 256;
      int head = p >> 4, h = p & 15;
#pragma unroll
      for (int nn = 0; nn < 8; nn++) {
        float kk = kx[nn][head * 16 + h];
        const float4* vp = reinterpret_cast<const float4*>(&vx[nn][head * 16]);
#pragma unroll
        for (int q = 0; q < 4; q++) {
          float4 vq = vp[q];
          hacc[c][q * 4 + 0] += kk * vq.x;
          hacc[c][q * 4 + 1] += kk * vq.y;
          hacc[c][q * 4 + 2] += kk * vq.z;
          hacc[c][q * 4 + 3] += kk * vq.w;
        }
      }
    }
    __syncthreads();
  }
  float* hgo = &h_att[(size_t)b * 8192];
#pragma unroll
  for (int c = 0; c < 2; c++) {
    int p = tid + c * 256;
#pragma unroll
    for (int j = 0; j < 16; j++) hgo[p * 16 + j] = hacc[c][j];
  }
  xk_sum[(size_t)b * 512 + tid] = ks0;
  xk_sum[(size_t)b * 512 + tid + 256] = ks1;
}

__global__ __launch_bounds__(256) void att_out_kernel(
    const float* __restrict__ xv0, const float* __restrict__ q_w,
    const float* __restrict__ xk_sum, const float* __restrict__ h_att,
    const int* __restrict__ batch, f16* __restrict__ out) {
  __shared__ float sqw[8192];
  int tid = threadIdx.x;
  for (int i = tid; i < 8192; i += 256) {
    int g = i >> 9, oo = (i >> 4) & 31, ii = i & 15;
    sqw[(oo * 16 + ii) * 16 + g] = q_w[i];
  }
  __syncthreads();
  int idx = blockIdx.x * 256 + tid;
  int n = idx >> 5, head = idx & 31;
  int b = batch[n];
  int g = head >> 1, j = head & 1;
  float x[16];
  const float4* xp4 = reinterpret_cast<const float4*>(&xv0[(size_t)n * 256 + g * 16]);
#pragma unroll
  for (int q = 0; q < 4; q++) {
    float4 xq = xp4[q];
#pragma unroll
    for (int t = 0; t < 4; t++) x[q * 4 + t] = (&xq.x)[t];
  }
  float qv[16];
  float denom = 0.f;
#pragma unroll
  for (int h = 0; h < 16; h++) {
    float a = 0.f;
    int oo = j * 16 + h;
#pragma unroll
    for (int i = 0; i < 16; i++) a += x[i] * sqw[(oo * 16 + i) * 16 + g];
    float e = expf(a * 0.25f);
    qv[h] = e;
    denom += e * xk_sum[(size_t)b * 512 + head * 16 + h];
  }
  float inv = 1.f / denom;
  const float* ha = &h_att[((size_t)b * 32 + head) * 256];
#pragma unroll
  for (int v = 0; v < 16; v++) {
    float a = 0.f;
#pragma unroll
    for (int h = 0; h < 16; h++) a += qv[h] * ha[h * 16 + v];
    out[(size_t)n * 512 + head * 16 + v] = (f16)(a * inv);
  }
}

__global__ __launch_bounds__(256) void virt_seg_kernel(const float* __restrict__ h_in,
    const int* __restrict__ goff, float* __restrict__ h_virt) {
  int b = blockIdx.x, c = threadIdx.x;
  float acc = h_virt[(size_t)b * 256 + c];
  int n0 = goff[b], n1 = goff[b + 1];
  for (int n = n0; n < n1; n++) acc += h_in[(size_t)n * 256 + c];
  h_virt[(size_t)b * 256 + c] = acc;
}

// ---------------- host driver ----------------

extern "C" void kernel_launch(void* const* d_in, const int* in_sizes, int n_in,
                              void* d_out, int out_size, void* d_ws, size_t ws_size,
                              hipStream_t stream) {
  const int* x_feat = (const int*)d_in[0];
  const int* eidx = (const int*)d_in[1];
  const int* eattr = (const int*)d_in[2];
  const int* batch = (const int*)d_in[3];
  const float* edist = (const float*)d_in[5];
  const float* atom_emb = (const float*)d_in[6];
  const float* bond2d = (const float*)d_in[7];
  const float* gmeans = (const float*)d_in[8];
  const float* gstds = (const float*)d_in[9];
  const float* attn_w = (const float*)d_in[10];
  const float* attn_b = (const float*)d_in[11];
  const float* scale_both = (const float*)d_in[12];
  const float* conv_bond_emb = (const float*)d_in[13];
  const float* conv_pre_w = (const float*)d_in[14];
  const float* conv_gate_w = (const float*)d_in[15];
  const float* conv_val_w = (const float*)d_in[16];
  const float* conv_post_w = (const float*)d_in[17];
  const float* conv_post_b = (const float*)d_in[18];
  const float* conv_scale = (const float*)d_in[19];
  const float* virt_pre_w = (const float*)d_in[20];
  const float* virt_pre_b = (const float*)d_in[21];
  const float* virt_gate_w = (const float*)d_in[22];
  const float* virt_val_w = (const float*)d_in[23];
  const float* virt_post_w = (const float*)d_in[24];
  const float* virt_post_b = (const float*)d_in[25];
  const float* virt_scale = (const float*)d_in[26];
  const float* att_pre_w = (const float*)d_in[27];
  const float* att_pre_b = (const float*)d_in[28];
  const float* att_q_w = (const float*)d_in[29];
  const float* att_k_w = (const float*)d_in[30];
  const float* att_v_w = (const float*)d_in[31];
  const float* att_post_w = (const float*)d_in[32];
  const float* att_post_b = (const float*)d_in[33];
  const float* att_scale = (const float*)d_in[34];
  const float* main_pre_w = (const float*)d_in[35];
  const float* main_pre_b = (const float*)d_in[36];
  const float* main_gate_w = (const float*)d_in[37];
  const float* main_val_w = (const float*)d_in[38];
  const float* main_post_w = (const float*)d_in[39];
  const float* main_post_b = (const float*)d_in[40];

  const int* src = eidx;
  const int* dst = eidx + EE;

  float* ws = (float*)d_ws;
  float* h_in = ws;
  float* h_out = ws + ND;
  float* x_raw = ws + 2 * ND;
  float* x_out = ws + 3 * ND;
  float* nodeA = ws + 4 * ND;
  f16* h_inH = (f16*)(ws + 5 * ND);
  f16* xrawH = (f16*)(ws + 5 * ND + ND / 2);
  f16* hTmp = (f16*)(ws + 6 * ND);
  f16* msgH = (f16*)(ws + 6 * ND + ND / 2);   // 3*ND halfs
  float* sm = ws + 8 * ND;
  f16* hW = (f16*)sm;                          // 2359296 halfs = 1179648 floats
  float* h_virt = sm + 1179648;
  float* h_att = h_virt + 65536;
  float* xk_sum = h_att + 2097152;
  float* vt1 = xk_sum + 131072;
  float* vout = vt1 + 65536;
  f16* vmidH = (f16*)(vout + 65536);           // B*512 halfs
  f16* virtH = vmidH + 131072;                 // B*256 halfs
  int* cnt = (int*)(virtH + 65536);
  int* deg = cnt + NN;
  int* goff = deg + NN;
  int* off = goff + BB + 1;
  int* cursor = off + NN + 1;
  int* elist = cursor + NN;
  int* ea_s = elist + EE;
  int* src_s = ea_s + 3 * EE;
  int* dst_s = src_s + EE;
  float* ed_s = (float*)(dst_s + EE);

  f16* wCpre = hW;
  f16* wCpost = hW + 524288;
  f16* wApre = hW + 1048576;
  f16* wApost = hW + 1179648;
  f16* wMpre = hW + 1441792;
  f16* wMpost = hW + 1572864;
  f16* wVpre = hW + 1966080;
  f16* wVpost = hW + 2097152;

  auto cvt = [&](const float* in, f16* out, int n) {
    f2h_kernel<<<n / 4 / 256, 256, 0, stream>>>(in, out, n / 4);
  };

  cvt(conv_pre_w, wCpre, 524288);
  cvt(conv_post_w, wCpost, 524288);
  cvt(att_pre_w, wApre, 131072);
  cvt(att_post_w, wApost, 262144);
  cvt(main_pre_w, wMpre, 131072);
  cvt(main_post_w, wMpost, 393216);
  cvt(virt_pre_w, wVpre, 131072);
  cvt(virt_post_w, wVpost, 262144);

  // degree + graph offsets + CSR (edges grouped by dst) + gathered edge data
  (void)hipMemsetAsync(cnt, 0, NN * sizeof(int), stream);
  count_deg_kernel<<<EE / 256, 256, 0, stream>>>(dst, cnt, EE);
  clip_deg_kernel<<<NN / 256, 256, 0, stream>>>(cnt, deg, NN);
  goff_kernel<<<(NN + 256) / 256, 256, 0, stream>>>(batch, goff, NN, BB);
  scan_off_kernel<<<1, 256, 0, stream>>>(cnt, off);
  copy_i_kernel<<<NN / 256, 256, 0, stream>>>(off, cursor, NN);
  fill_elist_kernel<<<EE / 256, 256, 0, stream>>>(dst, cursor, elist, EE);
  gather_edges_kernel<<<EE / 256, 256, 0, stream>>>(elist, eattr, src, dst, edist,
                                                    ea_s, src_s, dst_s, ed_s);

  // initial node features
  edge_feat_kernel<<<EE / 4, 256, 0, stream>>>(ea_s, ed_s, bond2d, gmeans, gstds,
                                               attn_w, attn_b, msgH);
  seg_reduce_kernel<float><<<NN / 4, 256, 0, stream>>>(msgH, off, x_out);
  atom_finish_kernel<<<NN * 64 / 256, 256, 0, stream>>>(x_feat, atom_emb, scale_both, deg,
                                                        x_out, h_in, h_inH);
  (void)hipMemsetAsync(h_virt, 0, 65536 * 4, stream);
  (void)hipMemsetAsync(h_att, 0, 2097152 * 4, stream);

  const dim3 gN(NN / 128, 4), gB(BB / 128, 4);
  const int n4 = (int)(ND / 4);

  for (int l = 0; l < 2; l++) {
    // ---- ConvMessage ----
    const f16* curH = h_inH;
    for (int k = 0; k < 4; k++) {
      if (k == 2) {
        add3_both_kernel<<<n4 / 256, 256, 0, stream>>>(x_raw, xrawH, h_in, x_out, n4);
        curH = xrawH;
      }
      size_t lk = (size_t)(l * 4 + k);
      hgemm_kernel<0><<<gN, 256, 0, stream>>>(curH, wCpre + lk * 65536, nullptr, nullptr,
                                              nullptr, nullptr, nullptr, nullptr, hTmp, 256);
      conv_edge_kernel<<<EE * 16 / 256, 256, 0, stream>>>(
          hTmp, ea_s, src_s, dst_s, conv_bond_emb + lk * 6144,
          conv_gate_w + lk * 4096, conv_val_w + lk * 4096, msgH);
      seg_reduce_kernel<f16><<<NN / 4, 256, 0, stream>>>(msgH, off, hTmp);
      if (k == 0 || k == 2)
        hgemm_kernel<5><<<gN, 256, 0, stream>>>(hTmp, wCpost + lk * 65536,
                                                conv_post_b + lk * 256, conv_scale + lk * 1024,
                                                cnt, deg, nullptr, x_out, xrawH, 256);
      else
        hgemm_kernel<4><<<gN, 256, 0, stream>>>(hTmp, wCpost + lk * 65536,
                                                conv_post_b + lk * 256, conv_scale + lk * 1024,
                                                cnt, deg, nullptr, x_out, xrawH, 256);
      curH = xrawH;
    }
    add3_kernel<<<n4 / 256, 256, 0, stream>>>(h_out, h_in, x_out, n4);

    // ---- VirtMessage ----
    virt_seg_kernel<<<BB, 256, 0, stream>>>(h_in, goff, h_virt);
    cvt(h_virt, virtH, 65536);
    hgemm_kernel<0><<<gB, 256, 0, stream>>>(virtH, wVpre + (size_t)l * 65536,
                                            virt_pre_b + (size_t)l * 256, nullptr, nullptr,
                                            nullptr, vt1, nullptr, nullptr, 256);
    glb_mid_kernel<32><<<BB * 16 / 256, 256, 0, stream>>>(
        vt1, virt_gate_w + (size_t)l * 8192, virt_val_w + (size_t)l * 8192, vmidH);
    hgemm_kernel<0><<<gB, 256, 0, stream>>>(vmidH, wVpost + (size_t)l * 131072,
                                            virt_post_b + (size_t)l * 256, nullptr, nullptr,
                                            nullptr, vout, nullptr, nullptr, 512);
    bcast_add_kernel<<<n4 / 256, 256, 0, stream>>>(
        h_out, vout, virt_scale + (size_t)l * 256, batch);

    // ---- AttMessage ----
    hgemm_kernel<0><<<gN, 256, 0, stream>>>(h_inH, wApre + (size_t)l * 65536,
                                            att_pre_b + (size_t)l * 256, nullptr, nullptr,
                                            nullptr, nodeA, nullptr, nullptr, 256);
    gn_vec_kernel<<<NN * 64 / 256, 256, 0, stream>>>(nodeA);
    att_graph_kernel<<<BB, 256, 0, stream>>>(
        nodeA, att_k_w + (size_t)l * 8192, att_v_w + (size_t)l * 8192, goff, h_att, xk_sum);
    att_out_kernel<<<NN * 32 / 256, 256, 0, stream>>>(
        nodeA, att_q_w + (size_t)l * 8192, xk_sum, h_att, batch, msgH);
    hgemm_kernel<2><<<gN, 256, 0, stream>>>(msgH, wApost + (size_t)l * 131072,
                                            att_post_b + (size_t)l * 256,
                                            att_scale + (size_t)l * 256, nullptr, nullptr,
                                            nullptr, h_out, hTmp, 512);

    // ---- main gated block ----
    hgemm_kernel<0><<<gN, 256, 0, stream>>>(hTmp, wMpre + (size_t)l * 65536,
                                            main_pre_b + (size_t)l * 256, nullptr, nullptr,
                                            nullptr, nodeA, nullptr, nullptr, 256);
    glb_mid_kernel<48><<<NN * 16 / 256, 256, 0, stream>>>(
        nodeA, main_gate_w + (size_t)l * 12288, main_val_w + (size_t)l * 12288, msgH);
    float* hdst = (l == 1) ? (float*)d_out : h_in;
    f16* hdstH = (l == 1) ? nullptr : h_inH;
    hgemm_kernel<0><<<gN, 256, 0, stream>>>(msgH, wMpost + (size_t)l * 196608,
                                            main_post_b + (size_t)l * 256, nullptr, nullptr,
                                            nullptr, hdst, nullptr, hdstH, 768);
  }
}

// Round 7
// 1198.446 us; speedup vs baseline: 5.8171x; 1.0694x over previous
//
#include <hip/hip_runtime.h>
#include <cstdint>
#include <cstddef>
#include <type_traits>

#define NN 16384
#define EE 49152
#define BB 256
// D=256, G=16, 16 channels per group, HD=16

typedef _Float16 f16;
typedef _Float16 half8 __attribute__((ext_vector_type(8)));
typedef _Float16 half4v __attribute__((ext_vector_type(4)));
typedef float floatx4 __attribute__((ext_vector_type(4)));

static constexpr size_t ND = (size_t)NN * 256;

// ---------------- setup kernels ----------------

__global__ __launch_bounds__(256) void count_deg_kernel(const int* __restrict__ dst, int* __restrict__ cnt, int e) {
  int i = blockIdx.x * 256 + threadIdx.x;
  if (i < e) atomicAdd(&cnt[dst[i]], 1);
}
__global__ __launch_bounds__(256) void clip_deg_kernel(const int* __restrict__ cnt, int* __restrict__ deg, int n) {
  int i = blockIdx.x * 256 + threadIdx.x;
  if (i < n) { int v = cnt[i] - 1; deg[i] = v < 0 ? 0 : (v > 3 ? 3 : v); }
}
__global__ __launch_bounds__(256) void goff_kernel(const int* __restrict__ batch, int* __restrict__ goff, int n, int b) {
  int i = blockIdx.x * 256 + threadIdx.x;
  if (i > n) return;
  int cur = (i < n) ? batch[i] : b;
  int prev = (i == 0) ? -1 : batch[i - 1];
  for (int x = prev + 1; x <= cur; x++) goff[x] = i;
}
__global__ __launch_bounds__(256) void scan_off_kernel(const int* __restrict__ cnt, int* __restrict__ off) {
  __shared__ int part[256];
  int tid = threadIdx.x;
  int base = tid * 64;
  int s = 0;
  for (int i = 0; i < 64; i++) s += cnt[base + i];
  part[tid] = s;
  __syncthreads();
  for (int o = 1; o < 256; o <<= 1) {
    int t = (tid >= o) ? part[tid - o] : 0;
    __syncthreads();
    part[tid] += t;
    __syncthreads();
  }
  int run = (tid == 0) ? 0 : part[tid - 1];
  for (int i = 0; i < 64; i++) {
    off[base + i] = run;
    run += cnt[base + i];
  }
  if (tid == 255) off[NN] = run;
}
__global__ __launch_bounds__(256) void copy_i_kernel(const int* __restrict__ a, int* __restrict__ b, int n) {
  int i = blockIdx.x * 256 + threadIdx.x;
  if (i < n) b[i] = a[i];
}
__global__ __launch_bounds__(256) void fill_elist_kernel(const int* __restrict__ dst,
    int* __restrict__ cursor, int* __restrict__ elist, int e) {
  int i = blockIdx.x * 256 + threadIdx.x;
  if (i < e) {
    int p = atomicAdd(&cursor[dst[i]], 1);
    elist[p] = i;
  }
}
// gather edge data into CSR (dst-sorted) order
__global__ __launch_bounds__(256) void gather_edges_kernel(const int* __restrict__ elist,
    const int* __restrict__ eattr, const int* __restrict__ src, const int* __restrict__ dst,
    const float* __restrict__ edist, int* __restrict__ ea_s, int* __restrict__ src_s,
    int* __restrict__ dst_s, float* __restrict__ ed_s) {
  int j = blockIdx.x * 256 + threadIdx.x;
  if (j >= EE) return;
  int e = elist[j];
  ea_s[j * 3 + 0] = eattr[e * 3 + 0];
  ea_s[j * 3 + 1] = eattr[e * 3 + 1];
  ea_s[j * 3 + 2] = eattr[e * 3 + 2];
  src_s[j] = src[e];
  dst_s[j] = dst[e];
  ed_s[j] = edist[e];
}
// float4 elementwise
__global__ __launch_bounds__(256) void add3_kernel(float* __restrict__ dst,
    const float* __restrict__ a, const float* __restrict__ b, int n4) {
  int i = blockIdx.x * 256 + threadIdx.x;
  if (i >= n4) return;
  float4 x = reinterpret_cast<const float4*>(a)[i];
  float4 y = reinterpret_cast<const float4*>(b)[i];
  x.x += y.x; x.y += y.y; x.z += y.z; x.w += y.w;
  reinterpret_cast<float4*>(dst)[i] = x;
}
__global__ __launch_bounds__(256) void add3_both_kernel(float* __restrict__ dst, f16* __restrict__ dstH,
    const float* __restrict__ a, const float* __restrict__ b, int n4) {
  int i = blockIdx.x * 256 + threadIdx.x;
  if (i >= n4) return;
  float4 x = reinterpret_cast<const float4*>(a)[i];
  float4 y = reinterpret_cast<const float4*>(b)[i];
  x.x += y.x; x.y += y.y; x.z += y.z; x.w += y.w;
  reinterpret_cast<float4*>(dst)[i] = x;
  half4v h;
  h[0] = (f16)x.x; h[1] = (f16)x.y; h[2] = (f16)x.z; h[3] = (f16)x.w;
  reinterpret_cast<half4v*>(dstH)[i] = h;
}
__global__ __launch_bounds__(256) void bcast_add_kernel(float* __restrict__ ho,
    const float* __restrict__ vo, const float* __restrict__ vs, const int* __restrict__ batch) {
  int i4 = blockIdx.x * 256 + threadIdx.x;
  int i = i4 * 4;
  int n = i >> 8, c = i & 255;
  float4 h = reinterpret_cast<const float4*>(&ho[i])[0];
  float4 v = *reinterpret_cast<const float4*>(&vo[(size_t)batch[n] * 256 + c]);
  float4 s = *reinterpret_cast<const float4*>(&vs[c]);
  h.x += expf(s.x) * v.x; h.y += expf(s.y) * v.y;
  h.z += expf(s.z) * v.z; h.w += expf(s.w) * v.w;
  *reinterpret_cast<float4*>(&ho[i]) = h;
}
__global__ __launch_bounds__(256) void f2h_kernel(const float* __restrict__ in, f16* __restrict__ out, int n4) {
  int i = blockIdx.x * 256 + threadIdx.x;
  if (i >= n4) return;
  float4 v = reinterpret_cast<const float4*>(in)[i];
  half4v o;
  o[0] = (f16)v.x; o[1] = (f16)v.y; o[2] = (f16)v.z; o[3] = (f16)v.w;
  reinterpret_cast<half4v*>(out)[i] = o;
}

// ---------------- segment reduce over CONTIGUOUS CSR rows ----------------
template <typename OUT>
__global__ __launch_bounds__(256) void seg_reduce_kernel(const f16* __restrict__ msg,
    const int* __restrict__ off, OUT* __restrict__ out) {
  int idx = blockIdx.x * 256 + threadIdx.x;
  int n = idx >> 6, c0 = (idx & 63) * 4;
  int j0 = off[n], j1 = off[n + 1];
  float a0 = 0.f, a1 = 0.f, a2 = 0.f, a3 = 0.f;
  int j = j0;
  for (; j + 1 < j1; j += 2) {
    half4v m0 = *reinterpret_cast<const half4v*>(&msg[(size_t)j * 256 + c0]);
    half4v m1 = *reinterpret_cast<const half4v*>(&msg[(size_t)(j + 1) * 256 + c0]);
    a0 += (float)m0[0] + (float)m1[0];
    a1 += (float)m0[1] + (float)m1[1];
    a2 += (float)m0[2] + (float)m1[2];
    a3 += (float)m0[3] + (float)m1[3];
  }
  if (j < j1) {
    half4v m0 = *reinterpret_cast<const half4v*>(&msg[(size_t)j * 256 + c0]);
    a0 += (float)m0[0]; a1 += (float)m0[1]; a2 += (float)m0[2]; a3 += (float)m0[3];
  }
  if constexpr (std::is_same<OUT, float>::value) {
    float4 o = {a0, a1, a2, a3};
    *reinterpret_cast<float4*>(&out[(size_t)n * 256 + c0]) = o;
  } else {
    half4v o;
    o[0] = (f16)a0; o[1] = (f16)a1; o[2] = (f16)a2; o[3] = (f16)a3;
    *reinterpret_cast<half4v*>(&out[(size_t)n * 256 + c0]) = o;
  }
}

// ---------------- initial edge / node features (CSR order) ----------------

__global__ __launch_bounds__(256) void edge_feat_kernel(
    const int* __restrict__ ea_s, const float* __restrict__ ed_s,
    const float* __restrict__ bond2d, const float* __restrict__ gmeans,
    const float* __restrict__ gstds, const float* __restrict__ attn_w,
    const float* __restrict__ attn_b, f16* __restrict__ msg) {
  int lane = threadIdx.x & 63;
  int j = blockIdx.x * 4 + (threadIdx.x >> 6);
  if (j >= EE) return;
  int a0 = ea_s[j * 3 + 0], a1 = ea_s[j * 3 + 1], a2 = ea_s[j * 3 + 2];
  float dist = ed_s[j];
  const float SQ2PI = sqrtf(2.0f * 3.14159f);
  int c0 = lane * 4;
  float4 b0 = *reinterpret_cast<const float4*>(&bond2d[a0 * 256 + c0]);
  float4 b1 = *reinterpret_cast<const float4*>(&bond2d[2048 + a1 * 256 + c0]);
  float4 b2 = *reinterpret_cast<const float4*>(&bond2d[4096 + a2 * 256 + c0]);
  float4 gm = *reinterpret_cast<const float4*>(&gmeans[c0]);
  float4 gs = *reinterpret_cast<const float4*>(&gstds[c0]);
  float4 w2 = *reinterpret_cast<const float4*>(&attn_w[c0]);
  float4 w3 = *reinterpret_cast<const float4*>(&attn_w[256 + c0]);
  float h2[4], h3[4];
  float part = 0.f;
#pragma unroll
  for (int i = 0; i < 4; i++) {
    h2[i] = (&b0.x)[i] + (&b1.x)[i] + (&b2.x)[i];
    float sd = fabsf((&gs.x)[i]) + 0.01f;
    float df = (dist - (&gm.x)[i]) / sd;
    h3[i] = expf(-0.5f * df * df) / (SQ2PI * sd);
    part += (&w2.x)[i] * h2[i] + (&w3.x)[i] * h3[i];
  }
#pragma unroll
  for (int off = 32; off > 0; off >>= 1) part += __shfl_xor(part, off);
  float wg = 1.f / (1.f + expf(-(part + attn_b[0])));
  half4v o;
#pragma unroll
  for (int i = 0; i < 4; i++) o[i] = (f16)(wg * h2[i] + (1.f - wg) * h3[i]);
  *reinterpret_cast<half4v*>(&msg[(size_t)j * 256 + c0]) = o;
}

__global__ __launch_bounds__(256) void atom_finish_kernel(
    const int* __restrict__ xf, const float* __restrict__ emb,
    const float* __restrict__ scale_both, const int* __restrict__ deg,
    const float* __restrict__ tmp, float* __restrict__ h_in, f16* __restrict__ h_inH) {
  int idx = blockIdx.x * 256 + threadIdx.x;
  int n = idx >> 6, c = (idx & 63) * 4;
  float a0 = 0.f, a1 = 0.f, a2 = 0.f, a3 = 0.f;
#pragma unroll
  for (int f = 0; f < 9; f++) {
    int v = xf[n * 9 + f];
    float4 e = *reinterpret_cast<const float4*>(&emb[((size_t)(f * 128 + v)) * 256 + c]);
    a0 += e.x; a1 += e.y; a2 += e.z; a3 += e.w;
  }
  int dg = deg[n];
  float4 s = *reinterpret_cast<const float4*>(&scale_both[dg * 256 + c]);
  float4 t = *reinterpret_cast<const float4*>(&tmp[(size_t)n * 256 + c]);
  float4 r;
  r.x = a0 + expf(s.x) * t.x; r.y = a1 + expf(s.y) * t.y;
  r.z = a2 + expf(s.z) * t.z; r.w = a3 + expf(s.w) * t.w;
  *reinterpret_cast<float4*>(&h_in[(size_t)n * 256 + c]) = r;
  half4v h;
  h[0] = (f16)r.x; h[1] = (f16)r.y; h[2] = (f16)r.z; h[3] = (f16)r.w;
  *reinterpret_cast<half4v*>(&h_inH[(size_t)n * 256 + c]) = h;
}

// ---------------- fp16 MFMA GEMM, tile 128x64, 4 waves (2x2), BK=32, reg prefetch ----------------
// MODE 0: v=acc(+bias); C?=v; Cf?=f16(v)
// MODE 2: v=acc+bias; nv=Cadd[oi]+expf(scale[col])*v; C?=nv; Cf?=f16(nv)
// MODE 4: v=acc+cnt[row]*bias[col]; Cadd[oi]+=expf(scale[deg[row]*256+col])*v; Cf?=f16(v)
// MODE 5: like 4 but Cadd[oi]= (init store)
template <int MODE>
__global__ __launch_bounds__(256) void hgemm_kernel(
    const f16* __restrict__ A, const f16* __restrict__ W,
    const float* __restrict__ bias, const float* __restrict__ scale,
    const int* __restrict__ cnt, const int* __restrict__ deg,
    float* __restrict__ C, float* __restrict__ Cadd, f16* __restrict__ Cf, int K) {
  __shared__ f16 Ah[128 * 40];
  __shared__ f16 Wh[64 * 40];
  const int tid = threadIdx.x;
  const int row0 = blockIdx.x * 128, col0 = blockIdx.y * 64;
  const int lane = tid & 63;
  const int wave = tid >> 6;
  const int wr = (wave >> 1) * 64, wc = (wave & 1) * 32;
  const floatx4 fz = {0.f, 0.f, 0.f, 0.f};
  floatx4 acc[4][2];
#pragma unroll
  for (int m = 0; m < 4; m++)
#pragma unroll
    for (int n = 0; n < 2; n++) acc[m][n] = fz;
  const int q0 = tid * 2;
  const int rA0 = q0 >> 2, pA0 = q0 & 3;
  const int rA1 = (q0 + 1) >> 2, pA1 = (q0 + 1) & 3;
  const int rW = tid >> 2, pW = tid & 3;
  const int kb = (lane >> 4) * 8;
  const int fr = lane & 15;
  uint4 a0 = *reinterpret_cast<const uint4*>(&A[(size_t)(row0 + rA0) * K + pA0 * 8]);
  uint4 a1 = *reinterpret_cast<const uint4*>(&A[(size_t)(row0 + rA1) * K + pA1 * 8]);
  uint4 w0 = *reinterpret_cast<const uint4*>(&W[(size_t)(col0 + rW) * K + pW * 8]);
  for (int k0 = 0;;) {
    *reinterpret_cast<uint4*>(&Ah[rA0 * 40 + pA0 * 8]) = a0;
    *reinterpret_cast<uint4*>(&Ah[rA1 * 40 + pA1 * 8]) = a1;
    *reinterpret_cast<uint4*>(&Wh[rW * 40 + pW * 8]) = w0;
    __syncthreads();
    int kn = k0 + 32;
    if (kn < K) {
      a0 = *reinterpret_cast<const uint4*>(&A[(size_t)(row0 + rA0) * K + kn + pA0 * 8]);
      a1 = *reinterpret_cast<const uint4*>(&A[(size_t)(row0 + rA1) * K + kn + pA1 * 8]);
      w0 = *reinterpret_cast<const uint4*>(&W[(size_t)(col0 + rW) * K + kn + pW * 8]);
    }
    half8 af[4], wf[2];
#pragma unroll
    for (int m = 0; m < 4; m++)
      af[m] = *reinterpret_cast<const half8*>(&Ah[(wr + m * 16 + fr) * 40 + kb]);
#pragma unroll
    for (int n = 0; n < 2; n++)
      wf[n] = *reinterpret_cast<const half8*>(&Wh[(wc + n * 16 + fr) * 40 + kb]);
#pragma unroll
    for (int m = 0; m < 4; m++)
#pragma unroll
      for (int n = 0; n < 2; n++)
        acc[m][n] = __builtin_amdgcn_mfma_f32_16x16x32_f16(af[m], wf[n], acc[m][n], 0, 0, 0);
    if (kn >= K) break;
    __syncthreads();
    k0 = kn;
  }
  const int rl4 = (lane >> 4) * 4, cl = lane & 15;
#pragma unroll
  for (int m = 0; m < 4; m++) {
#pragma unroll
    for (int i = 0; i < 4; i++) {
      int row = row0 + wr + m * 16 + rl4 + i;
      float cb = (MODE >= 4) ? (float)cnt[row] : 1.f;
      int dg = (MODE >= 4) ? deg[row] : 0;
#pragma unroll
      for (int n = 0; n < 2; n++) {
        int col = col0 + wc + n * 16 + cl;
        float v = acc[m][n][i];
        size_t oi = (size_t)row * 256 + col;
        if (MODE >= 4) {
          v += cb * bias[col];
          float sc = expf(scale[dg * 256 + col]);
          if (MODE == 4) Cadd[oi] += sc * v;
          else Cadd[oi] = sc * v;
          if (Cf) Cf[oi] = (f16)v;
        } else if (MODE == 2) {
          v += bias[col];
          float nv = Cadd[oi] + expf(scale[col]) * v;
          if (C) C[oi] = nv;
          if (Cf) Cf[oi] = (f16)nv;
        } else {
          if (bias) v += bias[col];
          if (C) C[oi] = v;
          if (Cf) Cf[oi] = (f16)v;
        }
      }
    }
  }
}

// ---------------- conv edge (CSR order): gather(fp16) + bond(global) + GN + glin + product ----------------
__global__ __launch_bounds__(256) void conv_edge_kernel(
    const f16* __restrict__ xp, const int* __restrict__ ea_s,
    const int* __restrict__ src_s, const int* __restrict__ dst_s,
    const float* __restrict__ bond_emb, const float* __restrict__ gate_w,
    const float* __restrict__ val_w, f16* __restrict__ msg) {
  __shared__ float sg[16 * 260];  // [g][o*16+i], row stride 260 (bank-spread)
  __shared__ float sv[16 * 260];
  int tid = threadIdx.x;
  for (int i = tid; i < 4096; i += 256) {
    int g = i >> 8, rem = i & 255;
    sg[g * 260 + rem] = gate_w[i];
    sv[g * 260 + rem] = val_w[i];
  }
  __syncthreads();
  int idx = blockIdx.x * 256 + tid;
  int j = idx >> 4, g = idx & 15;
  int a0 = ea_s[j * 3 + 0], a1 = ea_s[j * 3 + 1], a2 = ea_s[j * 3 + 2];
  int d = dst_s[j], s = src_s[j];
  half8 xd0 = *reinterpret_cast<const half8*>(&xp[(size_t)d * 256 + g * 16]);
  half8 xd1 = *reinterpret_cast<const half8*>(&xp[(size_t)d * 256 + g * 16 + 8]);
  half8 xs0 = *reinterpret_cast<const half8*>(&xp[(size_t)s * 256 + g * 16]);
  half8 xs1 = *reinterpret_cast<const half8*>(&xp[(size_t)s * 256 + g * 16 + 8]);
  const float4* b0p = reinterpret_cast<const float4*>(&bond_emb[a0 * 256 + g * 16]);
  const float4* b1p = reinterpret_cast<const float4*>(&bond_emb[2048 + a1 * 256 + g * 16]);
  const float4* b2p = reinterpret_cast<const float4*>(&bond_emb[4096 + a2 * 256 + g * 16]);
  float xg[16], xv[16];
  float mg = 0.f, mv = 0.f;
#pragma unroll
  for (int q = 0; q < 4; q++) {
    float4 b0 = b0p[q], b1 = b1p[q], b2 = b2p[q];
#pragma unroll
    for (int t = 0; t < 4; t++) {
      int i = q * 4 + t;
      float bo = (&b0.x)[t] + (&b1.x)[t] + (&b2.x)[t];
      float xd = (i < 8) ? (float)xd0[i & 7] : (float)xd1[i & 7];
      float xs = (i < 8) ? (float)xs0[i & 7] : (float)xs1[i & 7];
      xg[i] = xd + bo;
      xv[i] = xs + bo;
      mg += xg[i];
      mv += xv[i];
    }
  }
  mg *= (1.f / 16.f);
  mv *= (1.f / 16.f);
  float vg = 0.f, vv = 0.f;
#pragma unroll
  for (int i = 0; i < 16; i++) {
    float dg_ = xg[i] - mg, dv_ = xv[i] - mv;
    vg += dg_ * dg_;
    vv += dv_ * dv_;
  }
  float rg = rsqrtf(vg * (1.f / 16.f) + 1e-5f);
  float rv = rsqrtf(vv * (1.f / 16.f) + 1e-5f);
#pragma unroll
  for (int i = 0; i < 16; i++) {
    xg[i] = (xg[i] - mg) * rg;
    xv[i] = (xv[i] - mv) * rv;
  }
  f16 res[16];
#pragma unroll
  for (int o = 0; o < 16; o++) {
    const float4* gp = reinterpret_cast<const float4*>(&sg[g * 260 + o * 16]);
    const float4* vp = reinterpret_cast<const float4*>(&sv[g * 260 + o * 16]);
    float ag = 0.f, av = 0.f;
#pragma unroll
    for (int q = 0; q < 4; q++) {
      float4 gq = gp[q], vq = vp[q];
#pragma unroll
      for (int t = 0; t < 4; t++) {
        ag += xg[q * 4 + t] * (&gq.x)[t];
        av += xv[q * 4 + t] * (&vq.x)[t];
      }
    }
    res[o] = (f16)(fmaxf(ag, 0.f) * av);
  }
  uint4* op = reinterpret_cast<uint4*>(&msg[(size_t)j * 256 + g * 16]);
  op[0] = reinterpret_cast<const uint4*>(res)[0];
  op[1] = reinterpret_cast<const uint4*>(res)[1];
}

// ---------------- glb middle: GN + glin + relu*mul (fp16 weights in LDS) ----------------
template <int DOUT>
__global__ __launch_bounds__(256) void glb_mid_kernel(
    const float* __restrict__ X, const float* __restrict__ gate_w,
    const float* __restrict__ val_w, f16* __restrict__ out) {
  __shared__ f16 sg[16 * DOUT * 16];
  __shared__ f16 sv[16 * DOUT * 16];
  int tid = threadIdx.x;
  for (int i = tid; i < 16 * DOUT * 16; i += 256) {
    int g = i / (DOUT * 16), rem = i % (DOUT * 16), o = rem >> 4, ii = rem & 15;
    int t = (o * 16 + ii) * 16 + g;
    sg[t] = (f16)gate_w[i];
    sv[t] = (f16)val_w[i];
  }
  __syncthreads();
  int idx = blockIdx.x * 256 + tid;
  int n = idx >> 4, g = idx & 15;
  float x[16];
  float m = 0.f;
  const float4* xp4 = reinterpret_cast<const float4*>(&X[(size_t)n * 256 + g * 16]);
#pragma unroll
  for (int q = 0; q < 4; q++) {
    float4 xq = xp4[q];
#pragma unroll
    for (int t = 0; t < 4; t++) {
      x[q * 4 + t] = (&xq.x)[t];
      m += (&xq.x)[t];
    }
  }
  m *= (1.f / 16.f);
  float v = 0.f;
#pragma unroll
  for (int i = 0; i < 16; i++) {
    float d_ = x[i] - m;
    v += d_ * d_;
  }
  float r = rsqrtf(v * (1.f / 16.f) + 1e-5f);
#pragma unroll
  for (int i = 0; i < 16; i++) x[i] = (x[i] - m) * r;
  f16* op = &out[(size_t)n * (16 * DOUT) + g * DOUT];
  for (int o = 0; o < DOUT; o++) {
    float ag = 0.f, av = 0.f;
#pragma unroll
    for (int i = 0; i < 16; i++) {
      ag += x[i] * (float)sg[(o * 16 + i) * 16 + g];
      av += x[i] * (float)sv[(o * 16 + i) * 16 + g];
    }
    op[o] = (f16)(fmaxf(ag, 0.f) * av);
  }
}

// vectorized GroupNorm in place
__global__ __launch_bounds__(256) void gn_vec_kernel(float* __restrict__ X) {
  int idx = blockIdx.x * 256 + threadIdx.x;
  int n = idx >> 6, q = idx & 63;
  float4 x = *reinterpret_cast<const float4*>(&X[(size_t)n * 256 + q * 4]);
  float s = x.x + x.y + x.z + x.w;
  float s2 = x.x * x.x + x.y * x.y + x.z * x.z + x.w * x.w;
  s += __shfl_xor(s, 1); s2 += __shfl_xor(s2, 1);
  s += __shfl_xor(s, 2); s2 += __shfl_xor(s2, 2);
  float m = s * (1.f / 16.f);
  float var = s2 * (1.f / 16.f) - m * m;
  float r = rsqrtf(var + 1e-5f);
  x.x = (x.x - m) * r; x.y = (x.y - m) * r;
  x.z = (x.z - m) * r; x.w = (x.w - m) * r;
  *reinterpret_cast<float4*>(&X[(size_t)n * 256 + q * 4]) = x;
}

// ---------------- attention ----------------
// h_att layout (workspace-internal): [b][h][head][v] = b*8192 + h*512 + head*16 + v
__global__ __launch_bounds__(256) void att_graph_kernel(
    const float* __restrict__ xv0, const float* __restrict__ k_w,
    const float* __restrict__ v_w, const int* __restrict__ goff,
    float* __restrict__ h_att, float* __restrict__ xk_sum) {
  __shared__ float kx[8][512];
  __shared__ float vx[8][512];
  __shared__ float rows[8][256];
  const int tid = threadIdx.x, b = blockIdx.x;
  float wk0[16], wv0[16], wk1[16], wv1[16];
#pragma unroll
  for (int i = 0; i < 4; i++) {
    float4 k0 = *reinterpret_cast<const float4*>(&k_w[tid * 16 + i * 4]);
    float4 v0 = *reinterpret_cast<const float4*>(&v_w[tid * 16 + i * 4]);
    float4 k1 = *reinterpret_cast<const float4*>(&k_w[(tid + 256) * 16 + i * 4]);
    float4 v1 = *reinterpret_cast<const float4*>(&v_w[(tid + 256) * 16 + i * 4]);
    wk0[i * 4 + 0] = k0.x; wk0[i * 4 + 1] = k0.y; wk0[i * 4 + 2] = k0.z; wk0[i * 4 + 3] = k0.w;
    wv0[i * 4 + 0] = v0.x; wv0[i * 4 + 1] = v0.y; wv0[i * 4 + 2] = v0.z; wv0[i * 4 + 3] = v0.w;
    wk1[i * 4 + 0] = k1.x; wk1[i * 4 + 1] = k1.y; wk1[i * 4 + 2] = k1.z; wk1[i * 4 + 3] = k1.w;
    wv1[i * 4 + 0] = v1.x; wv1[i * 4 + 1] = v1.y; wv1[i * 4 + 2] = v1.z; wv1[i * 4 + 3] = v1.w;
  }
  float hacc[2][16];
  const float* hg = &h_att[(size_t)b * 8192];
#pragma unroll
  for (int c = 0; c < 2; c++) {
    int p = tid + c * 256;
    int head = p >> 4, h = p & 15;
#pragma unroll
    for (int j = 0; j < 16; j++) hacc[c][j] = hg[h * 512 + head * 16 + j];
  }
  float ks0 = 0.f, ks1 = 0.f;
  const int n0 = goff[b], n1 = goff[b + 1];
  const int g0 = tid >> 5, g1 = (tid + 256) >> 5;
  float r[8];
#pragma unroll
  for (int nn = 0; nn < 8; nn++) {
    int n = n0 + nn;
    r[nn] = (n < n1) ? xv0[(size_t)n * 256 + tid] : 0.f;
  }
  for (int nbase = n0; nbase < n1; nbase += 8) {
#pragma unroll
    for (int nn = 0; nn < 8; nn++) rows[nn][tid] = r[nn];
    __syncthreads();
#pragma unroll
    for (int nn = 0; nn < 8; nn++) {
      int n = nbase + 8 + nn;
      r[nn] = (n < n1) ? xv0[(size_t)n * 256 + tid] : 0.f;
    }
#pragma unroll
    for (int nn = 0; nn < 8; nn++) {
      const float4* rp0 = reinterpret_cast<const float4*>(&rows[nn][g0 * 16]);
      const float4* rp1 = reinterpret_cast<const float4*>(&rows[nn][g1 * 16]);
      float aK0 = 0.f, aV0 = 0.f, aK1 = 0.f, aV1 = 0.f;
#pragma unroll
      for (int q = 0; q < 4; q++) {
        float4 x0 = rp0[q], x1 = rp1[q];
#pragma unroll
        for (int t = 0; t < 4; t++) {
          float e0 = (&x0.x)[t], e1 = (&x1.x)[t];
          aK0 += e0 * wk0[q * 4 + t];
          aV0 += e0 * wv0[q * 4 + t];
          aK1 += e1 * wk1[q * 4 + t];
          aV1 += e1 * wv1[q * 4 + t];
        }
      }
      bool valid = (nbase + nn) < n1;
      float ek0 = valid ? expf(aK0 * 0.25f) : 0.f;
      float ek1 = valid ? expf(aK1 * 0.25f) : 0.f;
      kx[nn][tid] = ek0;
      kx[nn][tid + 256] = ek1;
      vx[nn][tid] = aV0;
      vx[nn][tid + 256] = aV1;
      ks0 += ek0;
      ks1 += ek1;
    }
    __syncthreads();
#pragma unroll
    for (int c = 0; c < 2; c++) {
      int p = tid + c * 256;
      int head = p >> 4, h = p & 15;
#pragma unroll
      for (int nn = 0; nn < 8; nn++) {
        float kk = kx[nn][head * 16 + h];
        const float4* vp = reinterpret_cast<const float4*>(&vx[nn][head * 16]);
#pragma unroll
        for (int q = 0; q < 4; q++) {
          float4 vq = vp[q];
          hacc[c][q * 4 + 0] += kk * vq.x;
          hacc[c][q * 4 + 1] += kk * vq.y;
          hacc[c][q * 4 + 2] += kk * vq.z;
          hacc[c][q * 4 + 3] += kk * vq.w;
        }
      }
    }
    __syncthreads();
  }
  float* hgo = &h_att[(size_t)b * 8192];
#pragma unroll
  for (int c = 0; c < 2; c++) {
    int p = tid + c * 256;
    int head = p >> 4, h = p & 15;
#pragma unroll
    for (int j = 0; j < 16; j++) hgo[h * 512 + head * 16 + j] = hacc[c][j];
  }
  xk_sum[(size_t)b * 512 + tid] = ks0;
  xk_sum[(size_t)b * 512 + tid + 256] = ks1;
}

// wave = 1 node; lane = (head, half): head=lane>>1, half=lane&1 handles v in [half*8, half*8+8)
__global__ __launch_bounds__(256) void att_out_kernel(
    const float* __restrict__ xv0, const float* __restrict__ q_w,
    const float* __restrict__ xk_sum, const float* __restrict__ h_att,
    const int* __restrict__ batch, f16* __restrict__ out) {
  __shared__ float sqw[16 * 260];  // [g][oo*16+i], stride 260 (16B aligned, bank-spread)
  int tid = threadIdx.x;
  for (int i = tid; i < 8192; i += 256) {
    int g = i >> 9, rem = i & 511;  // q_w layout [g][32][16]
    sqw[g * 260 + rem] = q_w[i];
  }
  __syncthreads();
  int wave = tid >> 6, lane = tid & 63;
  int n = blockIdx.x * 4 + wave;
  int head = lane >> 1, half = lane & 1;
  int g = head >> 1, j = head & 1;
  int b = batch[n];
  float x[16];
  const float4* xp4 = reinterpret_cast<const float4*>(&xv0[(size_t)n * 256 + g * 16]);
#pragma unroll
  for (int q = 0; q < 4; q++) {
    float4 xq = xp4[q];
#pragma unroll
    for (int t = 0; t < 4; t++) x[q * 4 + t] = (&xq.x)[t];
  }
  float qv[16];
  float denom = 0.f;
  const float* ks = &xk_sum[(size_t)b * 512 + head * 16];
#pragma unroll
  for (int h = 0; h < 16; h++) {
    const float4* wp = reinterpret_cast<const float4*>(&sqw[g * 260 + (j * 16 + h) * 16]);
    float a = 0.f;
#pragma unroll
    for (int q = 0; q < 4; q++) {
      float4 wq = wp[q];
#pragma unroll
      for (int t = 0; t < 4; t++) a += x[q * 4 + t] * (&wq.x)[t];
    }
    float e = expf(a * 0.25f);
    qv[h] = e;
    denom += e * ks[h];
  }
  float inv = 1.f / denom;
  float acc[8] = {0.f, 0.f, 0.f, 0.f, 0.f, 0.f, 0.f, 0.f};
  const float* hb = &h_att[(size_t)b * 8192 + head * 16 + half * 8];
#pragma unroll
  for (int h = 0; h < 16; h++) {
    float4 v0 = *reinterpret_cast<const float4*>(&hb[h * 512]);
    float4 v1 = *reinterpret_cast<const float4*>(&hb[h * 512 + 4]);
    float qh = qv[h];
    acc[0] += qh * v0.x; acc[1] += qh * v0.y; acc[2] += qh * v0.z; acc[3] += qh * v0.w;
    acc[4] += qh * v1.x; acc[5] += qh * v1.y; acc[6] += qh * v1.z; acc[7] += qh * v1.w;
  }
  half8 res;
#pragma unroll
  for (int v = 0; v < 8; v++) res[v] = (f16)(acc[v] * inv);
  *reinterpret_cast<half8*>(&out[(size_t)n * 512 + head * 16 + half * 8]) = res;
}

__global__ __launch_bounds__(256) void virt_seg_kernel(const float* __restrict__ h_in,
    const int* __restrict__ goff, float* __restrict__ h_virt) {
  int b = blockIdx.x, c = threadIdx.x;
  float acc = h_virt[(size_t)b * 256 + c];
  int n0 = goff[b], n1 = goff[b + 1];
  for (int n = n0; n < n1; n++) acc += h_in[(size_t)n * 256 + c];
  h_virt[(size_t)b * 256 + c] = acc;
}

// ---------------- host driver ----------------

extern "C" void kernel_launch(void* const* d_in, const int* in_sizes, int n_in,
                              void* d_out, int out_size, void* d_ws, size_t ws_size,
                              hipStream_t stream) {
  const int* x_feat = (const int*)d_in[0];
  const int* eidx = (const int*)d_in[1];
  const int* eattr = (const int*)d_in[2];
  const int* batch = (const int*)d_in[3];
  const float* edist = (const float*)d_in[5];
  const float* atom_emb = (const float*)d_in[6];
  const float* bond2d = (const float*)d_in[7];
  const float* gmeans = (const float*)d_in[8];
  const float* gstds = (const float*)d_in[9];
  const float* attn_w = (const float*)d_in[10];
  const float* attn_b = (const float*)d_in[11];
  const float* scale_both = (const float*)d_in[12];
  const float* conv_bond_emb = (const float*)d_in[13];
  const float* conv_pre_w = (const float*)d_in[14];
  const float* conv_gate_w = (const float*)d_in[15];
  const float* conv_val_w = (const float*)d_in[16];
  const float* conv_post_w = (const float*)d_in[17];
  const float* conv_post_b = (const float*)d_in[18];
  const float* conv_scale = (const float*)d_in[19];
  const float* virt_pre_w = (const float*)d_in[20];
  const float* virt_pre_b = (const float*)d_in[21];
  const float* virt_gate_w = (const float*)d_in[22];
  const float* virt_val_w = (const float*)d_in[23];
  const float* virt_post_w = (const float*)d_in[24];
  const float* virt_post_b = (const float*)d_in[25];
  const float* virt_scale = (const float*)d_in[26];
  const float* att_pre_w = (const float*)d_in[27];
  const float* att_pre_b = (const float*)d_in[28];
  const float* att_q_w = (const float*)d_in[29];
  const float* att_k_w = (const float*)d_in[30];
  const float* att_v_w = (const float*)d_in[31];
  const float* att_post_w = (const float*)d_in[32];
  const float* att_post_b = (const float*)d_in[33];
  const float* att_scale = (const float*)d_in[34];
  const float* main_pre_w = (const float*)d_in[35];
  const float* main_pre_b = (const float*)d_in[36];
  const float* main_gate_w = (const float*)d_in[37];
  const float* main_val_w = (const float*)d_in[38];
  const float* main_post_w = (const float*)d_in[39];
  const float* main_post_b = (const float*)d_in[40];

  const int* src = eidx;
  const int* dst = eidx + EE;

  float* ws = (float*)d_ws;
  float* h_in = ws;
  float* h_out = ws + ND;
  float* x_raw = ws + 2 * ND;
  float* x_out = ws + 3 * ND;
  float* nodeA = ws + 4 * ND;
  f16* h_inH = (f16*)(ws + 5 * ND);
  f16* xrawH = (f16*)(ws + 5 * ND + ND / 2);
  f16* hTmp = (f16*)(ws + 6 * ND);
  f16* msgH = (f16*)(ws + 6 * ND + ND / 2);   // 3*ND halfs
  float* sm = ws + 8 * ND;
  f16* hW = (f16*)sm;                          // 2359296 halfs = 1179648 floats
  float* h_virt = sm + 1179648;
  float* h_att = h_virt + 65536;
  float* xk_sum = h_att + 2097152;
  float* vt1 = xk_sum + 131072;
  float* vout = vt1 + 65536;
  f16* vmidH = (f16*)(vout + 65536);           // B*512 halfs
  f16* virtH = vmidH + 131072;                 // B*256 halfs
  int* cnt = (int*)(virtH + 65536);
  int* deg = cnt + NN;
  int* goff = deg + NN;
  int* off = goff + BB + 1;
  int* cursor = off + NN + 1;
  int* elist = cursor + NN;
  int* ea_s = elist + EE;
  int* src_s = ea_s + 3 * EE;
  int* dst_s = src_s + EE;
  float* ed_s = (float*)(dst_s + EE);

  f16* wCpre = hW;
  f16* wCpost = hW + 524288;
  f16* wApre = hW + 1048576;
  f16* wApost = hW + 1179648;
  f16* wMpre = hW + 1441792;
  f16* wMpost = hW + 1572864;
  f16* wVpre = hW + 1966080;
  f16* wVpost = hW + 2097152;

  auto cvt = [&](const float* in, f16* out, int n) {
    f2h_kernel<<<n / 4 / 256, 256, 0, stream>>>(in, out, n / 4);
  };

  cvt(conv_pre_w, wCpre, 524288);
  cvt(conv_post_w, wCpost, 524288);
  cvt(att_pre_w, wApre, 131072);
  cvt(att_post_w, wApost, 262144);
  cvt(main_pre_w, wMpre, 131072);
  cvt(main_post_w, wMpost, 393216);
  cvt(virt_pre_w, wVpre, 131072);
  cvt(virt_post_w, wVpost, 262144);

  // degree + graph offsets + CSR (edges grouped by dst) + gathered edge data
  (void)hipMemsetAsync(cnt, 0, NN * sizeof(int), stream);
  count_deg_kernel<<<EE / 256, 256, 0, stream>>>(dst, cnt, EE);
  clip_deg_kernel<<<NN / 256, 256, 0, stream>>>(cnt, deg, NN);
  goff_kernel<<<(NN + 256) / 256, 256, 0, stream>>>(batch, goff, NN, BB);
  scan_off_kernel<<<1, 256, 0, stream>>>(cnt, off);
  copy_i_kernel<<<NN / 256, 256, 0, stream>>>(off, cursor, NN);
  fill_elist_kernel<<<EE / 256, 256, 0, stream>>>(dst, cursor, elist, EE);
  gather_edges_kernel<<<EE / 256, 256, 0, stream>>>(elist, eattr, src, dst, edist,
                                                    ea_s, src_s, dst_s, ed_s);

  // initial node features
  edge_feat_kernel<<<EE / 4, 256, 0, stream>>>(ea_s, ed_s, bond2d, gmeans, gstds,
                                               attn_w, attn_b, msgH);
  seg_reduce_kernel<float><<<NN / 4, 256, 0, stream>>>(msgH, off, x_out);
  atom_finish_kernel<<<NN * 64 / 256, 256, 0, stream>>>(x_feat, atom_emb, scale_both, deg,
                                                        x_out, h_in, h_inH);
  (void)hipMemsetAsync(h_virt, 0, 65536 * 4, stream);
  (void)hipMemsetAsync(h_att, 0, 2097152 * 4, stream);

  const dim3 gN(NN / 128, 4), gB(BB / 128, 4);
  const int n4 = (int)(ND / 4);

  for (int l = 0; l < 2; l++) {
    // ---- ConvMessage ----
    const f16* curH = h_inH;
    for (int k = 0; k < 4; k++) {
      if (k == 2) {
        add3_both_kernel<<<n4 / 256, 256, 0, stream>>>(x_raw, xrawH, h_in, x_out, n4);
        curH = xrawH;
      }
      size_t lk = (size_t)(l * 4 + k);
      hgemm_kernel<0><<<gN, 256, 0, stream>>>(curH, wCpre + lk * 65536, nullptr, nullptr,
                                              nullptr, nullptr, nullptr, nullptr, hTmp, 256);
      conv_edge_kernel<<<EE * 16 / 256, 256, 0, stream>>>(
          hTmp, ea_s, src_s, dst_s, conv_bond_emb + lk * 6144,
          conv_gate_w + lk * 4096, conv_val_w + lk * 4096, msgH);
      seg_reduce_kernel<f16><<<NN / 4, 256, 0, stream>>>(msgH, off, hTmp);
      if (k == 0 || k == 2)
        hgemm_kernel<5><<<gN, 256, 0, stream>>>(hTmp, wCpost + lk * 65536,
                                                conv_post_b + lk * 256, conv_scale + lk * 1024,
                                                cnt, deg, nullptr, x_out, xrawH, 256);
      else
        hgemm_kernel<4><<<gN, 256, 0, stream>>>(hTmp, wCpost + lk * 65536,
                                                conv_post_b + lk * 256, conv_scale + lk * 1024,
                                                cnt, deg, nullptr, x_out, xrawH, 256);
      curH = xrawH;
    }
    add3_kernel<<<n4 / 256, 256, 0, stream>>>(h_out, h_in, x_out, n4);

    // ---- VirtMessage ----
    virt_seg_kernel<<<BB, 256, 0, stream>>>(h_in, goff, h_virt);
    cvt(h_virt, virtH, 65536);
    hgemm_kernel<0><<<gB, 256, 0, stream>>>(virtH, wVpre + (size_t)l * 65536,
                                            virt_pre_b + (size_t)l * 256, nullptr, nullptr,
                                            nullptr, vt1, nullptr, nullptr, 256);
    glb_mid_kernel<32><<<BB * 16 / 256, 256, 0, stream>>>(
        vt1, virt_gate_w + (size_t)l * 8192, virt_val_w + (size_t)l * 8192, vmidH);
    hgemm_kernel<0><<<gB, 256, 0, stream>>>(vmidH, wVpost + (size_t)l * 131072,
                                            virt_post_b + (size_t)l * 256, nullptr, nullptr,
                                            nullptr, vout, nullptr, nullptr, 512);
    bcast_add_kernel<<<n4 / 256, 256, 0, stream>>>(
        h_out, vout, virt_scale + (size_t)l * 256, batch);

    // ---- AttMessage ----
    hgemm_kernel<0><<<gN, 256, 0, stream>>>(h_inH, wApre + (size_t)l * 65536,
                                            att_pre_b + (size_t)l * 256, nullptr, nullptr,
                                            nullptr, nodeA, nullptr, nullptr, 256);
    gn_vec_kernel<<<NN * 64 / 256, 256, 0, stream>>>(nodeA);
    att_graph_kernel<<<BB, 256, 0, stream>>>(
        nodeA, att_k_w + (size_t)l * 8192, att_v_w + (size_t)l * 8192, goff, h_att, xk_sum);
    att_out_kernel<<<NN / 4, 256, 0, stream>>>(
        nodeA, att_q_w + (size_t)l * 8192, xk_sum, h_att, batch, msgH);
    hgemm_kernel<2><<<gN, 256, 0, stream>>>(msgH, wApost + (size_t)l * 131072,
                                            att_post_b + (size_t)l * 256,
                                            att_scale + (size_t)l * 256, nullptr, nullptr,
                                            nullptr, h_out, hTmp, 512);

    // ---- main gated block ----
    hgemm_kernel<0><<<gN, 256, 0, stream>>>(hTmp, wMpre + (size_t)l * 65536,
                                            main_pre_b + (size_t)l * 256, nullptr, nullptr,
                                            nullptr, nodeA, nullptr, nullptr, 256);
    glb_mid_kernel<48><<<NN * 16 / 256, 256, 0, stream>>>(
        nodeA, main_gate_w + (size_t)l * 12288, main_val_w + (size_t)l * 12288, msgH);
    float* hdst = (l == 1) ? (float*)d_out : h_in;
    f16* hdstH = (l == 1) ? nullptr : h_inH;
    hgemm_kernel<0><<<gN, 256, 0, stream>>>(msgH, wMpost + (size_t)l * 196608,
                                            main_post_b + (size_t)l * 256, nullptr, nullptr,
                                            nullptr, hdst, nullptr, hdstH, 768);
  }
}

// Round 8
// 1137.813 us; speedup vs baseline: 6.1271x; 1.0533x over previous
//
#include <hip/hip_runtime.h>
#include <cstdint>
#include <cstddef>
#include <type_traits>

#define NN 16384
#define EE 49152
#define BB 256
// D=256, G=16, 16 channels per group, HD=16

typedef _Float16 f16;
typedef _Float16 half8 __attribute__((ext_vector_type(8)));
typedef _Float16 half4v __attribute__((ext_vector_type(4)));
typedef _Float16 half2v __attribute__((ext_vector_type(2)));
typedef float floatx4 __attribute__((ext_vector_type(4)));

#if defined(__has_builtin)
#if __has_builtin(__builtin_amdgcn_fdot2)
#define HAVE_FDOT2 1
#endif
#endif

static constexpr size_t ND = (size_t)NN * 256;

// ---------------- setup kernels ----------------

__global__ __launch_bounds__(256) void count_deg_kernel(const int* __restrict__ dst, int* __restrict__ cnt, int e) {
  int i = blockIdx.x * 256 + threadIdx.x;
  if (i < e) atomicAdd(&cnt[dst[i]], 1);
}
__global__ __launch_bounds__(256) void clip_deg_kernel(const int* __restrict__ cnt, int* __restrict__ deg, int n) {
  int i = blockIdx.x * 256 + threadIdx.x;
  if (i < n) { int v = cnt[i] - 1; deg[i] = v < 0 ? 0 : (v > 3 ? 3 : v); }
}
__global__ __launch_bounds__(256) void goff_kernel(const int* __restrict__ batch, int* __restrict__ goff, int n, int b) {
  int i = blockIdx.x * 256 + threadIdx.x;
  if (i > n) return;
  int cur = (i < n) ? batch[i] : b;
  int prev = (i == 0) ? -1 : batch[i - 1];
  for (int x = prev + 1; x <= cur; x++) goff[x] = i;
}
__global__ __launch_bounds__(256) void scan_off_kernel(const int* __restrict__ cnt, int* __restrict__ off) {
  __shared__ int part[256];
  int tid = threadIdx.x;
  int base = tid * 64;
  int s = 0;
  for (int i = 0; i < 64; i++) s += cnt[base + i];
  part[tid] = s;
  __syncthreads();
  for (int o = 1; o < 256; o <<= 1) {
    int t = (tid >= o) ? part[tid - o] : 0;
    __syncthreads();
    part[tid] += t;
    __syncthreads();
  }
  int run = (tid == 0) ? 0 : part[tid - 1];
  for (int i = 0; i < 64; i++) {
    off[base + i] = run;
    run += cnt[base + i];
  }
  if (tid == 255) off[NN] = run;
}
__global__ __launch_bounds__(256) void copy_i_kernel(const int* __restrict__ a, int* __restrict__ b, int n) {
  int i = blockIdx.x * 256 + threadIdx.x;
  if (i < n) b[i] = a[i];
}
__global__ __launch_bounds__(256) void fill_elist_kernel(const int* __restrict__ dst,
    int* __restrict__ cursor, int* __restrict__ elist, int e) {
  int i = blockIdx.x * 256 + threadIdx.x;
  if (i < e) {
    int p = atomicAdd(&cursor[dst[i]], 1);
    elist[p] = i;
  }
}
// gather edge data into CSR (dst-sorted) order
__global__ __launch_bounds__(256) void gather_edges_kernel(const int* __restrict__ elist,
    const int* __restrict__ eattr, const int* __restrict__ src, const int* __restrict__ dst,
    const float* __restrict__ edist, int* __restrict__ ea_s, int* __restrict__ src_s,
    int* __restrict__ dst_s, float* __restrict__ ed_s) {
  int j = blockIdx.x * 256 + threadIdx.x;
  if (j >= EE) return;
  int e = elist[j];
  ea_s[j * 3 + 0] = eattr[e * 3 + 0];
  ea_s[j * 3 + 1] = eattr[e * 3 + 1];
  ea_s[j * 3 + 2] = eattr[e * 3 + 2];
  src_s[j] = src[e];
  dst_s[j] = dst[e];
  ed_s[j] = edist[e];
}
// float4 elementwise
__global__ __launch_bounds__(256) void add3_kernel(float* __restrict__ dst,
    const float* __restrict__ a, const float* __restrict__ b, int n4) {
  int i = blockIdx.x * 256 + threadIdx.x;
  if (i >= n4) return;
  float4 x = reinterpret_cast<const float4*>(a)[i];
  float4 y = reinterpret_cast<const float4*>(b)[i];
  x.x += y.x; x.y += y.y; x.z += y.z; x.w += y.w;
  reinterpret_cast<float4*>(dst)[i] = x;
}
__global__ __launch_bounds__(256) void add3_both_kernel(float* __restrict__ dst, f16* __restrict__ dstH,
    const float* __restrict__ a, const float* __restrict__ b, int n4) {
  int i = blockIdx.x * 256 + threadIdx.x;
  if (i >= n4) return;
  float4 x = reinterpret_cast<const float4*>(a)[i];
  float4 y = reinterpret_cast<const float4*>(b)[i];
  x.x += y.x; x.y += y.y; x.z += y.z; x.w += y.w;
  reinterpret_cast<float4*>(dst)[i] = x;
  half4v h;
  h[0] = (f16)x.x; h[1] = (f16)x.y; h[2] = (f16)x.z; h[3] = (f16)x.w;
  reinterpret_cast<half4v*>(dstH)[i] = h;
}
__global__ __launch_bounds__(256) void bcast_add_kernel(float* __restrict__ ho,
    const float* __restrict__ vo, const float* __restrict__ vs, const int* __restrict__ batch) {
  int i4 = blockIdx.x * 256 + threadIdx.x;
  int i = i4 * 4;
  int n = i >> 8, c = i & 255;
  float4 h = reinterpret_cast<const float4*>(&ho[i])[0];
  float4 v = *reinterpret_cast<const float4*>(&vo[(size_t)batch[n] * 256 + c]);
  float4 s = *reinterpret_cast<const float4*>(&vs[c]);
  h.x += expf(s.x) * v.x; h.y += expf(s.y) * v.y;
  h.z += expf(s.z) * v.z; h.w += expf(s.w) * v.w;
  *reinterpret_cast<float4*>(&ho[i]) = h;
}
__global__ __launch_bounds__(256) void f2h_kernel(const float* __restrict__ in, f16* __restrict__ out, int n4) {
  int i = blockIdx.x * 256 + threadIdx.x;
  if (i >= n4) return;
  float4 v = reinterpret_cast<const float4*>(in)[i];
  half4v o;
  o[0] = (f16)v.x; o[1] = (f16)v.y; o[2] = (f16)v.z; o[3] = (f16)v.w;
  reinterpret_cast<half4v*>(out)[i] = o;
}

// ---------------- segment reduce over CONTIGUOUS CSR rows ----------------
template <typename OUT>
__global__ __launch_bounds__(256) void seg_reduce_kernel(const f16* __restrict__ msg,
    const int* __restrict__ off, OUT* __restrict__ out) {
  int idx = blockIdx.x * 256 + threadIdx.x;
  int n = idx >> 6, c0 = (idx & 63) * 4;
  int j0 = off[n], j1 = off[n + 1];
  float a0 = 0.f, a1 = 0.f, a2 = 0.f, a3 = 0.f;
  int j = j0;
  for (; j + 1 < j1; j += 2) {
    half4v m0 = *reinterpret_cast<const half4v*>(&msg[(size_t)j * 256 + c0]);
    half4v m1 = *reinterpret_cast<const half4v*>(&msg[(size_t)(j + 1) * 256 + c0]);
    a0 += (float)m0[0] + (float)m1[0];
    a1 += (float)m0[1] + (float)m1[1];
    a2 += (float)m0[2] + (float)m1[2];
    a3 += (float)m0[3] + (float)m1[3];
  }
  if (j < j1) {
    half4v m0 = *reinterpret_cast<const half4v*>(&msg[(size_t)j * 256 + c0]);
    a0 += (float)m0[0]; a1 += (float)m0[1]; a2 += (float)m0[2]; a3 += (float)m0[3];
  }
  if constexpr (std::is_same<OUT, float>::value) {
    float4 o = {a0, a1, a2, a3};
    *reinterpret_cast<float4*>(&out[(size_t)n * 256 + c0]) = o;
  } else {
    half4v o;
    o[0] = (f16)a0; o[1] = (f16)a1; o[2] = (f16)a2; o[3] = (f16)a3;
    *reinterpret_cast<half4v*>(&out[(size_t)n * 256 + c0]) = o;
  }
}

// ---------------- initial edge / node features (CSR order) ----------------

__global__ __launch_bounds__(256) void edge_feat_kernel(
    const int* __restrict__ ea_s, const float* __restrict__ ed_s,
    const float* __restrict__ bond2d, const float* __restrict__ gmeans,
    const float* __restrict__ gstds, const float* __restrict__ attn_w,
    const float* __restrict__ attn_b, f16* __restrict__ msg) {
  int lane = threadIdx.x & 63;
  int j = blockIdx.x * 4 + (threadIdx.x >> 6);
  if (j >= EE) return;
  int a0 = ea_s[j * 3 + 0], a1 = ea_s[j * 3 + 1], a2 = ea_s[j * 3 + 2];
  float dist = ed_s[j];
  const float SQ2PI = sqrtf(2.0f * 3.14159f);
  int c0 = lane * 4;
  float4 b0 = *reinterpret_cast<const float4*>(&bond2d[a0 * 256 + c0]);
  float4 b1 = *reinterpret_cast<const float4*>(&bond2d[2048 + a1 * 256 + c0]);
  float4 b2 = *reinterpret_cast<const float4*>(&bond2d[4096 + a2 * 256 + c0]);
  float4 gm = *reinterpret_cast<const float4*>(&gmeans[c0]);
  float4 gs = *reinterpret_cast<const float4*>(&gstds[c0]);
  float4 w2 = *reinterpret_cast<const float4*>(&attn_w[c0]);
  float4 w3 = *reinterpret_cast<const float4*>(&attn_w[256 + c0]);
  float h2[4], h3[4];
  float part = 0.f;
#pragma unroll
  for (int i = 0; i < 4; i++) {
    h2[i] = (&b0.x)[i] + (&b1.x)[i] + (&b2.x)[i];
    float sd = fabsf((&gs.x)[i]) + 0.01f;
    float df = (dist - (&gm.x)[i]) / sd;
    h3[i] = expf(-0.5f * df * df) / (SQ2PI * sd);
    part += (&w2.x)[i] * h2[i] + (&w3.x)[i] * h3[i];
  }
#pragma unroll
  for (int off = 32; off > 0; off >>= 1) part += __shfl_xor(part, off);
  float wg = 1.f / (1.f + expf(-(part + attn_b[0])));
  half4v o;
#pragma unroll
  for (int i = 0; i < 4; i++) o[i] = (f16)(wg * h2[i] + (1.f - wg) * h3[i]);
  *reinterpret_cast<half4v*>(&msg[(size_t)j * 256 + c0]) = o;
}

__global__ __launch_bounds__(256) void atom_finish_kernel(
    const int* __restrict__ xf, const float* __restrict__ emb,
    const float* __restrict__ scale_both, const int* __restrict__ deg,
    const float* __restrict__ tmp, float* __restrict__ h_in, f16* __restrict__ h_inH) {
  int idx = blockIdx.x * 256 + threadIdx.x;
  int n = idx >> 6, c = (idx & 63) * 4;
  float a0 = 0.f, a1 = 0.f, a2 = 0.f, a3 = 0.f;
#pragma unroll
  for (int f = 0; f < 9; f++) {
    int v = xf[n * 9 + f];
    float4 e = *reinterpret_cast<const float4*>(&emb[((size_t)(f * 128 + v)) * 256 + c]);
    a0 += e.x; a1 += e.y; a2 += e.z; a3 += e.w;
  }
  int dg = deg[n];
  float4 s = *reinterpret_cast<const float4*>(&scale_both[dg * 256 + c]);
  float4 t = *reinterpret_cast<const float4*>(&tmp[(size_t)n * 256 + c]);
  float4 r;
  r.x = a0 + expf(s.x) * t.x; r.y = a1 + expf(s.y) * t.y;
  r.z = a2 + expf(s.z) * t.z; r.w = a3 + expf(s.w) * t.w;
  *reinterpret_cast<float4*>(&h_in[(size_t)n * 256 + c]) = r;
  half4v h;
  h[0] = (f16)r.x; h[1] = (f16)r.y; h[2] = (f16)r.z; h[3] = (f16)r.w;
  *reinterpret_cast<half4v*>(&h_inH[(size_t)n * 256 + c]) = h;
}

// ---------------- fp16 MFMA GEMM, tile 128x64, 4 waves (2x2), BK=32, reg prefetch ----------------
// MODE 0: v=acc(+bias); C?=v; Cf?=f16(v)
// MODE 2: v=acc+bias; nv=Cadd[oi]+expf(scale[col])*v; C?=nv; Cf?=f16(nv)
// MODE 4: v=acc+cnt[row]*bias[col]; Cadd[oi]+=expf(scale[deg[row]*256+col])*v; Cf?=f16(v)
// MODE 5: like 4 but Cadd[oi]= (init store)
template <int MODE>
__global__ __launch_bounds__(256) void hgemm_kernel(
    const f16* __restrict__ A, const f16* __restrict__ W,
    const float* __restrict__ bias, const float* __restrict__ scale,
    const int* __restrict__ cnt, const int* __restrict__ deg,
    float* __restrict__ C, float* __restrict__ Cadd, f16* __restrict__ Cf, int K) {
  __shared__ f16 Ah[128 * 40];
  __shared__ f16 Wh[64 * 40];
  const int tid = threadIdx.x;
  const int row0 = blockIdx.x * 128, col0 = blockIdx.y * 64;
  const int lane = tid & 63;
  const int wave = tid >> 6;
  const int wr = (wave >> 1) * 64, wc = (wave & 1) * 32;
  const floatx4 fz = {0.f, 0.f, 0.f, 0.f};
  floatx4 acc[4][2];
#pragma unroll
  for (int m = 0; m < 4; m++)
#pragma unroll
    for (int n = 0; n < 2; n++) acc[m][n] = fz;
  const int q0 = tid * 2;
  const int rA0 = q0 >> 2, pA0 = q0 & 3;
  const int rA1 = (q0 + 1) >> 2, pA1 = (q0 + 1) & 3;
  const int rW = tid >> 2, pW = tid & 3;
  const int kb = (lane >> 4) * 8;
  const int fr = lane & 15;
  uint4 a0 = *reinterpret_cast<const uint4*>(&A[(size_t)(row0 + rA0) * K + pA0 * 8]);
  uint4 a1 = *reinterpret_cast<const uint4*>(&A[(size_t)(row0 + rA1) * K + pA1 * 8]);
  uint4 w0 = *reinterpret_cast<const uint4*>(&W[(size_t)(col0 + rW) * K + pW * 8]);
  for (int k0 = 0;;) {
    *reinterpret_cast<uint4*>(&Ah[rA0 * 40 + pA0 * 8]) = a0;
    *reinterpret_cast<uint4*>(&Ah[rA1 * 40 + pA1 * 8]) = a1;
    *reinterpret_cast<uint4*>(&Wh[rW * 40 + pW * 8]) = w0;
    __syncthreads();
    int kn = k0 + 32;
    if (kn < K) {
      a0 = *reinterpret_cast<const uint4*>(&A[(size_t)(row0 + rA0) * K + kn + pA0 * 8]);
      a1 = *reinterpret_cast<const uint4*>(&A[(size_t)(row0 + rA1) * K + kn + pA1 * 8]);
      w0 = *reinterpret_cast<const uint4*>(&W[(size_t)(col0 + rW) * K + kn + pW * 8]);
    }
    half8 af[4], wf[2];
#pragma unroll
    for (int m = 0; m < 4; m++)
      af[m] = *reinterpret_cast<const half8*>(&Ah[(wr + m * 16 + fr) * 40 + kb]);
#pragma unroll
    for (int n = 0; n < 2; n++)
      wf[n] = *reinterpret_cast<const half8*>(&Wh[(wc + n * 16 + fr) * 40 + kb]);
#pragma unroll
    for (int m = 0; m < 4; m++)
#pragma unroll
      for (int n = 0; n < 2; n++)
        acc[m][n] = __builtin_amdgcn_mfma_f32_16x16x32_f16(af[m], wf[n], acc[m][n], 0, 0, 0);
    if (kn >= K) break;
    __syncthreads();
    k0 = kn;
  }
  const int rl4 = (lane >> 4) * 4, cl = lane & 15;
#pragma unroll
  for (int m = 0; m < 4; m++) {
#pragma unroll
    for (int i = 0; i < 4; i++) {
      int row = row0 + wr + m * 16 + rl4 + i;
      float cb = (MODE >= 4) ? (float)cnt[row] : 1.f;
      int dg = (MODE >= 4) ? deg[row] : 0;
#pragma unroll
      for (int n = 0; n < 2; n++) {
        int col = col0 + wc + n * 16 + cl;
        float v = acc[m][n][i];
        size_t oi = (size_t)row * 256 + col;
        if (MODE >= 4) {
          v += cb * bias[col];
          float sc = expf(scale[dg * 256 + col]);
          if (MODE == 4) Cadd[oi] += sc * v;
          else Cadd[oi] = sc * v;
          if (Cf) Cf[oi] = (f16)v;
        } else if (MODE == 2) {
          v += bias[col];
          float nv = Cadd[oi] + expf(scale[col]) * v;
          if (C) C[oi] = nv;
          if (Cf) Cf[oi] = (f16)nv;
        } else {
          if (bias) v += bias[col];
          if (C) C[oi] = v;
          if (Cf) Cf[oi] = (f16)v;
        }
      }
    }
  }
}

// ---------------- conv edge (CSR order): gather(fp16) + bond(global) + GN + glin + product ----------------
__global__ __launch_bounds__(256) void conv_edge_kernel(
    const f16* __restrict__ xp, const int* __restrict__ ea_s,
    const int* __restrict__ src_s, const int* __restrict__ dst_s,
    const float* __restrict__ bond_emb, const float* __restrict__ gate_w,
    const float* __restrict__ val_w, f16* __restrict__ msg) {
  __shared__ float sg[16 * 260];  // [g][o*16+i], row stride 260 (bank-spread)
  __shared__ float sv[16 * 260];
  int tid = threadIdx.x;
  for (int i = tid; i < 4096; i += 256) {
    int g = i >> 8, rem = i & 255;
    sg[g * 260 + rem] = gate_w[i];
    sv[g * 260 + rem] = val_w[i];
  }
  __syncthreads();
  int idx = blockIdx.x * 256 + tid;
  int j = idx >> 4, g = idx & 15;
  int a0 = ea_s[j * 3 + 0], a1 = ea_s[j * 3 + 1], a2 = ea_s[j * 3 + 2];
  int d = dst_s[j], s = src_s[j];
  half8 xd0 = *reinterpret_cast<const half8*>(&xp[(size_t)d * 256 + g * 16]);
  half8 xd1 = *reinterpret_cast<const half8*>(&xp[(size_t)d * 256 + g * 16 + 8]);
  half8 xs0 = *reinterpret_cast<const half8*>(&xp[(size_t)s * 256 + g * 16]);
  half8 xs1 = *reinterpret_cast<const half8*>(&xp[(size_t)s * 256 + g * 16 + 8]);
  const float4* b0p = reinterpret_cast<const float4*>(&bond_emb[a0 * 256 + g * 16]);
  const float4* b1p = reinterpret_cast<const float4*>(&bond_emb[2048 + a1 * 256 + g * 16]);
  const float4* b2p = reinterpret_cast<const float4*>(&bond_emb[4096 + a2 * 256 + g * 16]);
  float xg[16], xv[16];
  float mg = 0.f, mv = 0.f;
#pragma unroll
  for (int q = 0; q < 4; q++) {
    float4 b0 = b0p[q], b1 = b1p[q], b2 = b2p[q];
#pragma unroll
    for (int t = 0; t < 4; t++) {
      int i = q * 4 + t;
      float bo = (&b0.x)[t] + (&b1.x)[t] + (&b2.x)[t];
      float xd = (i < 8) ? (float)xd0[i & 7] : (float)xd1[i & 7];
      float xs = (i < 8) ? (float)xs0[i & 7] : (float)xs1[i & 7];
      xg[i] = xd + bo;
      xv[i] = xs + bo;
      mg += xg[i];
      mv += xv[i];
    }
  }
  mg *= (1.f / 16.f);
  mv *= (1.f / 16.f);
  float vg = 0.f, vv = 0.f;
#pragma unroll
  for (int i = 0; i < 16; i++) {
    float dg_ = xg[i] - mg, dv_ = xv[i] - mv;
    vg += dg_ * dg_;
    vv += dv_ * dv_;
  }
  float rg = rsqrtf(vg * (1.f / 16.f) + 1e-5f);
  float rv = rsqrtf(vv * (1.f / 16.f) + 1e-5f);
#pragma unroll
  for (int i = 0; i < 16; i++) {
    xg[i] = (xg[i] - mg) * rg;
    xv[i] = (xv[i] - mv) * rv;
  }
  f16 res[16];
#pragma unroll
  for (int o = 0; o < 16; o++) {
    const float4* gp = reinterpret_cast<const float4*>(&sg[g * 260 + o * 16]);
    const float4* vp = reinterpret_cast<const float4*>(&sv[g * 260 + o * 16]);
    float ag = 0.f, av = 0.f;
#pragma unroll
    for (int q = 0; q < 4; q++) {
      float4 gq = gp[q], vq = vp[q];
#pragma unroll
      for (int t = 0; t < 4; t++) {
        ag += xg[q * 4 + t] * (&gq.x)[t];
        av += xv[q * 4 + t] * (&vq.x)[t];
      }
    }
    res[o] = (f16)(fmaxf(ag, 0.f) * av);
  }
  uint4* op = reinterpret_cast<uint4*>(&msg[(size_t)j * 256 + g * 16]);
  op[0] = reinterpret_cast<const uint4*>(res)[0];
  op[1] = reinterpret_cast<const uint4*>(res)[1];
}

// ---------------- glb middle: GN + glin + relu*mul ----------------
// fp16 weights in LDS, [g][DOUT*16 + 8] padded rows; half8 reads; fdot2 inner product;
// register-accumulated outputs stored as half8.
template <int DOUT>
__global__ __launch_bounds__(256) void glb_mid_kernel(
    const float* __restrict__ X, const float* __restrict__ gate_w,
    const float* __restrict__ val_w, f16* __restrict__ out) {
  constexpr int RS = DOUT * 16 + 8;
  __shared__ f16 sg[16 * RS];
  __shared__ f16 sv[16 * RS];
  int tid = threadIdx.x;
  for (int i = tid; i < 16 * DOUT * 16; i += 256) {
    int g = i / (DOUT * 16), rem = i % (DOUT * 16);
    sg[g * RS + rem] = (f16)gate_w[i];
    sv[g * RS + rem] = (f16)val_w[i];
  }
  __syncthreads();
  int idx = blockIdx.x * 256 + tid;
  int n = idx >> 4, g = idx & 15;
  float x[16];
  float m = 0.f;
  const float4* xp4 = reinterpret_cast<const float4*>(&X[(size_t)n * 256 + g * 16]);
#pragma unroll
  for (int q = 0; q < 4; q++) {
    float4 xq = xp4[q];
#pragma unroll
    for (int t = 0; t < 4; t++) {
      x[q * 4 + t] = (&xq.x)[t];
      m += (&xq.x)[t];
    }
  }
  m *= (1.f / 16.f);
  float v = 0.f;
#pragma unroll
  for (int i = 0; i < 16; i++) {
    float d_ = x[i] - m;
    v += d_ * d_;
  }
  float r = rsqrtf(v * (1.f / 16.f) + 1e-5f);
#pragma unroll
  for (int i = 0; i < 16; i++) x[i] = (x[i] - m) * r;
#ifdef HAVE_FDOT2
  half2v xh[8];
#pragma unroll
  for (int q = 0; q < 8; q++) { xh[q][0] = (f16)x[2 * q]; xh[q][1] = (f16)x[2 * q + 1]; }
#endif
  const f16* gRow = &sg[g * RS];
  const f16* vRow = &sv[g * RS];
  f16 res[DOUT];
#pragma unroll
  for (int o = 0; o < DOUT; o++) {
    half8 gA = *reinterpret_cast<const half8*>(&gRow[o * 16]);
    half8 gB = *reinterpret_cast<const half8*>(&gRow[o * 16 + 8]);
    half8 vA = *reinterpret_cast<const half8*>(&vRow[o * 16]);
    half8 vB = *reinterpret_cast<const half8*>(&vRow[o * 16 + 8]);
    float ag = 0.f, av = 0.f;
#ifdef HAVE_FDOT2
#pragma unroll
    for (int q = 0; q < 4; q++) {
      half2v gq = {gA[2 * q], gA[2 * q + 1]};
      half2v g2 = {gB[2 * q], gB[2 * q + 1]};
      half2v vq = {vA[2 * q], vA[2 * q + 1]};
      half2v v2 = {vB[2 * q], vB[2 * q + 1]};
      ag = __builtin_amdgcn_fdot2(xh[q], gq, ag, false);
      ag = __builtin_amdgcn_fdot2(xh[q + 4], g2, ag, false);
      av = __builtin_amdgcn_fdot2(xh[q], vq, av, false);
      av = __builtin_amdgcn_fdot2(xh[q + 4], v2, av, false);
    }
#else
#pragma unroll
    for (int i = 0; i < 8; i++) {
      ag += x[i] * (float)gA[i] + x[i + 8] * (float)gB[i];
      av += x[i] * (float)vA[i] + x[i + 8] * (float)vB[i];
    }
#endif
    res[o] = (f16)(fmaxf(ag, 0.f) * av);
  }
  f16* op = &out[(size_t)n * (16 * DOUT) + g * DOUT];
#pragma unroll
  for (int q = 0; q < DOUT / 8; q++)
    *reinterpret_cast<half8*>(&op[q * 8]) = *reinterpret_cast<const half8*>(&res[q * 8]);
}

// vectorized GroupNorm in place
__global__ __launch_bounds__(256) void gn_vec_kernel(float* __restrict__ X) {
  int idx = blockIdx.x * 256 + threadIdx.x;
  int n = idx >> 6, q = idx & 63;
  float4 x = *reinterpret_cast<const float4*>(&X[(size_t)n * 256 + q * 4]);
  float s = x.x + x.y + x.z + x.w;
  float s2 = x.x * x.x + x.y * x.y + x.z * x.z + x.w * x.w;
  s += __shfl_xor(s, 1); s2 += __shfl_xor(s2, 1);
  s += __shfl_xor(s, 2); s2 += __shfl_xor(s2, 2);
  float m = s * (1.f / 16.f);
  float var = s2 * (1.f / 16.f) - m * m;
  float r = rsqrtf(var + 1e-5f);
  x.x = (x.x - m) * r; x.y = (x.y - m) * r;
  x.z = (x.z - m) * r; x.w = (x.w - m) * r;
  *reinterpret_cast<float4*>(&X[(size_t)n * 256 + q * 4]) = x;
}

// ---------------- attention ----------------
// h_att layout (workspace-internal): [b][h][head][v] = b*8192 + h*512 + head*16 + v
__global__ __launch_bounds__(256) void att_graph_kernel(
    const float* __restrict__ xv0, const float* __restrict__ k_w,
    const float* __restrict__ v_w, const int* __restrict__ goff,
    float* __restrict__ h_att, float* __restrict__ xk_sum) {
  __shared__ float kx[8][512];
  __shared__ float vx[8][512];
  __shared__ float rows[8][256];
  const int tid = threadIdx.x, b = blockIdx.x;
  float wk0[16], wv0[16], wk1[16], wv1[16];
#pragma unroll
  for (int i = 0; i < 4; i++) {
    float4 k0 = *reinterpret_cast<const float4*>(&k_w[tid * 16 + i * 4]);
    float4 v0 = *reinterpret_cast<const float4*>(&v_w[tid * 16 + i * 4]);
    float4 k1 = *reinterpret_cast<const float4*>(&k_w[(tid + 256) * 16 + i * 4]);
    float4 v1 = *reinterpret_cast<const float4*>(&v_w[(tid + 256) * 16 + i * 4]);
    wk0[i * 4 + 0] = k0.x; wk0[i * 4 + 1] = k0.y; wk0[i * 4 + 2] = k0.z; wk0[i * 4 + 3] = k0.w;
    wv0[i * 4 + 0] = v0.x; wv0[i * 4 + 1] = v0.y; wv0[i * 4 + 2] = v0.z; wv0[i * 4 + 3] = v0.w;
    wk1[i * 4 + 0] = k1.x; wk1[i * 4 + 1] = k1.y; wk1[i * 4 + 2] = k1.z; wk1[i * 4 + 3] = k1.w;
    wv1[i * 4 + 0] = v1.x; wv1[i * 4 + 1] = v1.y; wv1[i * 4 + 2] = v1.z; wv1[i * 4 + 3] = v1.w;
  }
  float hacc[2][16];
  const float* hg = &h_att[(size_t)b * 8192];
#pragma unroll
  for (int c = 0; c < 2; c++) {
    int p = tid + c * 256;
    int head = p >> 4, h = p & 15;
#pragma unroll
    for (int j = 0; j < 16; j++) hacc[c][j] = hg[h * 512 + head * 16 + j];
  }
  float ks0 = 0.f, ks1 = 0.f;
  const int n0 = goff[b], n1 = goff[b + 1];
  const int g0 = tid >> 5, g1 = (tid + 256) >> 5;
  float r[8];
#pragma unroll
  for (int nn = 0; nn < 8; nn++) {
    int n = n0 + nn;
    r[nn] = (n < n1) ? xv0[(size_t)n * 256 + tid] : 0.f;
  }
  for (int nbase = n0; nbase < n1; nbase += 8) {
#pragma unroll
    for (int nn = 0; nn < 8; nn++) rows[nn][tid] = r[nn];
    __syncthreads();
#pragma unroll
    for (int nn = 0; nn < 8; nn++) {
      int n = nbase + 8 + nn;
      r[nn] = (n < n1) ? xv0[(size_t)n * 256 + tid] : 0.f;
    }
#pragma unroll
    for (int nn = 0; nn < 8; nn++) {
      const float4* rp0 = reinterpret_cast<const float4*>(&rows[nn][g0 * 16]);
      const float4* rp1 = reinterpret_cast<const float4*>(&rows[nn][g1 * 16]);
      float aK0 = 0.f, aV0 = 0.f, aK1 = 0.f, aV1 = 0.f;
#pragma unroll
      for (int q = 0; q < 4; q++) {
        float4 x0 = rp0[q], x1 = rp1[q];
#pragma unroll
        for (int t = 0; t < 4; t++) {
          float e0 = (&x0.x)[t], e1 = (&x1.x)[t];
          aK0 += e0 * wk0[q * 4 + t];
          aV0 += e0 * wv0[q * 4 + t];
          aK1 += e1 * wk1[q * 4 + t];
          aV1 += e1 * wv1[q * 4 + t];
        }
      }
      bool valid = (nbase + nn) < n1;
      float ek0 = valid ? expf(aK0 * 0.25f) : 0.f;
      float ek1 = valid ? expf(aK1 * 0.25f) : 0.f;
      kx[nn][tid] = ek0;
      kx[nn][tid + 256] = ek1;
      vx[nn][tid] = aV0;
      vx[nn][tid + 256] = aV1;
      ks0 += ek0;
      ks1 += ek1;
    }
    __syncthreads();
#pragma unroll
    for (int c = 0; c < 2; c++) {
      int p = tid + c * 256;
      int head = p >> 4, h = p & 15;
#pragma unroll
      for (int nn = 0; nn < 8; nn++) {
        float kk = kx[nn][head * 16 + h];
        const float4* vp = reinterpret_cast<const float4*>(&vx[nn][head * 16]);
#pragma unroll
        for (int q = 0; q < 4; q++) {
          float4 vq = vp[q];
          hacc[c][q * 4 + 0] += kk * vq.x;
          hacc[c][q * 4 + 1] += kk * vq.y;
          hacc[c][q * 4 + 2] += kk * vq.z;
          hacc[c][q * 4 + 3] += kk * vq.w;
        }
      }
    }
    __syncthreads();
  }
  float* hgo = &h_att[(size_t)b * 8192];
#pragma unroll
  for (int c = 0; c < 2; c++) {
    int p = tid + c * 256;
    int head = p >> 4, h = p & 15;
#pragma unroll
    for (int j = 0; j < 16; j++) hgo[h * 512 + head * 16 + j] = hacc[c][j];
  }
  xk_sum[(size_t)b * 512 + tid] = ks0;
  xk_sum[(size_t)b * 512 + tid + 256] = ks1;
}

// wave = 1 node; lane = (head, half): head=lane>>1, half=lane&1 handles v in [half*8, half*8+8)
__global__ __launch_bounds__(256) void att_out_kernel(
    const float* __restrict__ xv0, const float* __restrict__ q_w,
    const float* __restrict__ xk_sum, const float* __restrict__ h_att,
    const int* __restrict__ batch, f16* __restrict__ out) {
  __shared__ float sqw[16 * 260];  // [g][oo*16+i], stride 260 (16B aligned, bank-spread)
  int tid = threadIdx.x;
  for (int i = tid; i < 8192; i += 256) {
    int g = i >> 9, rem = i & 511;  // q_w layout [g][32][16]
    sqw[g * 260 + rem] = q_w[i];
  }
  __syncthreads();
  int wave = tid >> 6, lane = tid & 63;
  int n = blockIdx.x * 4 + wave;
  int head = lane >> 1, half = lane & 1;
  int g = head >> 1, j = head & 1;
  int b = batch[n];
  float x[16];
  const float4* xp4 = reinterpret_cast<const float4*>(&xv0[(size_t)n * 256 + g * 16]);
#pragma unroll
  for (int q = 0; q < 4; q++) {
    float4 xq = xp4[q];
#pragma unroll
    for (int t = 0; t < 4; t++) x[q * 4 + t] = (&xq.x)[t];
  }
  float qv[16];
  float denom = 0.f;
  const float* ks = &xk_sum[(size_t)b * 512 + head * 16];
#pragma unroll
  for (int h = 0; h < 16; h++) {
    const float4* wp = reinterpret_cast<const float4*>(&sqw[g * 260 + (j * 16 + h) * 16]);
    float a = 0.f;
#pragma unroll
    for (int q = 0; q < 4; q++) {
      float4 wq = wp[q];
#pragma unroll
      for (int t = 0; t < 4; t++) a += x[q * 4 + t] * (&wq.x)[t];
    }
    float e = expf(a * 0.25f);
    qv[h] = e;
    denom += e * ks[h];
  }
  float inv = 1.f / denom;
  float acc[8] = {0.f, 0.f, 0.f, 0.f, 0.f, 0.f, 0.f, 0.f};
  const float* hb = &h_att[(size_t)b * 8192 + head * 16 + half * 8];
#pragma unroll
  for (int h = 0; h < 16; h++) {
    float4 v0 = *reinterpret_cast<const float4*>(&hb[h * 512]);
    float4 v1 = *reinterpret_cast<const float4*>(&hb[h * 512 + 4]);
    float qh = qv[h];
    acc[0] += qh * v0.x; acc[1] += qh * v0.y; acc[2] += qh * v0.z; acc[3] += qh * v0.w;
    acc[4] += qh * v1.x; acc[5] += qh * v1.y; acc[6] += qh * v1.z; acc[7] += qh * v1.w;
  }
  half8 res;
#pragma unroll
  for (int v = 0; v < 8; v++) res[v] = (f16)(acc[v] * inv);
  *reinterpret_cast<half8*>(&out[(size_t)n * 512 + head * 16 + half * 8]) = res;
}

__global__ __launch_bounds__(256) void virt_seg_kernel(const float* __restrict__ h_in,
    const int* __restrict__ goff, float* __restrict__ h_virt) {
  int b = blockIdx.x, c = threadIdx.x;
  float acc = h_virt[(size_t)b * 256 + c];
  int n0 = goff[b], n1 = goff[b + 1];
  for (int n = n0; n < n1; n++) acc += h_in[(size_t)n * 256 + c];
  h_virt[(size_t)b * 256 + c] = acc;
}

// ---------------- host driver ----------------

extern "C" void kernel_launch(void* const* d_in, const int* in_sizes, int n_in,
                              void* d_out, int out_size, void* d_ws, size_t ws_size,
                              hipStream_t stream) {
  const int* x_feat = (const int*)d_in[0];
  const int* eidx = (const int*)d_in[1];
  const int* eattr = (const int*)d_in[2];
  const int* batch = (const int*)d_in[3];
  const float* edist = (const float*)d_in[5];
  const float* atom_emb = (const float*)d_in[6];
  const float* bond2d = (const float*)d_in[7];
  const float* gmeans = (const float*)d_in[8];
  const float* gstds = (const float*)d_in[9];
  const float* attn_w = (const float*)d_in[10];
  const float* attn_b = (const float*)d_in[11];
  const float* scale_both = (const float*)d_in[12];
  const float* conv_bond_emb = (const float*)d_in[13];
  const float* conv_pre_w = (const float*)d_in[14];
  const float* conv_gate_w = (const float*)d_in[15];
  const float* conv_val_w = (const float*)d_in[16];
  const float* conv_post_w = (const float*)d_in[17];
  const float* conv_post_b = (const float*)d_in[18];
  const float* conv_scale = (const float*)d_in[19];
  const float* virt_pre_w = (const float*)d_in[20];
  const float* virt_pre_b = (const float*)d_in[21];
  const float* virt_gate_w = (const float*)d_in[22];
  const float* virt_val_w = (const float*)d_in[23];
  const float* virt_post_w = (const float*)d_in[24];
  const float* virt_post_b = (const float*)d_in[25];
  const float* virt_scale = (const float*)d_in[26];
  const float* att_pre_w = (const float*)d_in[27];
  const float* att_pre_b = (const float*)d_in[28];
  const float* att_q_w = (const float*)d_in[29];
  const float* att_k_w = (const float*)d_in[30];
  const float* att_v_w = (const float*)d_in[31];
  const float* att_post_w = (const float*)d_in[32];
  const float* att_post_b = (const float*)d_in[33];
  const float* att_scale = (const float*)d_in[34];
  const float* main_pre_w = (const float*)d_in[35];
  const float* main_pre_b = (const float*)d_in[36];
  const float* main_gate_w = (const float*)d_in[37];
  const float* main_val_w = (const float*)d_in[38];
  const float* main_post_w = (const float*)d_in[39];
  const float* main_post_b = (const float*)d_in[40];

  const int* src = eidx;
  const int* dst = eidx + EE;

  float* ws = (float*)d_ws;
  float* h_in = ws;
  float* h_out = ws + ND;
  float* x_raw = ws + 2 * ND;
  float* x_out = ws + 3 * ND;
  float* nodeA = ws + 4 * ND;
  f16* h_inH = (f16*)(ws + 5 * ND);
  f16* xrawH = (f16*)(ws + 5 * ND + ND / 2);
  f16* hTmp = (f16*)(ws + 6 * ND);
  f16* msgH = (f16*)(ws + 6 * ND + ND / 2);   // 3*ND halfs
  float* sm = ws + 8 * ND;
  f16* hW = (f16*)sm;                          // 2359296 halfs = 1179648 floats
  float* h_virt = sm + 1179648;
  float* h_att = h_virt + 65536;
  float* xk_sum = h_att + 2097152;
  float* vt1 = xk_sum + 131072;
  float* vout = vt1 + 65536;
  f16* vmidH = (f16*)(vout + 65536);           // B*512 halfs
  f16* virtH = vmidH + 131072;                 // B*256 halfs
  int* cnt = (int*)(virtH + 65536);
  int* deg = cnt + NN;
  int* goff = deg + NN;
  int* off = goff + BB + 1;
  int* cursor = off + NN + 1;
  int* elist = cursor + NN;
  int* ea_s = elist + EE;
  int* src_s = ea_s + 3 * EE;
  int* dst_s = src_s + EE;
  float* ed_s = (float*)(dst_s + EE);

  f16* wCpre = hW;
  f16* wCpost = hW + 524288;
  f16* wApre = hW + 1048576;
  f16* wApost = hW + 1179648;
  f16* wMpre = hW + 1441792;
  f16* wMpost = hW + 1572864;
  f16* wVpre = hW + 1966080;
  f16* wVpost = hW + 2097152;

  auto cvt = [&](const float* in, f16* out, int n) {
    f2h_kernel<<<n / 4 / 256, 256, 0, stream>>>(in, out, n / 4);
  };

  cvt(conv_pre_w, wCpre, 524288);
  cvt(conv_post_w, wCpost, 524288);
  cvt(att_pre_w, wApre, 131072);
  cvt(att_post_w, wApost, 262144);
  cvt(main_pre_w, wMpre, 131072);
  cvt(main_post_w, wMpost, 393216);
  cvt(virt_pre_w, wVpre, 131072);
  cvt(virt_post_w, wVpost, 262144);

  // degree + graph offsets + CSR (edges grouped by dst) + gathered edge data
  (void)hipMemsetAsync(cnt, 0, NN * sizeof(int), stream);
  count_deg_kernel<<<EE / 256, 256, 0, stream>>>(dst, cnt, EE);
  clip_deg_kernel<<<NN / 256, 256, 0, stream>>>(cnt, deg, NN);
  goff_kernel<<<(NN + 256) / 256, 256, 0, stream>>>(batch, goff, NN, BB);
  scan_off_kernel<<<1, 256, 0, stream>>>(cnt, off);
  copy_i_kernel<<<NN / 256, 256, 0, stream>>>(off, cursor, NN);
  fill_elist_kernel<<<EE / 256, 256, 0, stream>>>(dst, cursor, elist, EE);
  gather_edges_kernel<<<EE / 256, 256, 0, stream>>>(elist, eattr, src, dst, edist,
                                                    ea_s, src_s, dst_s, ed_s);

  // initial node features
  edge_feat_kernel<<<EE / 4, 256, 0, stream>>>(ea_s, ed_s, bond2d, gmeans, gstds,
                                               attn_w, attn_b, msgH);
  seg_reduce_kernel<float><<<NN / 4, 256, 0, stream>>>(msgH, off, x_out);
  atom_finish_kernel<<<NN * 64 / 256, 256, 0, stream>>>(x_feat, atom_emb, scale_both, deg,
                                                        x_out, h_in, h_inH);
  (void)hipMemsetAsync(h_virt, 0, 65536 * 4, stream);
  (void)hipMemsetAsync(h_att, 0, 2097152 * 4, stream);

  const dim3 gN(NN / 128, 4), gB(BB / 128, 4);
  const int n4 = (int)(ND / 4);

  for (int l = 0; l < 2; l++) {
    // ---- ConvMessage ----
    const f16* curH = h_inH;
    for (int k = 0; k < 4; k++) {
      if (k == 2) {
        add3_both_kernel<<<n4 / 256, 256, 0, stream>>>(x_raw, xrawH, h_in, x_out, n4);
        curH = xrawH;
      }
      size_t lk = (size_t)(l * 4 + k);
      hgemm_kernel<0><<<gN, 256, 0, stream>>>(curH, wCpre + lk * 65536, nullptr, nullptr,
                                              nullptr, nullptr, nullptr, nullptr, hTmp, 256);
      conv_edge_kernel<<<EE * 16 / 256, 256, 0, stream>>>(
          hTmp, ea_s, src_s, dst_s, conv_bond_emb + lk * 6144,
          conv_gate_w + lk * 4096, conv_val_w + lk * 4096, msgH);
      seg_reduce_kernel<f16><<<NN / 4, 256, 0, stream>>>(msgH, off, hTmp);
      if (k == 0 || k == 2)
        hgemm_kernel<5><<<gN, 256, 0, stream>>>(hTmp, wCpost + lk * 65536,
                                                conv_post_b + lk * 256, conv_scale + lk * 1024,
                                                cnt, deg, nullptr, x_out, xrawH, 256);
      else
        hgemm_kernel<4><<<gN, 256, 0, stream>>>(hTmp, wCpost + lk * 65536,
                                                conv_post_b + lk * 256, conv_scale + lk * 1024,
                                                cnt, deg, nullptr, x_out, xrawH, 256);
      curH = xrawH;
    }
    add3_kernel<<<n4 / 256, 256, 0, stream>>>(h_out, h_in, x_out, n4);

    // ---- VirtMessage ----
    virt_seg_kernel<<<BB, 256, 0, stream>>>(h_in, goff, h_virt);
    cvt(h_virt, virtH, 65536);
    hgemm_kernel<0><<<gB, 256, 0, stream>>>(virtH, wVpre + (size_t)l * 65536,
                                            virt_pre_b + (size_t)l * 256, nullptr, nullptr,
                                            nullptr, vt1, nullptr, nullptr, 256);
    glb_mid_kernel<32><<<BB * 16 / 256, 256, 0, stream>>>(
        vt1, virt_gate_w + (size_t)l * 8192, virt_val_w + (size_t)l * 8192, vmidH);
    hgemm_kernel<0><<<gB, 256, 0, stream>>>(vmidH, wVpost + (size_t)l * 131072,
                                            virt_post_b + (size_t)l * 256, nullptr, nullptr,
                                            nullptr, vout, nullptr, nullptr, 512);
    bcast_add_kernel<<<n4 / 256, 256, 0, stream>>>(
        h_out, vout, virt_scale + (size_t)l * 256, batch);

    // ---- AttMessage ----
    hgemm_kernel<0><<<gN, 256, 0, stream>>>(h_inH, wApre + (size_t)l * 65536,
                                            att_pre_b + (size_t)l * 256, nullptr, nullptr,
                                            nullptr, nodeA, nullptr, nullptr, 256);
    gn_vec_kernel<<<NN * 64 / 256, 256, 0, stream>>>(nodeA);
    att_graph_kernel<<<BB, 256, 0, stream>>>(
        nodeA, att_k_w + (size_t)l * 8192, att_v_w + (size_t)l * 8192, goff, h_att, xk_sum);
    att_out_kernel<<<NN / 4, 256, 0, stream>>>(
        nodeA, att_q_w + (size_t)l * 8192, xk_sum, h_att, batch, msgH);
    hgemm_kernel<2><<<gN, 256, 0, stream>>>(msgH, wApost + (size_t)l * 131072,
                                            att_post_b + (size_t)l * 256,
                                            att_scale + (size_t)l * 256, nullptr, nullptr,
                                            nullptr, h_out, hTmp, 512);

    // ---- main gated block ----
    hgemm_kernel<0><<<gN, 256, 0, stream>>>(hTmp, wMpre + (size_t)l * 65536,
                                            main_pre_b + (size_t)l * 256, nullptr, nullptr,
                                            nullptr, nodeA, nullptr, nullptr, 256);
    glb_mid_kernel<48><<<NN * 16 / 256, 256, 0, stream>>>(
        nodeA, main_gate_w + (size_t)l * 12288, main_val_w + (size_t)l * 12288, msgH);
    float* hdst = (l == 1) ? (float*)d_out : h_in;
    f16* hdstH = (l == 1) ? nullptr : h_inH;
    hgemm_kernel<0><<<gN, 256, 0, stream>>>(msgH, wMpost + (size_t)l * 196608,
                                            main_post_b + (size_t)l * 256, nullptr, nullptr,
                                            nullptr, hdst, nullptr, hdstH, 768);
  }
}

// Round 9
// 1065.663 us; speedup vs baseline: 6.5419x; 1.0677x over previous
//
#include <hip/hip_runtime.h>
#include <cstdint>
#include <cstddef>
#include <type_traits>

#define NN 16384
#define EE 49152
#define BB 256
// D=256, G=16, 16 channels per group, HD=16

typedef _Float16 f16;
typedef _Float16 half8 __attribute__((ext_vector_type(8)));
typedef _Float16 half4v __attribute__((ext_vector_type(4)));
typedef _Float16 half2v __attribute__((ext_vector_type(2)));
typedef float floatx4 __attribute__((ext_vector_type(4)));

#if defined(__has_builtin)
#if __has_builtin(__builtin_amdgcn_fdot2)
#define HAVE_FDOT2 1
#endif
#endif

static constexpr size_t ND = (size_t)NN * 256;

// ---------------- setup kernels ----------------

__global__ __launch_bounds__(256) void count_deg_kernel(const int* __restrict__ dst, int* __restrict__ cnt, int e) {
  int i = blockIdx.x * 256 + threadIdx.x;
  if (i < e) atomicAdd(&cnt[dst[i]], 1);
}
__global__ __launch_bounds__(256) void clip_deg_kernel(const int* __restrict__ cnt, int* __restrict__ deg, int n) {
  int i = blockIdx.x * 256 + threadIdx.x;
  if (i < n) { int v = cnt[i] - 1; deg[i] = v < 0 ? 0 : (v > 3 ? 3 : v); }
}
__global__ __launch_bounds__(256) void goff_kernel(const int* __restrict__ batch, int* __restrict__ goff, int n, int b) {
  int i = blockIdx.x * 256 + threadIdx.x;
  if (i > n) return;
  int cur = (i < n) ? batch[i] : b;
  int prev = (i == 0) ? -1 : batch[i - 1];
  for (int x = prev + 1; x <= cur; x++) goff[x] = i;
}
__global__ __launch_bounds__(256) void scan_off_kernel(const int* __restrict__ cnt, int* __restrict__ off) {
  __shared__ int part[256];
  int tid = threadIdx.x;
  int base = tid * 64;
  int s = 0;
  for (int i = 0; i < 64; i++) s += cnt[base + i];
  part[tid] = s;
  __syncthreads();
  for (int o = 1; o < 256; o <<= 1) {
    int t = (tid >= o) ? part[tid - o] : 0;
    __syncthreads();
    part[tid] += t;
    __syncthreads();
  }
  int run = (tid == 0) ? 0 : part[tid - 1];
  for (int i = 0; i < 64; i++) {
    off[base + i] = run;
    run += cnt[base + i];
  }
  if (tid == 255) off[NN] = run;
}
__global__ __launch_bounds__(256) void copy_i_kernel(const int* __restrict__ a, int* __restrict__ b, int n) {
  int i = blockIdx.x * 256 + threadIdx.x;
  if (i < n) b[i] = a[i];
}
__global__ __launch_bounds__(256) void fill_elist_kernel(const int* __restrict__ dst,
    int* __restrict__ cursor, int* __restrict__ elist, int e) {
  int i = blockIdx.x * 256 + threadIdx.x;
  if (i < e) {
    int p = atomicAdd(&cursor[dst[i]], 1);
    elist[p] = i;
  }
}
// gather edge data into CSR (dst-sorted) order
__global__ __launch_bounds__(256) void gather_edges_kernel(const int* __restrict__ elist,
    const int* __restrict__ eattr, const int* __restrict__ src, const int* __restrict__ dst,
    const float* __restrict__ edist, int* __restrict__ ea_s, int* __restrict__ src_s,
    int* __restrict__ dst_s, float* __restrict__ ed_s) {
  int j = blockIdx.x * 256 + threadIdx.x;
  if (j >= EE) return;
  int e = elist[j];
  ea_s[j * 3 + 0] = eattr[e * 3 + 0];
  ea_s[j * 3 + 1] = eattr[e * 3 + 1];
  ea_s[j * 3 + 2] = eattr[e * 3 + 2];
  src_s[j] = src[e];
  dst_s[j] = dst[e];
  ed_s[j] = edist[e];
}
// float4 elementwise
__global__ __launch_bounds__(256) void add3_kernel(float* __restrict__ dst,
    const float* __restrict__ a, const float* __restrict__ b, int n4) {
  int i = blockIdx.x * 256 + threadIdx.x;
  if (i >= n4) return;
  float4 x = reinterpret_cast<const float4*>(a)[i];
  float4 y = reinterpret_cast<const float4*>(b)[i];
  x.x += y.x; x.y += y.y; x.z += y.z; x.w += y.w;
  reinterpret_cast<float4*>(dst)[i] = x;
}
__global__ __launch_bounds__(256) void add3_both_kernel(float* __restrict__ dst, f16* __restrict__ dstH,
    const float* __restrict__ a, const float* __restrict__ b, int n4) {
  int i = blockIdx.x * 256 + threadIdx.x;
  if (i >= n4) return;
  float4 x = reinterpret_cast<const float4*>(a)[i];
  float4 y = reinterpret_cast<const float4*>(b)[i];
  x.x += y.x; x.y += y.y; x.z += y.z; x.w += y.w;
  reinterpret_cast<float4*>(dst)[i] = x;
  half4v h;
  h[0] = (f16)x.x; h[1] = (f16)x.y; h[2] = (f16)x.z; h[3] = (f16)x.w;
  reinterpret_cast<half4v*>(dstH)[i] = h;
}
__global__ __launch_bounds__(256) void bcast_add_kernel(float* __restrict__ ho,
    const float* __restrict__ vo, const float* __restrict__ vs, const int* __restrict__ batch) {
  int i4 = blockIdx.x * 256 + threadIdx.x;
  int i = i4 * 4;
  int n = i >> 8, c = i & 255;
  float4 h = reinterpret_cast<const float4*>(&ho[i])[0];
  float4 v = *reinterpret_cast<const float4*>(&vo[(size_t)batch[n] * 256 + c]);
  float4 s = *reinterpret_cast<const float4*>(&vs[c]);
  h.x += expf(s.x) * v.x; h.y += expf(s.y) * v.y;
  h.z += expf(s.z) * v.z; h.w += expf(s.w) * v.w;
  *reinterpret_cast<float4*>(&ho[i]) = h;
}
__global__ __launch_bounds__(256) void f2h_kernel(const float* __restrict__ in, f16* __restrict__ out, int n4) {
  int i = blockIdx.x * 256 + threadIdx.x;
  if (i >= n4) return;
  float4 v = reinterpret_cast<const float4*>(in)[i];
  half4v o;
  o[0] = (f16)v.x; o[1] = (f16)v.y; o[2] = (f16)v.z; o[3] = (f16)v.w;
  reinterpret_cast<half4v*>(out)[i] = o;
}

// ---------------- segment reduce over CONTIGUOUS CSR rows ----------------
template <typename OUT>
__global__ __launch_bounds__(256) void seg_reduce_kernel(const f16* __restrict__ msg,
    const int* __restrict__ off, OUT* __restrict__ out) {
  int idx = blockIdx.x * 256 + threadIdx.x;
  int n = idx >> 6, c0 = (idx & 63) * 4;
  int j0 = off[n], j1 = off[n + 1];
  float a0 = 0.f, a1 = 0.f, a2 = 0.f, a3 = 0.f;
  int j = j0;
  for (; j + 1 < j1; j += 2) {
    half4v m0 = *reinterpret_cast<const half4v*>(&msg[(size_t)j * 256 + c0]);
    half4v m1 = *reinterpret_cast<const half4v*>(&msg[(size_t)(j + 1) * 256 + c0]);
    a0 += (float)m0[0] + (float)m1[0];
    a1 += (float)m0[1] + (float)m1[1];
    a2 += (float)m0[2] + (float)m1[2];
    a3 += (float)m0[3] + (float)m1[3];
  }
  if (j < j1) {
    half4v m0 = *reinterpret_cast<const half4v*>(&msg[(size_t)j * 256 + c0]);
    a0 += (float)m0[0]; a1 += (float)m0[1]; a2 += (float)m0[2]; a3 += (float)m0[3];
  }
  if constexpr (std::is_same<OUT, float>::value) {
    float4 o = {a0, a1, a2, a3};
    *reinterpret_cast<float4*>(&out[(size_t)n * 256 + c0]) = o;
  } else {
    half4v o;
    o[0] = (f16)a0; o[1] = (f16)a1; o[2] = (f16)a2; o[3] = (f16)a3;
    *reinterpret_cast<half4v*>(&out[(size_t)n * 256 + c0]) = o;
  }
}

// ---------------- initial edge / node features (CSR order) ----------------

__global__ __launch_bounds__(256) void edge_feat_kernel(
    const int* __restrict__ ea_s, const float* __restrict__ ed_s,
    const float* __restrict__ bond2d, const float* __restrict__ gmeans,
    const float* __restrict__ gstds, const float* __restrict__ attn_w,
    const float* __restrict__ attn_b, f16* __restrict__ msg) {
  int lane = threadIdx.x & 63;
  int j = blockIdx.x * 4 + (threadIdx.x >> 6);
  if (j >= EE) return;
  int a0 = ea_s[j * 3 + 0], a1 = ea_s[j * 3 + 1], a2 = ea_s[j * 3 + 2];
  float dist = ed_s[j];
  const float SQ2PI = sqrtf(2.0f * 3.14159f);
  int c0 = lane * 4;
  float4 b0 = *reinterpret_cast<const float4*>(&bond2d[a0 * 256 + c0]);
  float4 b1 = *reinterpret_cast<const float4*>(&bond2d[2048 + a1 * 256 + c0]);
  float4 b2 = *reinterpret_cast<const float4*>(&bond2d[4096 + a2 * 256 + c0]);
  float4 gm = *reinterpret_cast<const float4*>(&gmeans[c0]);
  float4 gs = *reinterpret_cast<const float4*>(&gstds[c0]);
  float4 w2 = *reinterpret_cast<const float4*>(&attn_w[c0]);
  float4 w3 = *reinterpret_cast<const float4*>(&attn_w[256 + c0]);
  float h2[4], h3[4];
  float part = 0.f;
#pragma unroll
  for (int i = 0; i < 4; i++) {
    h2[i] = (&b0.x)[i] + (&b1.x)[i] + (&b2.x)[i];
    float sd = fabsf((&gs.x)[i]) + 0.01f;
    float df = (dist - (&gm.x)[i]) / sd;
    h3[i] = expf(-0.5f * df * df) / (SQ2PI * sd);
    part += (&w2.x)[i] * h2[i] + (&w3.x)[i] * h3[i];
  }
#pragma unroll
  for (int off = 32; off > 0; off >>= 1) part += __shfl_xor(part, off);
  float wg = 1.f / (1.f + expf(-(part + attn_b[0])));
  half4v o;
#pragma unroll
  for (int i = 0; i < 4; i++) o[i] = (f16)(wg * h2[i] + (1.f - wg) * h3[i]);
  *reinterpret_cast<half4v*>(&msg[(size_t)j * 256 + c0]) = o;
}

__global__ __launch_bounds__(256) void atom_finish_kernel(
    const int* __restrict__ xf, const float* __restrict__ emb,
    const float* __restrict__ scale_both, const int* __restrict__ deg,
    const float* __restrict__ tmp, float* __restrict__ h_in, f16* __restrict__ h_inH) {
  int idx = blockIdx.x * 256 + threadIdx.x;
  int n = idx >> 6, c = (idx & 63) * 4;
  float a0 = 0.f, a1 = 0.f, a2 = 0.f, a3 = 0.f;
#pragma unroll
  for (int f = 0; f < 9; f++) {
    int v = xf[n * 9 + f];
    float4 e = *reinterpret_cast<const float4*>(&emb[((size_t)(f * 128 + v)) * 256 + c]);
    a0 += e.x; a1 += e.y; a2 += e.z; a3 += e.w;
  }
  int dg = deg[n];
  float4 s = *reinterpret_cast<const float4*>(&scale_both[dg * 256 + c]);
  float4 t = *reinterpret_cast<const float4*>(&tmp[(size_t)n * 256 + c]);
  float4 r;
  r.x = a0 + expf(s.x) * t.x; r.y = a1 + expf(s.y) * t.y;
  r.z = a2 + expf(s.z) * t.z; r.w = a3 + expf(s.w) * t.w;
  *reinterpret_cast<float4*>(&h_in[(size_t)n * 256 + c]) = r;
  half4v h;
  h[0] = (f16)r.x; h[1] = (f16)r.y; h[2] = (f16)r.z; h[3] = (f16)r.w;
  *reinterpret_cast<half4v*>(&h_inH[(size_t)n * 256 + c]) = h;
}

// ---------------- fp16 MFMA GEMM, tile 128x64, 4 waves (2x2), BK=32, reg prefetch ----------------
// MODE 0: v=acc(+bias); C?=v; Cf?=f16(v)
// MODE 2: v=acc+bias; nv=Cadd[oi]+expf(scale[col])*v; C?=nv; Cf?=f16(nv)
// MODE 4: v=acc+cnt[row]*bias[col]; Cadd[oi]+=expf(scale[deg[row]*256+col])*v; Cf?=f16(v)
// MODE 5: like 4 but Cadd[oi]= (init store)
template <int MODE>
__global__ __launch_bounds__(256) void hgemm_kernel(
    const f16* __restrict__ A, const f16* __restrict__ W,
    const float* __restrict__ bias, const float* __restrict__ scale,
    const int* __restrict__ cnt, const int* __restrict__ deg,
    float* __restrict__ C, float* __restrict__ Cadd, f16* __restrict__ Cf, int K) {
  __shared__ f16 Ah[128 * 40];
  __shared__ f16 Wh[64 * 40];
  const int tid = threadIdx.x;
  const int row0 = blockIdx.x * 128, col0 = blockIdx.y * 64;
  const int lane = tid & 63;
  const int wave = tid >> 6;
  const int wr = (wave >> 1) * 64, wc = (wave & 1) * 32;
  const floatx4 fz = {0.f, 0.f, 0.f, 0.f};
  floatx4 acc[4][2];
#pragma unroll
  for (int m = 0; m < 4; m++)
#pragma unroll
    for (int n = 0; n < 2; n++) acc[m][n] = fz;
  const int q0 = tid * 2;
  const int rA0 = q0 >> 2, pA0 = q0 & 3;
  const int rA1 = (q0 + 1) >> 2, pA1 = (q0 + 1) & 3;
  const int rW = tid >> 2, pW = tid & 3;
  const int kb = (lane >> 4) * 8;
  const int fr = lane & 15;
  uint4 a0 = *reinterpret_cast<const uint4*>(&A[(size_t)(row0 + rA0) * K + pA0 * 8]);
  uint4 a1 = *reinterpret_cast<const uint4*>(&A[(size_t)(row0 + rA1) * K + pA1 * 8]);
  uint4 w0 = *reinterpret_cast<const uint4*>(&W[(size_t)(col0 + rW) * K + pW * 8]);
  for (int k0 = 0;;) {
    *reinterpret_cast<uint4*>(&Ah[rA0 * 40 + pA0 * 8]) = a0;
    *reinterpret_cast<uint4*>(&Ah[rA1 * 40 + pA1 * 8]) = a1;
    *reinterpret_cast<uint4*>(&Wh[rW * 40 + pW * 8]) = w0;
    __syncthreads();
    int kn = k0 + 32;
    if (kn < K) {
      a0 = *reinterpret_cast<const uint4*>(&A[(size_t)(row0 + rA0) * K + kn + pA0 * 8]);
      a1 = *reinterpret_cast<const uint4*>(&A[(size_t)(row0 + rA1) * K + kn + pA1 * 8]);
      w0 = *reinterpret_cast<const uint4*>(&W[(size_t)(col0 + rW) * K + kn + pW * 8]);
    }
    half8 af[4], wf[2];
#pragma unroll
    for (int m = 0; m < 4; m++)
      af[m] = *reinterpret_cast<const half8*>(&Ah[(wr + m * 16 + fr) * 40 + kb]);
#pragma unroll
    for (int n = 0; n < 2; n++)
      wf[n] = *reinterpret_cast<const half8*>(&Wh[(wc + n * 16 + fr) * 40 + kb]);
#pragma unroll
    for (int m = 0; m < 4; m++)
#pragma unroll
      for (int n = 0; n < 2; n++)
        acc[m][n] = __builtin_amdgcn_mfma_f32_16x16x32_f16(af[m], wf[n], acc[m][n], 0, 0, 0);
    if (kn >= K) break;
    __syncthreads();
    k0 = kn;
  }
  const int rl4 = (lane >> 4) * 4, cl = lane & 15;
#pragma unroll
  for (int m = 0; m < 4; m++) {
#pragma unroll
    for (int i = 0; i < 4; i++) {
      int row = row0 + wr + m * 16 + rl4 + i;
      float cb = (MODE >= 4) ? (float)cnt[row] : 1.f;
      int dg = (MODE >= 4) ? deg[row] : 0;
#pragma unroll
      for (int n = 0; n < 2; n++) {
        int col = col0 + wc + n * 16 + cl;
        float v = acc[m][n][i];
        size_t oi = (size_t)row * 256 + col;
        if (MODE >= 4) {
          v += cb * bias[col];
          float sc = expf(scale[dg * 256 + col]);
          if (MODE == 4) Cadd[oi] += sc * v;
          else Cadd[oi] = sc * v;
          if (Cf) Cf[oi] = (f16)v;
        } else if (MODE == 2) {
          v += bias[col];
          float nv = Cadd[oi] + expf(scale[col]) * v;
          if (C) C[oi] = nv;
          if (Cf) Cf[oi] = (f16)nv;
        } else {
          if (bias) v += bias[col];
          if (C) C[oi] = v;
          if (Cf) Cf[oi] = (f16)v;
        }
      }
    }
  }
}

// ---------------- conv edge (CSR order): gather(fp16) + bond(global) + GN + fp16 glin ----------------
__global__ __launch_bounds__(256) void conv_edge_kernel(
    const f16* __restrict__ xp, const int* __restrict__ ea_s,
    const int* __restrict__ src_s, const int* __restrict__ dst_s,
    const float* __restrict__ bond_emb, const float* __restrict__ gate_w,
    const float* __restrict__ val_w, f16* __restrict__ msg) {
  constexpr int RS = 264;  // f16 row stride: 256 + 8 pad
  __shared__ f16 sg[16 * RS];
  __shared__ f16 sv[16 * RS];
  int tid = threadIdx.x;
  for (int i = tid; i < 4096; i += 256) {
    int g = i >> 8, rem = i & 255;
    sg[g * RS + rem] = (f16)gate_w[i];
    sv[g * RS + rem] = (f16)val_w[i];
  }
  __syncthreads();
  int idx = blockIdx.x * 256 + tid;
  int j = idx >> 4, g = idx & 15;
  int a0 = ea_s[j * 3 + 0], a1 = ea_s[j * 3 + 1], a2 = ea_s[j * 3 + 2];
  int d = dst_s[j], s = src_s[j];
  half8 xd0 = *reinterpret_cast<const half8*>(&xp[(size_t)d * 256 + g * 16]);
  half8 xd1 = *reinterpret_cast<const half8*>(&xp[(size_t)d * 256 + g * 16 + 8]);
  half8 xs0 = *reinterpret_cast<const half8*>(&xp[(size_t)s * 256 + g * 16]);
  half8 xs1 = *reinterpret_cast<const half8*>(&xp[(size_t)s * 256 + g * 16 + 8]);
  const float4* b0p = reinterpret_cast<const float4*>(&bond_emb[a0 * 256 + g * 16]);
  const float4* b1p = reinterpret_cast<const float4*>(&bond_emb[2048 + a1 * 256 + g * 16]);
  const float4* b2p = reinterpret_cast<const float4*>(&bond_emb[4096 + a2 * 256 + g * 16]);
  float xg[16], xv[16];
  float mg = 0.f, mv = 0.f;
#pragma unroll
  for (int q = 0; q < 4; q++) {
    float4 b0 = b0p[q], b1 = b1p[q], b2 = b2p[q];
#pragma unroll
    for (int t = 0; t < 4; t++) {
      int i = q * 4 + t;
      float bo = (&b0.x)[t] + (&b1.x)[t] + (&b2.x)[t];
      float xd = (i < 8) ? (float)xd0[i & 7] : (float)xd1[i & 7];
      float xs = (i < 8) ? (float)xs0[i & 7] : (float)xs1[i & 7];
      xg[i] = xd + bo;
      xv[i] = xs + bo;
      mg += xg[i];
      mv += xv[i];
    }
  }
  mg *= (1.f / 16.f);
  mv *= (1.f / 16.f);
  float vg = 0.f, vv = 0.f;
#pragma unroll
  for (int i = 0; i < 16; i++) {
    float dg_ = xg[i] - mg, dv_ = xv[i] - mv;
    vg += dg_ * dg_;
    vv += dv_ * dv_;
  }
  float rg = rsqrtf(vg * (1.f / 16.f) + 1e-5f);
  float rv = rsqrtf(vv * (1.f / 16.f) + 1e-5f);
#ifdef HAVE_FDOT2
  half2v xgh[8], xvh[8];
#pragma unroll
  for (int q = 0; q < 8; q++) {
    xgh[q][0] = (f16)((xg[2 * q] - mg) * rg);
    xgh[q][1] = (f16)((xg[2 * q + 1] - mg) * rg);
    xvh[q][0] = (f16)((xv[2 * q] - mv) * rv);
    xvh[q][1] = (f16)((xv[2 * q + 1] - mv) * rv);
  }
#else
#pragma unroll
  for (int i = 0; i < 16; i++) {
    xg[i] = (xg[i] - mg) * rg;
    xv[i] = (xv[i] - mv) * rv;
  }
#endif
  const f16* gRow = &sg[g * RS];
  const f16* vRow = &sv[g * RS];
  f16 res[16];
#pragma unroll
  for (int o = 0; o < 16; o++) {
    half8 gA = *reinterpret_cast<const half8*>(&gRow[o * 16]);
    half8 gB = *reinterpret_cast<const half8*>(&gRow[o * 16 + 8]);
    half8 vA = *reinterpret_cast<const half8*>(&vRow[o * 16]);
    half8 vB = *reinterpret_cast<const half8*>(&vRow[o * 16 + 8]);
    float ag = 0.f, av = 0.f;
#ifdef HAVE_FDOT2
#pragma unroll
    for (int q = 0; q < 4; q++) {
      half2v ga = {gA[2 * q], gA[2 * q + 1]};
      half2v gb = {gB[2 * q], gB[2 * q + 1]};
      half2v va = {vA[2 * q], vA[2 * q + 1]};
      half2v vb = {vB[2 * q], vB[2 * q + 1]};
      ag = __builtin_amdgcn_fdot2(xgh[q], ga, ag, false);
      ag = __builtin_amdgcn_fdot2(xgh[q + 4], gb, ag, false);
      av = __builtin_amdgcn_fdot2(xvh[q], va, av, false);
      av = __builtin_amdgcn_fdot2(xvh[q + 4], vb, av, false);
    }
#else
#pragma unroll
    for (int i = 0; i < 8; i++) {
      ag += xg[i] * (float)gA[i] + xg[i + 8] * (float)gB[i];
      av += xv[i] * (float)vA[i] + xv[i + 8] * (float)vB[i];
    }
#endif
    res[o] = (f16)(fmaxf(ag, 0.f) * av);
  }
  uint4* op = reinterpret_cast<uint4*>(&msg[(size_t)j * 256 + g * 16]);
  op[0] = reinterpret_cast<const uint4*>(res)[0];
  op[1] = reinterpret_cast<const uint4*>(res)[1];
}

// ---------------- glb middle: GN + glin + relu*mul ----------------
template <int DOUT>
__global__ __launch_bounds__(256) void glb_mid_kernel(
    const float* __restrict__ X, const float* __restrict__ gate_w,
    const float* __restrict__ val_w, f16* __restrict__ out) {
  constexpr int RS = DOUT * 16 + 8;
  __shared__ f16 sg[16 * RS];
  __shared__ f16 sv[16 * RS];
  int tid = threadIdx.x;
  for (int i = tid; i < 16 * DOUT * 16; i += 256) {
    int g = i / (DOUT * 16), rem = i % (DOUT * 16);
    sg[g * RS + rem] = (f16)gate_w[i];
    sv[g * RS + rem] = (f16)val_w[i];
  }
  __syncthreads();
  int idx = blockIdx.x * 256 + tid;
  int n = idx >> 4, g = idx & 15;
  float x[16];
  float m = 0.f;
  const float4* xp4 = reinterpret_cast<const float4*>(&X[(size_t)n * 256 + g * 16]);
#pragma unroll
  for (int q = 0; q < 4; q++) {
    float4 xq = xp4[q];
#pragma unroll
    for (int t = 0; t < 4; t++) {
      x[q * 4 + t] = (&xq.x)[t];
      m += (&xq.x)[t];
    }
  }
  m *= (1.f / 16.f);
  float v = 0.f;
#pragma unroll
  for (int i = 0; i < 16; i++) {
    float d_ = x[i] - m;
    v += d_ * d_;
  }
  float r = rsqrtf(v * (1.f / 16.f) + 1e-5f);
#pragma unroll
  for (int i = 0; i < 16; i++) x[i] = (x[i] - m) * r;
#ifdef HAVE_FDOT2
  half2v xh[8];
#pragma unroll
  for (int q = 0; q < 8; q++) { xh[q][0] = (f16)x[2 * q]; xh[q][1] = (f16)x[2 * q + 1]; }
#endif
  const f16* gRow = &sg[g * RS];
  const f16* vRow = &sv[g * RS];
  f16 res[DOUT];
#pragma unroll
  for (int o = 0; o < DOUT; o++) {
    half8 gA = *reinterpret_cast<const half8*>(&gRow[o * 16]);
    half8 gB = *reinterpret_cast<const half8*>(&gRow[o * 16 + 8]);
    half8 vA = *reinterpret_cast<const half8*>(&vRow[o * 16]);
    half8 vB = *reinterpret_cast<const half8*>(&vRow[o * 16 + 8]);
    float ag = 0.f, av = 0.f;
#ifdef HAVE_FDOT2
#pragma unroll
    for (int q = 0; q < 4; q++) {
      half2v gq = {gA[2 * q], gA[2 * q + 1]};
      half2v g2 = {gB[2 * q], gB[2 * q + 1]};
      half2v vq = {vA[2 * q], vA[2 * q + 1]};
      half2v v2 = {vB[2 * q], vB[2 * q + 1]};
      ag = __builtin_amdgcn_fdot2(xh[q], gq, ag, false);
      ag = __builtin_amdgcn_fdot2(xh[q + 4], g2, ag, false);
      av = __builtin_amdgcn_fdot2(xh[q], vq, av, false);
      av = __builtin_amdgcn_fdot2(xh[q + 4], v2, av, false);
    }
#else
#pragma unroll
    for (int i = 0; i < 8; i++) {
      ag += x[i] * (float)gA[i] + x[i + 8] * (float)gB[i];
      av += x[i] * (float)vA[i] + x[i + 8] * (float)vB[i];
    }
#endif
    res[o] = (f16)(fmaxf(ag, 0.f) * av);
  }
  f16* op = &out[(size_t)n * (16 * DOUT) + g * DOUT];
#pragma unroll
  for (int q = 0; q < DOUT / 8; q++)
    *reinterpret_cast<half8*>(&op[q * 8]) = *reinterpret_cast<const half8*>(&res[q * 8]);
}

// vectorized GroupNorm in place
__global__ __launch_bounds__(256) void gn_vec_kernel(float* __restrict__ X) {
  int idx = blockIdx.x * 256 + threadIdx.x;
  int n = idx >> 6, q = idx & 63;
  float4 x = *reinterpret_cast<const float4*>(&X[(size_t)n * 256 + q * 4]);
  float s = x.x + x.y + x.z + x.w;
  float s2 = x.x * x.x + x.y * x.y + x.z * x.z + x.w * x.w;
  s += __shfl_xor(s, 1); s2 += __shfl_xor(s2, 1);
  s += __shfl_xor(s, 2); s2 += __shfl_xor(s2, 2);
  float m = s * (1.f / 16.f);
  float var = s2 * (1.f / 16.f) - m * m;
  float r = rsqrtf(var + 1e-5f);
  x.x = (x.x - m) * r; x.y = (x.y - m) * r;
  x.z = (x.z - m) * r; x.w = (x.w - m) * r;
  *reinterpret_cast<float4*>(&X[(size_t)n * 256 + q * 4]) = x;
}

// ---------------- attention ----------------
// h_att layout (workspace-internal): [b][h][head][v] = b*8192 + h*512 + head*16 + v
// 2 blocks per graph: block (b, half) owns output cols p = half*256 + tid.
__global__ __launch_bounds__(256) void att_graph_kernel(
    const float* __restrict__ xv0, const float* __restrict__ k_w,
    const float* __restrict__ v_w, const int* __restrict__ goff,
    float* __restrict__ h_att, float* __restrict__ xk_sum) {
  __shared__ float kx[8][256];
  __shared__ float vx[8][256];
  __shared__ float rows[8][256];
  const int tid = threadIdx.x;
  const int b = blockIdx.x >> 1, half = blockIdx.x & 1;
  const int p = half * 256 + tid;
  const int g = p >> 5;
  const int headLocal = tid >> 4;
  const int head = p >> 4, h = p & 15;
  float wk[16], wv[16];
#pragma unroll
  for (int i = 0; i < 4; i++) {
    float4 k0 = *reinterpret_cast<const float4*>(&k_w[p * 16 + i * 4]);
    float4 v0 = *reinterpret_cast<const float4*>(&v_w[p * 16 + i * 4]);
    wk[i * 4 + 0] = k0.x; wk[i * 4 + 1] = k0.y; wk[i * 4 + 2] = k0.z; wk[i * 4 + 3] = k0.w;
    wv[i * 4 + 0] = v0.x; wv[i * 4 + 1] = v0.y; wv[i * 4 + 2] = v0.z; wv[i * 4 + 3] = v0.w;
  }
  float hacc[16];
  const float* hg = &h_att[(size_t)b * 8192];
#pragma unroll
  for (int j = 0; j < 16; j++) hacc[j] = hg[h * 512 + head * 16 + j];
  float ks = 0.f;
  const int n0 = goff[b], n1 = goff[b + 1];
  float r[8];
#pragma unroll
  for (int nn = 0; nn < 8; nn++) {
    int n = n0 + nn;
    r[nn] = (n < n1) ? xv0[(size_t)n * 256 + tid] : 0.f;
  }
  for (int nbase = n0; nbase < n1; nbase += 8) {
#pragma unroll
    for (int nn = 0; nn < 8; nn++) rows[nn][tid] = r[nn];
    __syncthreads();
#pragma unroll
    for (int nn = 0; nn < 8; nn++) {
      int n = nbase + 8 + nn;
      r[nn] = (n < n1) ? xv0[(size_t)n * 256 + tid] : 0.f;
    }
#pragma unroll
    for (int nn = 0; nn < 8; nn++) {
      const float4* rp = reinterpret_cast<const float4*>(&rows[nn][g * 16]);
      float aK = 0.f, aV = 0.f;
#pragma unroll
      for (int q = 0; q < 4; q++) {
        float4 x0 = rp[q];
#pragma unroll
        for (int t = 0; t < 4; t++) {
          float e0 = (&x0.x)[t];
          aK += e0 * wk[q * 4 + t];
          aV += e0 * wv[q * 4 + t];
        }
      }
      bool valid = (nbase + nn) < n1;
      float ek = valid ? expf(aK * 0.25f) : 0.f;
      kx[nn][tid] = ek;
      vx[nn][tid] = aV;
      ks += ek;
    }
    __syncthreads();
#pragma unroll
    for (int nn = 0; nn < 8; nn++) {
      float kk = kx[nn][tid];
      const float4* vp = reinterpret_cast<const float4*>(&vx[nn][headLocal * 16]);
#pragma unroll
      for (int q = 0; q < 4; q++) {
        float4 vq = vp[q];
        hacc[q * 4 + 0] += kk * vq.x;
        hacc[q * 4 + 1] += kk * vq.y;
        hacc[q * 4 + 2] += kk * vq.z;
        hacc[q * 4 + 3] += kk * vq.w;
      }
    }
    __syncthreads();
  }
  float* hgo = &h_att[(size_t)b * 8192];
#pragma unroll
  for (int j = 0; j < 16; j++) hgo[h * 512 + head * 16 + j] = hacc[j];
  xk_sum[(size_t)b * 512 + p] = ks;
}

// wave = 1 node; lane = (head, half): head=lane>>1, half=lane&1 handles v in [half*8, half*8+8)
__global__ __launch_bounds__(256) void att_out_kernel(
    const float* __restrict__ xv0, const float* __restrict__ q_w,
    const float* __restrict__ xk_sum, const float* __restrict__ h_att,
    const int* __restrict__ batch, f16* __restrict__ out) {
  __shared__ float sqw[16 * 260];  // [g][oo*16+i], stride 260 (16B aligned, bank-spread)
  int tid = threadIdx.x;
  for (int i = tid; i < 8192; i += 256) {
    int g = i >> 9, rem = i & 511;  // q_w layout [g][32][16]
    sqw[g * 260 + rem] = q_w[i];
  }
  __syncthreads();
  int wave = tid >> 6, lane = tid & 63;
  int n = blockIdx.x * 4 + wave;
  int head = lane >> 1, half = lane & 1;
  int g = head >> 1, j = head & 1;
  int b = batch[n];
  float x[16];
  const float4* xp4 = reinterpret_cast<const float4*>(&xv0[(size_t)n * 256 + g * 16]);
#pragma unroll
  for (int q = 0; q < 4; q++) {
    float4 xq = xp4[q];
#pragma unroll
    for (int t = 0; t < 4; t++) x[q * 4 + t] = (&xq.x)[t];
  }
  float qv[16];
  float denom = 0.f;
  const float* ks = &xk_sum[(size_t)b * 512 + head * 16];
#pragma unroll
  for (int h = 0; h < 16; h++) {
    const float4* wp = reinterpret_cast<const float4*>(&sqw[g * 260 + (j * 16 + h) * 16]);
    float a = 0.f;
#pragma unroll
    for (int q = 0; q < 4; q++) {
      float4 wq = wp[q];
#pragma unroll
      for (int t = 0; t < 4; t++) a += x[q * 4 + t] * (&wq.x)[t];
    }
    float e = expf(a * 0.25f);
    qv[h] = e;
    denom += e * ks[h];
  }
  float inv = 1.f / denom;
  float acc[8] = {0.f, 0.f, 0.f, 0.f, 0.f, 0.f, 0.f, 0.f};
  const float* hb = &h_att[(size_t)b * 8192 + head * 16 + half * 8];
#pragma unroll
  for (int h = 0; h < 16; h++) {
    float4 v0 = *reinterpret_cast<const float4*>(&hb[h * 512]);
    float4 v1 = *reinterpret_cast<const float4*>(&hb[h * 512 + 4]);
    float qh = qv[h];
    acc[0] += qh * v0.x; acc[1] += qh * v0.y; acc[2] += qh * v0.z; acc[3] += qh * v0.w;
    acc[4] += qh * v1.x; acc[5] += qh * v1.y; acc[6] += qh * v1.z; acc[7] += qh * v1.w;
  }
  half8 res;
#pragma unroll
  for (int v = 0; v < 8; v++) res[v] = (f16)(acc[v] * inv);
  *reinterpret_cast<half8*>(&out[(size_t)n * 512 + head * 16 + half * 8]) = res;
}

__global__ __launch_bounds__(256) void virt_seg_kernel(const float* __restrict__ h_in,
    const int* __restrict__ goff, float* __restrict__ h_virt) {
  int b = blockIdx.x, c = threadIdx.x;
  float acc = h_virt[(size_t)b * 256 + c];
  int n0 = goff[b], n1 = goff[b + 1];
  for (int n = n0; n < n1; n++) acc += h_in[(size_t)n * 256 + c];
  h_virt[(size_t)b * 256 + c] = acc;
}

// ---------------- host driver ----------------

extern "C" void kernel_launch(void* const* d_in, const int* in_sizes, int n_in,
                              void* d_out, int out_size, void* d_ws, size_t ws_size,
                              hipStream_t stream) {
  const int* x_feat = (const int*)d_in[0];
  const int* eidx = (const int*)d_in[1];
  const int* eattr = (const int*)d_in[2];
  const int* batch = (const int*)d_in[3];
  const float* edist = (const float*)d_in[5];
  const float* atom_emb = (const float*)d_in[6];
  const float* bond2d = (const float*)d_in[7];
  const float* gmeans = (const float*)d_in[8];
  const float* gstds = (const float*)d_in[9];
  const float* attn_w = (const float*)d_in[10];
  const float* attn_b = (const float*)d_in[11];
  const float* scale_both = (const float*)d_in[12];
  const float* conv_bond_emb = (const float*)d_in[13];
  const float* conv_pre_w = (const float*)d_in[14];
  const float* conv_gate_w = (const float*)d_in[15];
  const float* conv_val_w = (const float*)d_in[16];
  const float* conv_post_w = (const float*)d_in[17];
  const float* conv_post_b = (const float*)d_in[18];
  const float* conv_scale = (const float*)d_in[19];
  const float* virt_pre_w = (const float*)d_in[20];
  const float* virt_pre_b = (const float*)d_in[21];
  const float* virt_gate_w = (const float*)d_in[22];
  const float* virt_val_w = (const float*)d_in[23];
  const float* virt_post_w = (const float*)d_in[24];
  const float* virt_post_b = (const float*)d_in[25];
  const float* virt_scale = (const float*)d_in[26];
  const float* att_pre_w = (const float*)d_in[27];
  const float* att_pre_b = (const float*)d_in[28];
  const float* att_q_w = (const float*)d_in[29];
  const float* att_k_w = (const float*)d_in[30];
  const float* att_v_w = (const float*)d_in[31];
  const float* att_post_w = (const float*)d_in[32];
  const float* att_post_b = (const float*)d_in[33];
  const float* att_scale = (const float*)d_in[34];
  const float* main_pre_w = (const float*)d_in[35];
  const float* main_pre_b = (const float*)d_in[36];
  const float* main_gate_w = (const float*)d_in[37];
  const float* main_val_w = (const float*)d_in[38];
  const float* main_post_w = (const float*)d_in[39];
  const float* main_post_b = (const float*)d_in[40];

  const int* src = eidx;
  const int* dst = eidx + EE;

  float* ws = (float*)d_ws;
  float* h_in = ws;
  float* h_out = ws + ND;
  float* x_raw = ws + 2 * ND;
  float* x_out = ws + 3 * ND;
  float* nodeA = ws + 4 * ND;
  f16* h_inH = (f16*)(ws + 5 * ND);
  f16* xrawH = (f16*)(ws + 5 * ND + ND / 2);
  f16* hTmp = (f16*)(ws + 6 * ND);
  f16* msgH = (f16*)(ws + 6 * ND + ND / 2);   // 3*ND halfs
  float* sm = ws + 8 * ND;
  f16* hW = (f16*)sm;                          // 2359296 halfs = 1179648 floats
  float* h_virt = sm + 1179648;
  float* h_att = h_virt + 65536;
  float* xk_sum = h_att + 2097152;
  float* vt1 = xk_sum + 131072;
  float* vout = vt1 + 65536;
  f16* vmidH = (f16*)(vout + 65536);           // B*512 halfs
  f16* virtH = vmidH + 131072;                 // B*256 halfs
  int* cnt = (int*)(virtH + 65536);
  int* deg = cnt + NN;
  int* goff = deg + NN;
  int* off = goff + BB + 1;
  int* cursor = off + NN + 1;
  int* elist = cursor + NN;
  int* ea_s = elist + EE;
  int* src_s = ea_s + 3 * EE;
  int* dst_s = src_s + EE;
  float* ed_s = (float*)(dst_s + EE);

  f16* wCpre = hW;
  f16* wCpost = hW + 524288;
  f16* wApre = hW + 1048576;
  f16* wApost = hW + 1179648;
  f16* wMpre = hW + 1441792;
  f16* wMpost = hW + 1572864;
  f16* wVpre = hW + 1966080;
  f16* wVpost = hW + 2097152;

  auto cvt = [&](const float* in, f16* out, int n) {
    f2h_kernel<<<n / 4 / 256, 256, 0, stream>>>(in, out, n / 4);
  };

  cvt(conv_pre_w, wCpre, 524288);
  cvt(conv_post_w, wCpost, 524288);
  cvt(att_pre_w, wApre, 131072);
  cvt(att_post_w, wApost, 262144);
  cvt(main_pre_w, wMpre, 131072);
  cvt(main_post_w, wMpost, 393216);
  cvt(virt_pre_w, wVpre, 131072);
  cvt(virt_post_w, wVpost, 262144);

  // degree + graph offsets + CSR (edges grouped by dst) + gathered edge data
  (void)hipMemsetAsync(cnt, 0, NN * sizeof(int), stream);
  count_deg_kernel<<<EE / 256, 256, 0, stream>>>(dst, cnt, EE);
  clip_deg_kernel<<<NN / 256, 256, 0, stream>>>(cnt, deg, NN);
  goff_kernel<<<(NN + 256) / 256, 256, 0, stream>>>(batch, goff, NN, BB);
  scan_off_kernel<<<1, 256, 0, stream>>>(cnt, off);
  copy_i_kernel<<<NN / 256, 256, 0, stream>>>(off, cursor, NN);
  fill_elist_kernel<<<EE / 256, 256, 0, stream>>>(dst, cursor, elist, EE);
  gather_edges_kernel<<<EE / 256, 256, 0, stream>>>(elist, eattr, src, dst, edist,
                                                    ea_s, src_s, dst_s, ed_s);

  // initial node features
  edge_feat_kernel<<<EE / 4, 256, 0, stream>>>(ea_s, ed_s, bond2d, gmeans, gstds,
                                               attn_w, attn_b, msgH);
  seg_reduce_kernel<float><<<NN / 4, 256, 0, stream>>>(msgH, off, x_out);
  atom_finish_kernel<<<NN * 64 / 256, 256, 0, stream>>>(x_feat, atom_emb, scale_both, deg,
                                                        x_out, h_in, h_inH);
  (void)hipMemsetAsync(h_virt, 0, 65536 * 4, stream);
  (void)hipMemsetAsync(h_att, 0, 2097152 * 4, stream);

  const dim3 gN(NN / 128, 4), gB(BB / 128, 4);
  const int n4 = (int)(ND / 4);

  for (int l = 0; l < 2; l++) {
    // ---- ConvMessage ----
    const f16* curH = h_inH;
    for (int k = 0; k < 4; k++) {
      if (k == 2) {
        add3_both_kernel<<<n4 / 256, 256, 0, stream>>>(x_raw, xrawH, h_in, x_out, n4);
        curH = xrawH;
      }
      size_t lk = (size_t)(l * 4 + k);
      hgemm_kernel<0><<<gN, 256, 0, stream>>>(curH, wCpre + lk * 65536, nullptr, nullptr,
                                              nullptr, nullptr, nullptr, nullptr, hTmp, 256);
      conv_edge_kernel<<<EE * 16 / 256, 256, 0, stream>>>(
          hTmp, ea_s, src_s, dst_s, conv_bond_emb + lk * 6144,
          conv_gate_w + lk * 4096, conv_val_w + lk * 4096, msgH);
      seg_reduce_kernel<f16><<<NN / 4, 256, 0, stream>>>(msgH, off, hTmp);
      if (k == 0 || k == 2)
        hgemm_kernel<5><<<gN, 256, 0, stream>>>(hTmp, wCpost + lk * 65536,
                                                conv_post_b + lk * 256, conv_scale + lk * 1024,
                                                cnt, deg, nullptr, x_out, xrawH, 256);
      else
        hgemm_kernel<4><<<gN, 256, 0, stream>>>(hTmp, wCpost + lk * 65536,
                                                conv_post_b + lk * 256, conv_scale + lk * 1024,
                                                cnt, deg, nullptr, x_out, xrawH, 256);
      curH = xrawH;
    }
    add3_kernel<<<n4 / 256, 256, 0, stream>>>(h_out, h_in, x_out, n4);

    // ---- VirtMessage ----
    virt_seg_kernel<<<BB, 256, 0, stream>>>(h_in, goff, h_virt);
    cvt(h_virt, virtH, 65536);
    hgemm_kernel<0><<<gB, 256, 0, stream>>>(virtH, wVpre + (size_t)l * 65536,
                                            virt_pre_b + (size_t)l * 256, nullptr, nullptr,
                                            nullptr, vt1, nullptr, nullptr, 256);
    glb_mid_kernel<32><<<BB * 16 / 256, 256, 0, stream>>>(
        vt1, virt_gate_w + (size_t)l * 8192, virt_val_w + (size_t)l * 8192, vmidH);
    hgemm_kernel<0><<<gB, 256, 0, stream>>>(vmidH, wVpost + (size_t)l * 131072,
                                            virt_post_b + (size_t)l * 256, nullptr, nullptr,
                                            nullptr, vout, nullptr, nullptr, 512);
    bcast_add_kernel<<<n4 / 256, 256, 0, stream>>>(
        h_out, vout, virt_scale + (size_t)l * 256, batch);

    // ---- AttMessage ----
    hgemm_kernel<0><<<gN, 256, 0, stream>>>(h_inH, wApre + (size_t)l * 65536,
                                            att_pre_b + (size_t)l * 256, nullptr, nullptr,
                                            nullptr, nodeA, nullptr, nullptr, 256);
    gn_vec_kernel<<<NN * 64 / 256, 256, 0, stream>>>(nodeA);
    att_graph_kernel<<<BB * 2, 256, 0, stream>>>(
        nodeA, att_k_w + (size_t)l * 8192, att_v_w + (size_t)l * 8192, goff, h_att, xk_sum);
    att_out_kernel<<<NN / 4, 256, 0, stream>>>(
        nodeA, att_q_w + (size_t)l * 8192, xk_sum, h_att, batch, msgH);
    hgemm_kernel<2><<<gN, 256, 0, stream>>>(msgH, wApost + (size_t)l * 131072,
                                            att_post_b + (size_t)l * 256,
                                            att_scale + (size_t)l * 256, nullptr, nullptr,
                                            nullptr, h_out, hTmp, 512);

    // ---- main gated block ----
    hgemm_kernel<0><<<gN, 256, 0, stream>>>(hTmp, wMpre + (size_t)l * 65536,
                                            main_pre_b + (size_t)l * 256, nullptr, nullptr,
                                            nullptr, nodeA, nullptr, nullptr, 256);
    glb_mid_kernel<48><<<NN * 16 / 256, 256, 0, stream>>>(
        nodeA, main_gate_w + (size_t)l * 12288, main_val_w + (size_t)l * 12288, msgH);
    float* hdst = (l == 1) ? (float*)d_out : h_in;
    f16* hdstH = (l == 1) ? nullptr : h_inH;
    hgemm_kernel<0><<<gN, 256, 0, stream>>>(msgH, wMpost + (size_t)l * 196608,
                                            main_post_b + (size_t)l * 256, nullptr, nullptr,
                                            nullptr, hdst, nullptr, hdstH, 768);
  }
}

// Round 10
// 1053.770 us; speedup vs baseline: 6.6157x; 1.0113x over previous
//
#include <hip/hip_runtime.h>
#include <cstdint>
#include <cstddef>
#include <type_traits>

#define NN 16384
#define EE 49152
#define BB 256
// D=256, G=16, 16 channels per group, HD=16

typedef _Float16 f16;
typedef _Float16 half8 __attribute__((ext_vector_type(8)));
typedef _Float16 half4v __attribute__((ext_vector_type(4)));
typedef _Float16 half2v __attribute__((ext_vector_type(2)));
typedef float floatx4 __attribute__((ext_vector_type(4)));

#if defined(__has_builtin)
#if __has_builtin(__builtin_amdgcn_fdot2)
#define HAVE_FDOT2 1
#endif
#endif

static constexpr size_t ND = (size_t)NN * 256;

// ---------------- setup kernels ----------------

__global__ __launch_bounds__(256) void count_deg_kernel(const int* __restrict__ dst, int* __restrict__ cnt, int e) {
  int i = blockIdx.x * 256 + threadIdx.x;
  if (i < e) atomicAdd(&cnt[dst[i]], 1);
}
__global__ __launch_bounds__(256) void clip_deg_kernel(const int* __restrict__ cnt, int* __restrict__ deg, int n) {
  int i = blockIdx.x * 256 + threadIdx.x;
  if (i < n) { int v = cnt[i] - 1; deg[i] = v < 0 ? 0 : (v > 3 ? 3 : v); }
}
__global__ __launch_bounds__(256) void goff_kernel(const int* __restrict__ batch, int* __restrict__ goff, int n, int b) {
  int i = blockIdx.x * 256 + threadIdx.x;
  if (i > n) return;
  int cur = (i < n) ? batch[i] : b;
  int prev = (i == 0) ? -1 : batch[i - 1];
  for (int x = prev + 1; x <= cur; x++) goff[x] = i;
}
__global__ __launch_bounds__(256) void scan_off_kernel(const int* __restrict__ cnt, int* __restrict__ off) {
  __shared__ int part[256];
  int tid = threadIdx.x;
  int base = tid * 64;
  int s = 0;
  for (int i = 0; i < 64; i++) s += cnt[base + i];
  part[tid] = s;
  __syncthreads();
  for (int o = 1; o < 256; o <<= 1) {
    int t = (tid >= o) ? part[tid - o] : 0;
    __syncthreads();
    part[tid] += t;
    __syncthreads();
  }
  int run = (tid == 0) ? 0 : part[tid - 1];
  for (int i = 0; i < 64; i++) {
    off[base + i] = run;
    run += cnt[base + i];
  }
  if (tid == 255) off[NN] = run;
}
__global__ __launch_bounds__(256) void copy_i_kernel(const int* __restrict__ a, int* __restrict__ b, int n) {
  int i = blockIdx.x * 256 + threadIdx.x;
  if (i < n) b[i] = a[i];
}
__global__ __launch_bounds__(256) void fill_elist_kernel(const int* __restrict__ dst,
    int* __restrict__ cursor, int* __restrict__ elist, int e) {
  int i = blockIdx.x * 256 + threadIdx.x;
  if (i < e) {
    int p = atomicAdd(&cursor[dst[i]], 1);
    elist[p] = i;
  }
}
// gather edge data into CSR (dst-sorted) order
__global__ __launch_bounds__(256) void gather_edges_kernel(const int* __restrict__ elist,
    const int* __restrict__ eattr, const int* __restrict__ src, const int* __restrict__ dst,
    const float* __restrict__ edist, int* __restrict__ ea_s, int* __restrict__ src_s,
    int* __restrict__ dst_s, float* __restrict__ ed_s) {
  int j = blockIdx.x * 256 + threadIdx.x;
  if (j >= EE) return;
  int e = elist[j];
  ea_s[j * 3 + 0] = eattr[e * 3 + 0];
  ea_s[j * 3 + 1] = eattr[e * 3 + 1];
  ea_s[j * 3 + 2] = eattr[e * 3 + 2];
  src_s[j] = src[e];
  dst_s[j] = dst[e];
  ed_s[j] = edist[e];
}
// float4 elementwise
__global__ __launch_bounds__(256) void add3_kernel(float* __restrict__ dst,
    const float* __restrict__ a, const float* __restrict__ b, int n4) {
  int i = blockIdx.x * 256 + threadIdx.x;
  if (i >= n4) return;
  float4 x = reinterpret_cast<const float4*>(a)[i];
  float4 y = reinterpret_cast<const float4*>(b)[i];
  x.x += y.x; x.y += y.y; x.z += y.z; x.w += y.w;
  reinterpret_cast<float4*>(dst)[i] = x;
}
__global__ __launch_bounds__(256) void add3_both_kernel(float* __restrict__ dst, f16* __restrict__ dstH,
    const float* __restrict__ a, const float* __restrict__ b, int n4) {
  int i = blockIdx.x * 256 + threadIdx.x;
  if (i >= n4) return;
  float4 x = reinterpret_cast<const float4*>(a)[i];
  float4 y = reinterpret_cast<const float4*>(b)[i];
  x.x += y.x; x.y += y.y; x.z += y.z; x.w += y.w;
  reinterpret_cast<float4*>(dst)[i] = x;
  half4v h;
  h[0] = (f16)x.x; h[1] = (f16)x.y; h[2] = (f16)x.z; h[3] = (f16)x.w;
  reinterpret_cast<half4v*>(dstH)[i] = h;
}
__global__ __launch_bounds__(256) void bcast_add_kernel(float* __restrict__ ho,
    const float* __restrict__ vo, const float* __restrict__ vs, const int* __restrict__ batch) {
  int i4 = blockIdx.x * 256 + threadIdx.x;
  int i = i4 * 4;
  int n = i >> 8, c = i & 255;
  float4 h = reinterpret_cast<const float4*>(&ho[i])[0];
  float4 v = *reinterpret_cast<const float4*>(&vo[(size_t)batch[n] * 256 + c]);
  float4 s = *reinterpret_cast<const float4*>(&vs[c]);
  h.x += expf(s.x) * v.x; h.y += expf(s.y) * v.y;
  h.z += expf(s.z) * v.z; h.w += expf(s.w) * v.w;
  *reinterpret_cast<float4*>(&ho[i]) = h;
}
__global__ __launch_bounds__(256) void f2h_kernel(const float* __restrict__ in, f16* __restrict__ out, int n4) {
  int i = blockIdx.x * 256 + threadIdx.x;
  if (i >= n4) return;
  float4 v = reinterpret_cast<const float4*>(in)[i];
  half4v o;
  o[0] = (f16)v.x; o[1] = (f16)v.y; o[2] = (f16)v.z; o[3] = (f16)v.w;
  reinterpret_cast<half4v*>(out)[i] = o;
}

// ---------------- segment reduce over CONTIGUOUS CSR rows ----------------
template <typename OUT>
__global__ __launch_bounds__(256) void seg_reduce_kernel(const f16* __restrict__ msg,
    const int* __restrict__ off, OUT* __restrict__ out) {
  int idx = blockIdx.x * 256 + threadIdx.x;
  int n = idx >> 6, c0 = (idx & 63) * 4;
  int j0 = off[n], j1 = off[n + 1];
  float a0 = 0.f, a1 = 0.f, a2 = 0.f, a3 = 0.f;
  int j = j0;
  for (; j + 1 < j1; j += 2) {
    half4v m0 = *reinterpret_cast<const half4v*>(&msg[(size_t)j * 256 + c0]);
    half4v m1 = *reinterpret_cast<const half4v*>(&msg[(size_t)(j + 1) * 256 + c0]);
    a0 += (float)m0[0] + (float)m1[0];
    a1 += (float)m0[1] + (float)m1[1];
    a2 += (float)m0[2] + (float)m1[2];
    a3 += (float)m0[3] + (float)m1[3];
  }
  if (j < j1) {
    half4v m0 = *reinterpret_cast<const half4v*>(&msg[(size_t)j * 256 + c0]);
    a0 += (float)m0[0]; a1 += (float)m0[1]; a2 += (float)m0[2]; a3 += (float)m0[3];
  }
  if constexpr (std::is_same<OUT, float>::value) {
    float4 o = {a0, a1, a2, a3};
    *reinterpret_cast<float4*>(&out[(size_t)n * 256 + c0]) = o;
  } else {
    half4v o;
    o[0] = (f16)a0; o[1] = (f16)a1; o[2] = (f16)a2; o[3] = (f16)a3;
    *reinterpret_cast<half4v*>(&out[(size_t)n * 256 + c0]) = o;
  }
}

// ---------------- initial edge / node features (CSR order) ----------------

__global__ __launch_bounds__(256) void edge_feat_kernel(
    const int* __restrict__ ea_s, const float* __restrict__ ed_s,
    const float* __restrict__ bond2d, const float* __restrict__ gmeans,
    const float* __restrict__ gstds, const float* __restrict__ attn_w,
    const float* __restrict__ attn_b, f16* __restrict__ msg) {
  int lane = threadIdx.x & 63;
  int j = blockIdx.x * 4 + (threadIdx.x >> 6);
  if (j >= EE) return;
  int a0 = ea_s[j * 3 + 0], a1 = ea_s[j * 3 + 1], a2 = ea_s[j * 3 + 2];
  float dist = ed_s[j];
  const float SQ2PI = sqrtf(2.0f * 3.14159f);
  int c0 = lane * 4;
  float4 b0 = *reinterpret_cast<const float4*>(&bond2d[a0 * 256 + c0]);
  float4 b1 = *reinterpret_cast<const float4*>(&bond2d[2048 + a1 * 256 + c0]);
  float4 b2 = *reinterpret_cast<const float4*>(&bond2d[4096 + a2 * 256 + c0]);
  float4 gm = *reinterpret_cast<const float4*>(&gmeans[c0]);
  float4 gs = *reinterpret_cast<const float4*>(&gstds[c0]);
  float4 w2 = *reinterpret_cast<const float4*>(&attn_w[c0]);
  float4 w3 = *reinterpret_cast<const float4*>(&attn_w[256 + c0]);
  float h2[4], h3[4];
  float part = 0.f;
#pragma unroll
  for (int i = 0; i < 4; i++) {
    h2[i] = (&b0.x)[i] + (&b1.x)[i] + (&b2.x)[i];
    float sd = fabsf((&gs.x)[i]) + 0.01f;
    float df = (dist - (&gm.x)[i]) / sd;
    h3[i] = expf(-0.5f * df * df) / (SQ2PI * sd);
    part += (&w2.x)[i] * h2[i] + (&w3.x)[i] * h3[i];
  }
#pragma unroll
  for (int off = 32; off > 0; off >>= 1) part += __shfl_xor(part, off);
  float wg = 1.f / (1.f + expf(-(part + attn_b[0])));
  half4v o;
#pragma unroll
  for (int i = 0; i < 4; i++) o[i] = (f16)(wg * h2[i] + (1.f - wg) * h3[i]);
  *reinterpret_cast<half4v*>(&msg[(size_t)j * 256 + c0]) = o;
}

__global__ __launch_bounds__(256) void atom_finish_kernel(
    const int* __restrict__ xf, const float* __restrict__ emb,
    const float* __restrict__ scale_both, const int* __restrict__ deg,
    const float* __restrict__ tmp, float* __restrict__ h_in, f16* __restrict__ h_inH) {
  int idx = blockIdx.x * 256 + threadIdx.x;
  int n = idx >> 6, c = (idx & 63) * 4;
  float a0 = 0.f, a1 = 0.f, a2 = 0.f, a3 = 0.f;
#pragma unroll
  for (int f = 0; f < 9; f++) {
    int v = xf[n * 9 + f];
    float4 e = *reinterpret_cast<const float4*>(&emb[((size_t)(f * 128 + v)) * 256 + c]);
    a0 += e.x; a1 += e.y; a2 += e.z; a3 += e.w;
  }
  int dg = deg[n];
  float4 s = *reinterpret_cast<const float4*>(&scale_both[dg * 256 + c]);
  float4 t = *reinterpret_cast<const float4*>(&tmp[(size_t)n * 256 + c]);
  float4 r;
  r.x = a0 + expf(s.x) * t.x; r.y = a1 + expf(s.y) * t.y;
  r.z = a2 + expf(s.z) * t.z; r.w = a3 + expf(s.w) * t.w;
  *reinterpret_cast<float4*>(&h_in[(size_t)n * 256 + c]) = r;
  half4v h;
  h[0] = (f16)r.x; h[1] = (f16)r.y; h[2] = (f16)r.z; h[3] = (f16)r.w;
  *reinterpret_cast<half4v*>(&h_inH[(size_t)n * 256 + c]) = h;
}

// ---------------- fp16 MFMA GEMM, tile 128x64, 4 waves (2x2), BK=32, reg prefetch ----------------
// MODE 0: v=acc(+bias); C?=v; Cf?=f16(v)
// MODE 2: v=acc+bias; nv=Cadd[oi]+expf(scale[col])*v; C?=nv; Cf?=f16(nv)
// MODE 4: v=acc+cnt[row]*bias[col]; Cadd[oi]+=expf(scale[deg[row]*256+col])*v; Cf?=f16(v)
// MODE 5: like 4 but Cadd[oi]= (init store)
template <int MODE>
__global__ __launch_bounds__(256) void hgemm_kernel(
    const f16* __restrict__ A, const f16* __restrict__ W,
    const float* __restrict__ bias, const float* __restrict__ scale,
    const int* __restrict__ cnt, const int* __restrict__ deg,
    float* __restrict__ C, float* __restrict__ Cadd, f16* __restrict__ Cf, int K) {
  __shared__ f16 Ah[128 * 40];
  __shared__ f16 Wh[64 * 40];
  const int tid = threadIdx.x;
  const int row0 = blockIdx.x * 128, col0 = blockIdx.y * 64;
  const int lane = tid & 63;
  const int wave = tid >> 6;
  const int wr = (wave >> 1) * 64, wc = (wave & 1) * 32;
  const floatx4 fz = {0.f, 0.f, 0.f, 0.f};
  floatx4 acc[4][2];
#pragma unroll
  for (int m = 0; m < 4; m++)
#pragma unroll
    for (int n = 0; n < 2; n++) acc[m][n] = fz;
  const int q0 = tid * 2;
  const int rA0 = q0 >> 2, pA0 = q0 & 3;
  const int rA1 = (q0 + 1) >> 2, pA1 = (q0 + 1) & 3;
  const int rW = tid >> 2, pW = tid & 3;
  const int kb = (lane >> 4) * 8;
  const int fr = lane & 15;
  uint4 a0 = *reinterpret_cast<const uint4*>(&A[(size_t)(row0 + rA0) * K + pA0 * 8]);
  uint4 a1 = *reinterpret_cast<const uint4*>(&A[(size_t)(row0 + rA1) * K + pA1 * 8]);
  uint4 w0 = *reinterpret_cast<const uint4*>(&W[(size_t)(col0 + rW) * K + pW * 8]);
  for (int k0 = 0;;) {
    *reinterpret_cast<uint4*>(&Ah[rA0 * 40 + pA0 * 8]) = a0;
    *reinterpret_cast<uint4*>(&Ah[rA1 * 40 + pA1 * 8]) = a1;
    *reinterpret_cast<uint4*>(&Wh[rW * 40 + pW * 8]) = w0;
    __syncthreads();
    int kn = k0 + 32;
    if (kn < K) {
      a0 = *reinterpret_cast<const uint4*>(&A[(size_t)(row0 + rA0) * K + kn + pA0 * 8]);
      a1 = *reinterpret_cast<const uint4*>(&A[(size_t)(row0 + rA1) * K + kn + pA1 * 8]);
      w0 = *reinterpret_cast<const uint4*>(&W[(size_t)(col0 + rW) * K + kn + pW * 8]);
    }
    half8 af[4], wf[2];
#pragma unroll
    for (int m = 0; m < 4; m++)
      af[m] = *reinterpret_cast<const half8*>(&Ah[(wr + m * 16 + fr) * 40 + kb]);
#pragma unroll
    for (int n = 0; n < 2; n++)
      wf[n] = *reinterpret_cast<const half8*>(&Wh[(wc + n * 16 + fr) * 40 + kb]);
#pragma unroll
    for (int m = 0; m < 4; m++)
#pragma unroll
      for (int n = 0; n < 2; n++)
        acc[m][n] = __builtin_amdgcn_mfma_f32_16x16x32_f16(af[m], wf[n], acc[m][n], 0, 0, 0);
    if (kn >= K) break;
    __syncthreads();
    k0 = kn;
  }
  const int rl4 = (lane >> 4) * 4, cl = lane & 15;
#pragma unroll
  for (int m = 0; m < 4; m++) {
#pragma unroll
    for (int i = 0; i < 4; i++) {
      int row = row0 + wr + m * 16 + rl4 + i;
      float cb = (MODE >= 4) ? (float)cnt[row] : 1.f;
      int dg = (MODE >= 4) ? deg[row] : 0;
#pragma unroll
      for (int n = 0; n < 2; n++) {
        int col = col0 + wc + n * 16 + cl;
        float v = acc[m][n][i];
        size_t oi = (size_t)row * 256 + col;
        if (MODE >= 4) {
          v += cb * bias[col];
          float sc = expf(scale[dg * 256 + col]);
          if (MODE == 4) Cadd[oi] += sc * v;
          else Cadd[oi] = sc * v;
          if (Cf) Cf[oi] = (f16)v;
        } else if (MODE == 2) {
          v += bias[col];
          float nv = Cadd[oi] + expf(scale[col]) * v;
          if (C) C[oi] = nv;
          if (Cf) Cf[oi] = (f16)nv;
        } else {
          if (bias) v += bias[col];
          if (C) C[oi] = v;
          if (Cf) Cf[oi] = (f16)v;
        }
      }
    }
  }
}

// ---------------- conv edge (CSR order): gather(fp16) + bond(global) + GN + fp16 glin ----------------
__global__ __launch_bounds__(256) void conv_edge_kernel(
    const f16* __restrict__ xp, const int* __restrict__ ea_s,
    const int* __restrict__ src_s, const int* __restrict__ dst_s,
    const float* __restrict__ bond_emb, const float* __restrict__ gate_w,
    const float* __restrict__ val_w, f16* __restrict__ msg) {
  constexpr int RS = 264;  // f16 row stride: 256 + 8 pad
  __shared__ f16 sg[16 * RS];
  __shared__ f16 sv[16 * RS];
  int tid = threadIdx.x;
  for (int i = tid; i < 4096; i += 256) {
    int g = i >> 8, rem = i & 255;
    sg[g * RS + rem] = (f16)gate_w[i];
    sv[g * RS + rem] = (f16)val_w[i];
  }
  __syncthreads();
  int idx = blockIdx.x * 256 + tid;
  int j = idx >> 4, g = idx & 15;
  int a0 = ea_s[j * 3 + 0], a1 = ea_s[j * 3 + 1], a2 = ea_s[j * 3 + 2];
  int d = dst_s[j], s = src_s[j];
  half8 xd0 = *reinterpret_cast<const half8*>(&xp[(size_t)d * 256 + g * 16]);
  half8 xd1 = *reinterpret_cast<const half8*>(&xp[(size_t)d * 256 + g * 16 + 8]);
  half8 xs0 = *reinterpret_cast<const half8*>(&xp[(size_t)s * 256 + g * 16]);
  half8 xs1 = *reinterpret_cast<const half8*>(&xp[(size_t)s * 256 + g * 16 + 8]);
  const float4* b0p = reinterpret_cast<const float4*>(&bond_emb[a0 * 256 + g * 16]);
  const float4* b1p = reinterpret_cast<const float4*>(&bond_emb[2048 + a1 * 256 + g * 16]);
  const float4* b2p = reinterpret_cast<const float4*>(&bond_emb[4096 + a2 * 256 + g * 16]);
  float xg[16], xv[16];
  float mg = 0.f, mv = 0.f;
#pragma unroll
  for (int q = 0; q < 4; q++) {
    float4 b0 = b0p[q], b1 = b1p[q], b2 = b2p[q];
#pragma unroll
    for (int t = 0; t < 4; t++) {
      int i = q * 4 + t;
      float bo = (&b0.x)[t] + (&b1.x)[t] + (&b2.x)[t];
      float xd = (i < 8) ? (float)xd0[i & 7] : (float)xd1[i & 7];
      float xs = (i < 8) ? (float)xs0[i & 7] : (float)xs1[i & 7];
      xg[i] = xd + bo;
      xv[i] = xs + bo;
      mg += xg[i];
      mv += xv[i];
    }
  }
  mg *= (1.f / 16.f);
  mv *= (1.f / 16.f);
  float vg = 0.f, vv = 0.f;
#pragma unroll
  for (int i = 0; i < 16; i++) {
    float dg_ = xg[i] - mg, dv_ = xv[i] - mv;
    vg += dg_ * dg_;
    vv += dv_ * dv_;
  }
  float rg = rsqrtf(vg * (1.f / 16.f) + 1e-5f);
  float rv = rsqrtf(vv * (1.f / 16.f) + 1e-5f);
#ifdef HAVE_FDOT2
  half2v xgh[8], xvh[8];
#pragma unroll
  for (int q = 0; q < 8; q++) {
    xgh[q][0] = (f16)((xg[2 * q] - mg) * rg);
    xgh[q][1] = (f16)((xg[2 * q + 1] - mg) * rg);
    xvh[q][0] = (f16)((xv[2 * q] - mv) * rv);
    xvh[q][1] = (f16)((xv[2 * q + 1] - mv) * rv);
  }
#else
#pragma unroll
  for (int i = 0; i < 16; i++) {
    xg[i] = (xg[i] - mg) * rg;
    xv[i] = (xv[i] - mv) * rv;
  }
#endif
  const f16* gRow = &sg[g * RS];
  const f16* vRow = &sv[g * RS];
  f16 res[16];
#pragma unroll
  for (int o = 0; o < 16; o++) {
    half8 gA = *reinterpret_cast<const half8*>(&gRow[o * 16]);
    half8 gB = *reinterpret_cast<const half8*>(&gRow[o * 16 + 8]);
    half8 vA = *reinterpret_cast<const half8*>(&vRow[o * 16]);
    half8 vB = *reinterpret_cast<const half8*>(&vRow[o * 16 + 8]);
    float ag = 0.f, av = 0.f;
#ifdef HAVE_FDOT2
#pragma unroll
    for (int q = 0; q < 4; q++) {
      half2v ga = {gA[2 * q], gA[2 * q + 1]};
      half2v gb = {gB[2 * q], gB[2 * q + 1]};
      half2v va = {vA[2 * q], vA[2 * q + 1]};
      half2v vb = {vB[2 * q], vB[2 * q + 1]};
      ag = __builtin_amdgcn_fdot2(xgh[q], ga, ag, false);
      ag = __builtin_amdgcn_fdot2(xgh[q + 4], gb, ag, false);
      av = __builtin_amdgcn_fdot2(xvh[q], va, av, false);
      av = __builtin_amdgcn_fdot2(xvh[q + 4], vb, av, false);
    }
#else
#pragma unroll
    for (int i = 0; i < 8; i++) {
      ag += xg[i] * (float)gA[i] + xg[i + 8] * (float)gB[i];
      av += xv[i] * (float)vA[i] + xv[i + 8] * (float)vB[i];
    }
#endif
    res[o] = (f16)(fmaxf(ag, 0.f) * av);
  }
  uint4* op = reinterpret_cast<uint4*>(&msg[(size_t)j * 256 + g * 16]);
  op[0] = reinterpret_cast<const uint4*>(res)[0];
  op[1] = reinterpret_cast<const uint4*>(res)[1];
}

// ---------------- glb middle: GN + glin + relu*mul ----------------
template <int DOUT>
__global__ __launch_bounds__(256) void glb_mid_kernel(
    const float* __restrict__ X, const float* __restrict__ gate_w,
    const float* __restrict__ val_w, f16* __restrict__ out) {
  constexpr int RS = DOUT * 16 + 8;
  __shared__ f16 sg[16 * RS];
  __shared__ f16 sv[16 * RS];
  int tid = threadIdx.x;
  for (int i = tid; i < 16 * DOUT * 16; i += 256) {
    int g = i / (DOUT * 16), rem = i % (DOUT * 16);
    sg[g * RS + rem] = (f16)gate_w[i];
    sv[g * RS + rem] = (f16)val_w[i];
  }
  __syncthreads();
  int idx = blockIdx.x * 256 + tid;
  int n = idx >> 4, g = idx & 15;
  float x[16];
  float m = 0.f;
  const float4* xp4 = reinterpret_cast<const float4*>(&X[(size_t)n * 256 + g * 16]);
#pragma unroll
  for (int q = 0; q < 4; q++) {
    float4 xq = xp4[q];
#pragma unroll
    for (int t = 0; t < 4; t++) {
      x[q * 4 + t] = (&xq.x)[t];
      m += (&xq.x)[t];
    }
  }
  m *= (1.f / 16.f);
  float v = 0.f;
#pragma unroll
  for (int i = 0; i < 16; i++) {
    float d_ = x[i] - m;
    v += d_ * d_;
  }
  float r = rsqrtf(v * (1.f / 16.f) + 1e-5f);
#pragma unroll
  for (int i = 0; i < 16; i++) x[i] = (x[i] - m) * r;
#ifdef HAVE_FDOT2
  half2v xh[8];
#pragma unroll
  for (int q = 0; q < 8; q++) { xh[q][0] = (f16)x[2 * q]; xh[q][1] = (f16)x[2 * q + 1]; }
#endif
  const f16* gRow = &sg[g * RS];
  const f16* vRow = &sv[g * RS];
  f16 res[DOUT];
#pragma unroll
  for (int o = 0; o < DOUT; o++) {
    half8 gA = *reinterpret_cast<const half8*>(&gRow[o * 16]);
    half8 gB = *reinterpret_cast<const half8*>(&gRow[o * 16 + 8]);
    half8 vA = *reinterpret_cast<const half8*>(&vRow[o * 16]);
    half8 vB = *reinterpret_cast<const half8*>(&vRow[o * 16 + 8]);
    float ag = 0.f, av = 0.f;
#ifdef HAVE_FDOT2
#pragma unroll
    for (int q = 0; q < 4; q++) {
      half2v gq = {gA[2 * q], gA[2 * q + 1]};
      half2v g2 = {gB[2 * q], gB[2 * q + 1]};
      half2v vq = {vA[2 * q], vA[2 * q + 1]};
      half2v v2 = {vB[2 * q], vB[2 * q + 1]};
      ag = __builtin_amdgcn_fdot2(xh[q], gq, ag, false);
      ag = __builtin_amdgcn_fdot2(xh[q + 4], g2, ag, false);
      av = __builtin_amdgcn_fdot2(xh[q], vq, av, false);
      av = __builtin_amdgcn_fdot2(xh[q + 4], v2, av, false);
    }
#else
#pragma unroll
    for (int i = 0; i < 8; i++) {
      ag += x[i] * (float)gA[i] + x[i + 8] * (float)gB[i];
      av += x[i] * (float)vA[i] + x[i + 8] * (float)vB[i];
    }
#endif
    res[o] = (f16)(fmaxf(ag, 0.f) * av);
  }
  f16* op = &out[(size_t)n * (16 * DOUT) + g * DOUT];
#pragma unroll
  for (int q = 0; q < DOUT / 8; q++)
    *reinterpret_cast<half8*>(&op[q * 8]) = *reinterpret_cast<const half8*>(&res[q * 8]);
}

// vectorized GroupNorm in place
__global__ __launch_bounds__(256) void gn_vec_kernel(float* __restrict__ X) {
  int idx = blockIdx.x * 256 + threadIdx.x;
  int n = idx >> 6, q = idx & 63;
  float4 x = *reinterpret_cast<const float4*>(&X[(size_t)n * 256 + q * 4]);
  float s = x.x + x.y + x.z + x.w;
  float s2 = x.x * x.x + x.y * x.y + x.z * x.z + x.w * x.w;
  s += __shfl_xor(s, 1); s2 += __shfl_xor(s2, 1);
  s += __shfl_xor(s, 2); s2 += __shfl_xor(s2, 2);
  float m = s * (1.f / 16.f);
  float var = s2 * (1.f / 16.f) - m * m;
  float r = rsqrtf(var + 1e-5f);
  x.x = (x.x - m) * r; x.y = (x.y - m) * r;
  x.z = (x.z - m) * r; x.w = (x.w - m) * r;
  *reinterpret_cast<float4*>(&X[(size_t)n * 256 + q * 4]) = x;
}

// ---------------- attention ----------------
// h_att layout (workspace-internal): [b][h][head][v] = b*8192 + h*512 + head*16 + v
// 2 blocks per graph: block (b, half) owns output cols p = half*256 + tid.
// FIRST=true: h_att starts at zero (no read); else accumulate onto previous layer.
template <bool FIRST>
__global__ __launch_bounds__(256) void att_graph_kernel(
    const float* __restrict__ xv0, const float* __restrict__ k_w,
    const float* __restrict__ v_w, const int* __restrict__ goff,
    float* __restrict__ h_att, float* __restrict__ xk_sum) {
  __shared__ float kx[8][256];
  __shared__ float vx[8][256];
  __shared__ float rows[8][256];
  const int tid = threadIdx.x;
  const int b = blockIdx.x >> 1, half = blockIdx.x & 1;
  const int p = half * 256 + tid;
  const int g = p >> 5;
  const int headLocal = tid >> 4;
  const int head = p >> 4, h = p & 15;
  float wk[16], wv[16];
#pragma unroll
  for (int i = 0; i < 4; i++) {
    float4 k0 = *reinterpret_cast<const float4*>(&k_w[p * 16 + i * 4]);
    float4 v0 = *reinterpret_cast<const float4*>(&v_w[p * 16 + i * 4]);
    wk[i * 4 + 0] = k0.x; wk[i * 4 + 1] = k0.y; wk[i * 4 + 2] = k0.z; wk[i * 4 + 3] = k0.w;
    wv[i * 4 + 0] = v0.x; wv[i * 4 + 1] = v0.y; wv[i * 4 + 2] = v0.z; wv[i * 4 + 3] = v0.w;
  }
  float hacc[16];
  if (FIRST) {
#pragma unroll
    for (int j = 0; j < 16; j++) hacc[j] = 0.f;
  } else {
    const float* hg = &h_att[(size_t)b * 8192];
#pragma unroll
    for (int j = 0; j < 16; j++) hacc[j] = hg[h * 512 + head * 16 + j];
  }
  float ks = 0.f;
  const int n0 = goff[b], n1 = goff[b + 1];
  float r[8];
#pragma unroll
  for (int nn = 0; nn < 8; nn++) {
    int n = n0 + nn;
    r[nn] = (n < n1) ? xv0[(size_t)n * 256 + tid] : 0.f;
  }
  for (int nbase = n0; nbase < n1; nbase += 8) {
#pragma unroll
    for (int nn = 0; nn < 8; nn++) rows[nn][tid] = r[nn];
    __syncthreads();
#pragma unroll
    for (int nn = 0; nn < 8; nn++) {
      int n = nbase + 8 + nn;
      r[nn] = (n < n1) ? xv0[(size_t)n * 256 + tid] : 0.f;
    }
#pragma unroll
    for (int nn = 0; nn < 8; nn++) {
      const float4* rp = reinterpret_cast<const float4*>(&rows[nn][g * 16]);
      float aK = 0.f, aV = 0.f;
#pragma unroll
      for (int q = 0; q < 4; q++) {
        float4 x0 = rp[q];
#pragma unroll
        for (int t = 0; t < 4; t++) {
          float e0 = (&x0.x)[t];
          aK += e0 * wk[q * 4 + t];
          aV += e0 * wv[q * 4 + t];
        }
      }
      bool valid = (nbase + nn) < n1;
      float ek = valid ? expf(aK * 0.25f) : 0.f;
      kx[nn][tid] = ek;
      vx[nn][tid] = aV;
      ks += ek;
    }
    __syncthreads();
#pragma unroll
    for (int nn = 0; nn < 8; nn++) {
      float kk = kx[nn][tid];
      const float4* vp = reinterpret_cast<const float4*>(&vx[nn][headLocal * 16]);
#pragma unroll
      for (int q = 0; q < 4; q++) {
        float4 vq = vp[q];
        hacc[q * 4 + 0] += kk * vq.x;
        hacc[q * 4 + 1] += kk * vq.y;
        hacc[q * 4 + 2] += kk * vq.z;
        hacc[q * 4 + 3] += kk * vq.w;
      }
    }
    __syncthreads();
  }
  float* hgo = &h_att[(size_t)b * 8192];
#pragma unroll
  for (int j = 0; j < 16; j++) hgo[h * 512 + head * 16 + j] = hacc[j];
  xk_sum[(size_t)b * 512 + p] = ks;
}

// Per-graph att_out: block = graph b; h_att[b] + q_w staged in LDS; loop nodes 8 at a
// time with thread = (nodeLocal, head). Each thread computes its head's full 16-wide
// output row (32 B coalesced store).
__global__ __launch_bounds__(256) void att_out_kernel(
    const float* __restrict__ xv0, const float* __restrict__ q_w,
    const float* __restrict__ xk_sum, const float* __restrict__ h_att,
    const int* __restrict__ goff, f16* __restrict__ out) {
  __shared__ float sqw[16 * 260];  // [g][oo*16+i], stride 260
  __shared__ float hat[16 * 644];  // [h][head*20+v], h-plane stride 644 (16B aligned)
  int tid = threadIdx.x, b = blockIdx.x;
  for (int i = tid; i < 8192; i += 256) {
    int g = i >> 9, rem = i & 511;  // q_w layout [g][32][16]
    sqw[g * 260 + rem] = q_w[i];
  }
  for (int i = tid; i < 8192; i += 256) {
    int h = i >> 9, rem = i & 511;  // rem = head*16 + v
    int head = rem >> 4, v = rem & 15;
    hat[h * 644 + head * 20 + v] = h_att[(size_t)b * 8192 + i];
  }
  __syncthreads();
  int n0 = goff[b], n1 = goff[b + 1];
  int nl = tid >> 5, head = tid & 31;
  int g = head >> 1, j = head & 1;
  const float* ks = &xk_sum[(size_t)b * 512 + head * 16];
  for (int nbase = n0; nbase < n1; nbase += 8) {
    int n = nbase + nl;
    if (n >= n1) continue;
    float x[16];
    const float4* xp4 = reinterpret_cast<const float4*>(&xv0[(size_t)n * 256 + g * 16]);
#pragma unroll
    for (int q = 0; q < 4; q++) {
      float4 xq = xp4[q];
#pragma unroll
      for (int t = 0; t < 4; t++) x[q * 4 + t] = (&xq.x)[t];
    }
    float qv[16];
    float denom = 0.f;
#pragma unroll
    for (int h = 0; h < 16; h++) {
      const float4* wp = reinterpret_cast<const float4*>(&sqw[g * 260 + (j * 16 + h) * 16]);
      float a = 0.f;
#pragma unroll
      for (int q = 0; q < 4; q++) {
        float4 wq = wp[q];
#pragma unroll
        for (int t = 0; t < 4; t++) a += x[q * 4 + t] * (&wq.x)[t];
      }
      float e = expf(a * 0.25f);
      qv[h] = e;
      denom += e * ks[h];
    }
    float inv = 1.f / denom;
    float acc[16] = {0.f, 0.f, 0.f, 0.f, 0.f, 0.f, 0.f, 0.f,
                     0.f, 0.f, 0.f, 0.f, 0.f, 0.f, 0.f, 0.f};
#pragma unroll
    for (int h = 0; h < 16; h++) {
      float qh = qv[h];
      const float4* hp = reinterpret_cast<const float4*>(&hat[h * 644 + head * 20]);
#pragma unroll
      for (int q = 0; q < 4; q++) {
        float4 vq = hp[q];
        acc[q * 4 + 0] += qh * vq.x;
        acc[q * 4 + 1] += qh * vq.y;
        acc[q * 4 + 2] += qh * vq.z;
        acc[q * 4 + 3] += qh * vq.w;
      }
    }
    f16 res[16];
#pragma unroll
    for (int v = 0; v < 16; v++) res[v] = (f16)(acc[v] * inv);
    uint4* op = reinterpret_cast<uint4*>(&out[(size_t)n * 512 + head * 16]);
    op[0] = reinterpret_cast<const uint4*>(res)[0];
    op[1] = reinterpret_cast<const uint4*>(res)[1];
  }
}

__global__ __launch_bounds__(256) void virt_seg_kernel(const float* __restrict__ h_in,
    const int* __restrict__ goff, float* __restrict__ h_virt) {
  int b = blockIdx.x, c = threadIdx.x;
  float acc = h_virt[(size_t)b * 256 + c];
  int n0 = goff[b], n1 = goff[b + 1];
  for (int n = n0; n < n1; n++) acc += h_in[(size_t)n * 256 + c];
  h_virt[(size_t)b * 256 + c] = acc;
}

// ---------------- host driver ----------------

extern "C" void kernel_launch(void* const* d_in, const int* in_sizes, int n_in,
                              void* d_out, int out_size, void* d_ws, size_t ws_size,
                              hipStream_t stream) {
  const int* x_feat = (const int*)d_in[0];
  const int* eidx = (const int*)d_in[1];
  const int* eattr = (const int*)d_in[2];
  const int* batch = (const int*)d_in[3];
  const float* edist = (const float*)d_in[5];
  const float* atom_emb = (const float*)d_in[6];
  const float* bond2d = (const float*)d_in[7];
  const float* gmeans = (const float*)d_in[8];
  const float* gstds = (const float*)d_in[9];
  const float* attn_w = (const float*)d_in[10];
  const float* attn_b = (const float*)d_in[11];
  const float* scale_both = (const float*)d_in[12];
  const float* conv_bond_emb = (const float*)d_in[13];
  const float* conv_pre_w = (const float*)d_in[14];
  const float* conv_gate_w = (const float*)d_in[15];
  const float* conv_val_w = (const float*)d_in[16];
  const float* conv_post_w = (const float*)d_in[17];
  const float* conv_post_b = (const float*)d_in[18];
  const float* conv_scale = (const float*)d_in[19];
  const float* virt_pre_w = (const float*)d_in[20];
  const float* virt_pre_b = (const float*)d_in[21];
  const float* virt_gate_w = (const float*)d_in[22];
  const float* virt_val_w = (const float*)d_in[23];
  const float* virt_post_w = (const float*)d_in[24];
  const float* virt_post_b = (const float*)d_in[25];
  const float* virt_scale = (const float*)d_in[26];
  const float* att_pre_w = (const float*)d_in[27];
  const float* att_pre_b = (const float*)d_in[28];
  const float* att_q_w = (const float*)d_in[29];
  const float* att_k_w = (const float*)d_in[30];
  const float* att_v_w = (const float*)d_in[31];
  const float* att_post_w = (const float*)d_in[32];
  const float* att_post_b = (const float*)d_in[33];
  const float* att_scale = (const float*)d_in[34];
  const float* main_pre_w = (const float*)d_in[35];
  const float* main_pre_b = (const float*)d_in[36];
  const float* main_gate_w = (const float*)d_in[37];
  const float* main_val_w = (const float*)d_in[38];
  const float* main_post_w = (const float*)d_in[39];
  const float* main_post_b = (const float*)d_in[40];

  const int* src = eidx;
  const int* dst = eidx + EE;

  float* ws = (float*)d_ws;
  float* h_in = ws;
  float* h_out = ws + ND;
  float* x_raw = ws + 2 * ND;
  float* x_out = ws + 3 * ND;
  float* nodeA = ws + 4 * ND;
  f16* h_inH = (f16*)(ws + 5 * ND);
  f16* xrawH = (f16*)(ws + 5 * ND + ND / 2);
  f16* hTmp = (f16*)(ws + 6 * ND);
  f16* msgH = (f16*)(ws + 6 * ND + ND / 2);   // 3*ND halfs
  float* sm = ws + 8 * ND;
  f16* hW = (f16*)sm;                          // 2359296 halfs = 1179648 floats
  float* h_virt = sm + 1179648;
  float* h_att = h_virt + 65536;
  float* xk_sum = h_att + 2097152;
  float* vt1 = xk_sum + 131072;
  float* vout = vt1 + 65536;
  f16* vmidH = (f16*)(vout + 65536);           // B*512 halfs
  f16* virtH = vmidH + 131072;                 // B*256 halfs
  int* cnt = (int*)(virtH + 65536);
  int* deg = cnt + NN;
  int* goff = deg + NN;
  int* off = goff + BB + 1;
  int* cursor = off + NN + 1;
  int* elist = cursor + NN;
  int* ea_s = elist + EE;
  int* src_s = ea_s + 3 * EE;
  int* dst_s = src_s + EE;
  float* ed_s = (float*)(dst_s + EE);

  f16* wCpre = hW;
  f16* wCpost = hW + 524288;
  f16* wApre = hW + 1048576;
  f16* wApost = hW + 1179648;
  f16* wMpre = hW + 1441792;
  f16* wMpost = hW + 1572864;
  f16* wVpre = hW + 1966080;
  f16* wVpost = hW + 2097152;

  auto cvt = [&](const float* in, f16* out, int n) {
    f2h_kernel<<<n / 4 / 256, 256, 0, stream>>>(in, out, n / 4);
  };

  cvt(conv_pre_w, wCpre, 524288);
  cvt(conv_post_w, wCpost, 524288);
  cvt(att_pre_w, wApre, 131072);
  cvt(att_post_w, wApost, 262144);
  cvt(main_pre_w, wMpre, 131072);
  cvt(main_post_w, wMpost, 393216);
  cvt(virt_pre_w, wVpre, 131072);
  cvt(virt_post_w, wVpost, 262144);

  // degree + graph offsets + CSR (edges grouped by dst) + gathered edge data
  (void)hipMemsetAsync(cnt, 0, NN * sizeof(int), stream);
  count_deg_kernel<<<EE / 256, 256, 0, stream>>>(dst, cnt, EE);
  clip_deg_kernel<<<NN / 256, 256, 0, stream>>>(cnt, deg, NN);
  goff_kernel<<<(NN + 256) / 256, 256, 0, stream>>>(batch, goff, NN, BB);
  scan_off_kernel<<<1, 256, 0, stream>>>(cnt, off);
  copy_i_kernel<<<NN / 256, 256, 0, stream>>>(off, cursor, NN);
  fill_elist_kernel<<<EE / 256, 256, 0, stream>>>(dst, cursor, elist, EE);
  gather_edges_kernel<<<EE / 256, 256, 0, stream>>>(elist, eattr, src, dst, edist,
                                                    ea_s, src_s, dst_s, ed_s);

  // initial node features
  edge_feat_kernel<<<EE / 4, 256, 0, stream>>>(ea_s, ed_s, bond2d, gmeans, gstds,
                                               attn_w, attn_b, msgH);
  seg_reduce_kernel<float><<<NN / 4, 256, 0, stream>>>(msgH, off, x_out);
  atom_finish_kernel<<<NN * 64 / 256, 256, 0, stream>>>(x_feat, atom_emb, scale_both, deg,
                                                        x_out, h_in, h_inH);
  (void)hipMemsetAsync(h_virt, 0, 65536 * 4, stream);

  const dim3 gN(NN / 128, 4), gB(BB / 128, 4);
  const int n4 = (int)(ND / 4);

  for (int l = 0; l < 2; l++) {
    // ---- ConvMessage ----
    const f16* curH = h_inH;
    for (int k = 0; k < 4; k++) {
      if (k == 2) {
        add3_both_kernel<<<n4 / 256, 256, 0, stream>>>(x_raw, xrawH, h_in, x_out, n4);
        curH = xrawH;
      }
      size_t lk = (size_t)(l * 4 + k);
      hgemm_kernel<0><<<gN, 256, 0, stream>>>(curH, wCpre + lk * 65536, nullptr, nullptr,
                                              nullptr, nullptr, nullptr, nullptr, hTmp, 256);
      conv_edge_kernel<<<EE * 16 / 256, 256, 0, stream>>>(
          hTmp, ea_s, src_s, dst_s, conv_bond_emb + lk * 6144,
          conv_gate_w + lk * 4096, conv_val_w + lk * 4096, msgH);
      seg_reduce_kernel<f16><<<NN / 4, 256, 0, stream>>>(msgH, off, hTmp);
      if (k == 0 || k == 2)
        hgemm_kernel<5><<<gN, 256, 0, stream>>>(hTmp, wCpost + lk * 65536,
                                                conv_post_b + lk * 256, conv_scale + lk * 1024,
                                                cnt, deg, nullptr, x_out, xrawH, 256);
      else
        hgemm_kernel<4><<<gN, 256, 0, stream>>>(hTmp, wCpost + lk * 65536,
                                                conv_post_b + lk * 256, conv_scale + lk * 1024,
                                                cnt, deg, nullptr, x_out, xrawH, 256);
      curH = xrawH;
    }
    add3_kernel<<<n4 / 256, 256, 0, stream>>>(h_out, h_in, x_out, n4);

    // ---- VirtMessage ----
    virt_seg_kernel<<<BB, 256, 0, stream>>>(h_in, goff, h_virt);
    cvt(h_virt, virtH, 65536);
    hgemm_kernel<0><<<gB, 256, 0, stream>>>(virtH, wVpre + (size_t)l * 65536,
                                            virt_pre_b + (size_t)l * 256, nullptr, nullptr,
                                            nullptr, vt1, nullptr, nullptr, 256);
    glb_mid_kernel<32><<<BB * 16 / 256, 256, 0, stream>>>(
        vt1, virt_gate_w + (size_t)l * 8192, virt_val_w + (size_t)l * 8192, vmidH);
    hgemm_kernel<0><<<gB, 256, 0, stream>>>(vmidH, wVpost + (size_t)l * 131072,
                                            virt_post_b + (size_t)l * 256, nullptr, nullptr,
                                            nullptr, vout, nullptr, nullptr, 512);
    bcast_add_kernel<<<n4 / 256, 256, 0, stream>>>(
        h_out, vout, virt_scale + (size_t)l * 256, batch);

    // ---- AttMessage ----
    hgemm_kernel<0><<<gN, 256, 0, stream>>>(h_inH, wApre + (size_t)l * 65536,
                                            att_pre_b + (size_t)l * 256, nullptr, nullptr,
                                            nullptr, nodeA, nullptr, nullptr, 256);
    gn_vec_kernel<<<NN * 64 / 256, 256, 0, stream>>>(nodeA);
    if (l == 0)
      att_graph_kernel<true><<<BB * 2, 256, 0, stream>>>(
          nodeA, att_k_w + (size_t)l * 8192, att_v_w + (size_t)l * 8192, goff, h_att, xk_sum);
    else
      att_graph_kernel<false><<<BB * 2, 256, 0, stream>>>(
          nodeA, att_k_w + (size_t)l * 8192, att_v_w + (size_t)l * 8192, goff, h_att, xk_sum);
    att_out_kernel<<<BB, 256, 0, stream>>>(
        nodeA, att_q_w + (size_t)l * 8192, xk_sum, h_att, goff, msgH);
    hgemm_kernel<2><<<gN, 256, 0, stream>>>(msgH, wApost + (size_t)l * 131072,
                                            att_post_b + (size_t)l * 256,
                                            att_scale + (size_t)l * 256, nullptr, nullptr,
                                            nullptr, h_out, hTmp, 512);

    // ---- main gated block ----
    hgemm_kernel<0><<<gN, 256, 0, stream>>>(hTmp, wMpre + (size_t)l * 65536,
                                            main_pre_b + (size_t)l * 256, nullptr, nullptr,
                                            nullptr, nodeA, nullptr, nullptr, 256);
    glb_mid_kernel<48><<<NN * 16 / 256, 256, 0, stream>>>(
        nodeA, main_gate_w + (size_t)l * 12288, main_val_w + (size_t)l * 12288, msgH);
    float* hdst = (l == 1) ? (float*)d_out : h_in;
    f16* hdstH = (l == 1) ? nullptr : h_inH;
    hgemm_kernel<0><<<gN, 256, 0, stream>>>(msgH, wMpost + (size_t)l * 196608,
                                            main_post_b + (size_t)l * 256, nullptr, nullptr,
                                            nullptr, hdst, nullptr, hdstH, 768);
  }
}